// Round 1
// baseline (1129.920 us; speedup 1.0000x reference)
//
#include <hip/hip_runtime.h>

#define N_USERS 40000
#define N_POIS  20000
#define DIM     128
#define N_EDGES 500000
#define BATCH   256
#define NPOS    100
#define TOPK    20
#define NCHUNK  256
#define CPT     157   // ceil(40000/256)

__device__ __forceinline__ int iclamp(int x, int lo, int hi) {
    return x < lo ? lo : (x > hi ? hi : x);
}
__device__ __forceinline__ float2 h2f2(unsigned int u) {
    union { unsigned int u32; _Float16 h[2]; } v; v.u32 = u;
    return make_float2((float)v.h[0], (float)v.h[1]);
}
__device__ __forceinline__ unsigned int f2h2(float x, float y) {
    union { unsigned int u32; _Float16 h[2]; } v;
    v.h[0] = (_Float16)x; v.h[1] = (_Float16)y; return v.u32;
}
__device__ __forceinline__ float softmax3(const float* p, int sel) {
    float a0 = p[0], a1 = p[1], a2 = p[2];
    float m = fmaxf(a0, fmaxf(a1, a2));
    float e0 = expf(a0 - m), e1 = expf(a1 - m), e2 = expf(a2 - m);
    float den = e0 + e1 + e2;
    float e = (sel == 0) ? e0 : ((sel == 1) ? e1 : e2);
    return e / den;
}

// ---------------- zero init ----------------
__global__ void zero_kernel(unsigned int* __restrict__ p, int nwords) {
    int i = blockIdx.x * blockDim.x + threadIdx.x;
    if (i < nwords) p[i] = 0u;
}

// ---------------- fp32 -> fp16 cast ----------------
__global__ void cast_f16_kernel(const float* __restrict__ src, unsigned short* __restrict__ dst,
                                int n2) {
    int i = blockIdx.x * blockDim.x + threadIdx.x;
    if (i < n2) {
        float2 v = *(const float2*)(src + 2 * (size_t)i);
        *(unsigned int*)(dst + 2 * (size_t)i) = f2h2(v.x, v.y);
    }
}

// ---------------- CSR build ----------------
__global__ void hist_kernel(const int* __restrict__ er, const int* __restrict__ ec,
                            int* __restrict__ rcnt, int* __restrict__ ccnt) {
    int e = blockIdx.x * blockDim.x + threadIdx.x;
    if (e < N_EDGES) {
        atomicAdd(&rcnt[iclamp(er[e], 0, N_USERS - 1)], 1);
        atomicAdd(&ccnt[iclamp(ec[e], 0, N_POIS - 1)], 1);
    }
}

__global__ void scan_kernel(const int* __restrict__ rcnt, int* __restrict__ rptr,
                            const int* __restrict__ ccnt, int* __restrict__ cptr) {
    const int* cnt = blockIdx.x ? ccnt : rcnt;
    int* ptr = blockIdx.x ? cptr : rptr;
    int n = blockIdx.x ? N_POIS : N_USERS;
    __shared__ int part[256];
    __shared__ int pref[257];
    int C = (n + 255) / 256;
    int lo = threadIdx.x * C;
    int hi = lo + C; if (hi > n) hi = n;
    int s = 0;
    for (int i = lo; i < hi; i++) s += cnt[i];
    part[threadIdx.x] = s;
    __syncthreads();
    if (threadIdx.x == 0) {
        int r = 0;
        for (int i = 0; i < 256; i++) { pref[i] = r; r += part[i]; }
        pref[256] = r;
    }
    __syncthreads();
    int r = pref[threadIdx.x];
    for (int i = lo; i < hi; i++) { ptr[i] = r; r += cnt[i]; }
    if (threadIdx.x == 0) ptr[n] = pref[256];
}

__global__ void fill_kernel(const int* __restrict__ er, const int* __restrict__ ec,
                            const int* __restrict__ rptr, const int* __restrict__ cptr,
                            int* __restrict__ rcur, int* __restrict__ ccur,
                            int* __restrict__ rcols, int* __restrict__ crows,
                            const float* __restrict__ ck, const float* __restrict__ fv,
                            const float* __restrict__ cs,
                            float* __restrict__ rv0, float* __restrict__ rv1, float* __restrict__ rv2,
                            float* __restrict__ cv0, float* __restrict__ cv1, float* __restrict__ cv2) {
    int e = blockIdx.x * blockDim.x + threadIdx.x;
    if (e < N_EDGES) {
        int r = iclamp(er[e], 0, N_USERS - 1), c = iclamp(ec[e], 0, N_POIS - 1);
        float v0 = ck[e], v1 = fv[e], v2 = cs[e];
        int pr = iclamp(rptr[r] + atomicAdd(&rcur[r], 1), 0, N_EDGES - 1);
        rcols[pr] = c; rv0[pr] = v0; rv1[pr] = v1; rv2[pr] = v2;
        int pc = iclamp(cptr[c] + atomicAdd(&ccur[c], 1), 0, N_EDGES - 1);
        crows[pc] = r; cv0[pc] = v0; cv1[pc] = v1; cv2[pc] = v2;
    }
}

// ---------------- SpMM: one wave per row; fp16 src gather; predicated tail batch ----------------
// raw_h (fp16) = A*src ; acc (fp32) = base + raw/||raw||
__global__ __launch_bounds__(256) void spmm_kernel(
        const int* __restrict__ ptr, const int* __restrict__ nbr,
        const float* __restrict__ vals,                 // CSR-ordered
        const unsigned short* __restrict__ src,         // fp16 [*,128]
        unsigned short* __restrict__ raw_h,             // fp16 out
        const float* __restrict__ base,                 // fp32 (may alias acc)
        float* __restrict__ acc, int nrows) {
    int wid = (blockIdx.x * blockDim.x + threadIdx.x) >> 6;
    int lane = threadIdx.x & 63;
    if (wid >= nrows) return;
    int beg = __builtin_amdgcn_readfirstlane(iclamp(ptr[wid], 0, N_EDGES));
    int end = __builtin_amdgcn_readfirstlane(iclamp(ptr[wid + 1], 0, N_EDGES));
    if (end < beg) end = beg;
    float ax = 0.f, ay = 0.f;
    int e = beg;
    int lo2 = lane * 2;
    for (; e + 8 <= end; e += 8) {
        int c0 = nbr[e + 0], c1 = nbr[e + 1], c2 = nbr[e + 2], c3 = nbr[e + 3];
        int c4 = nbr[e + 4], c5 = nbr[e + 5], c6 = nbr[e + 6], c7 = nbr[e + 7];
        float v0 = vals[e + 0], v1 = vals[e + 1], v2 = vals[e + 2], v3 = vals[e + 3];
        float v4 = vals[e + 4], v5 = vals[e + 5], v6 = vals[e + 6], v7 = vals[e + 7];
        float2 p0 = h2f2(*(const unsigned int*)(src + (size_t)c0 * DIM + lo2));
        float2 p1 = h2f2(*(const unsigned int*)(src + (size_t)c1 * DIM + lo2));
        float2 p2 = h2f2(*(const unsigned int*)(src + (size_t)c2 * DIM + lo2));
        float2 p3 = h2f2(*(const unsigned int*)(src + (size_t)c3 * DIM + lo2));
        float2 p4 = h2f2(*(const unsigned int*)(src + (size_t)c4 * DIM + lo2));
        float2 p5 = h2f2(*(const unsigned int*)(src + (size_t)c5 * DIM + lo2));
        float2 p6 = h2f2(*(const unsigned int*)(src + (size_t)c6 * DIM + lo2));
        float2 p7 = h2f2(*(const unsigned int*)(src + (size_t)c7 * DIM + lo2));
        ax = fmaf(v0, p0.x, fmaf(v1, p1.x, fmaf(v2, p2.x, fmaf(v3, p3.x, ax))));
        ax = fmaf(v4, p4.x, fmaf(v5, p5.x, fmaf(v6, p6.x, fmaf(v7, p7.x, ax))));
        ay = fmaf(v0, p0.y, fmaf(v1, p1.y, fmaf(v2, p2.y, fmaf(v3, p3.y, ay))));
        ay = fmaf(v4, p4.y, fmaf(v5, p5.y, fmaf(v6, p6.y, fmaf(v7, p7.y, ay))));
    }
    if (e < end) {
        // branchless predicated batch of up to 8 — all loads in flight before any FMA
        int last = end - 1;
        int e1 = e + 1 <= last ? e + 1 : last;
        int e2 = e + 2 <= last ? e + 2 : last;
        int e3 = e + 3 <= last ? e + 3 : last;
        int e4 = e + 4 <= last ? e + 4 : last;
        int e5 = e + 5 <= last ? e + 5 : last;
        int e6 = e + 6 <= last ? e + 6 : last;
        int e7 = e + 7 <= last ? e + 7 : last;
        int c0 = nbr[e], c1 = nbr[e1], c2 = nbr[e2], c3 = nbr[e3];
        int c4 = nbr[e4], c5 = nbr[e5], c6 = nbr[e6], c7 = nbr[e7];
        float v0 = vals[e];
        float v1 = (e + 1 < end) ? vals[e1] : 0.f;
        float v2 = (e + 2 < end) ? vals[e2] : 0.f;
        float v3 = (e + 3 < end) ? vals[e3] : 0.f;
        float v4 = (e + 4 < end) ? vals[e4] : 0.f;
        float v5 = (e + 5 < end) ? vals[e5] : 0.f;
        float v6 = (e + 6 < end) ? vals[e6] : 0.f;
        float v7 = (e + 7 < end) ? vals[e7] : 0.f;
        float2 p0 = h2f2(*(const unsigned int*)(src + (size_t)c0 * DIM + lo2));
        float2 p1 = h2f2(*(const unsigned int*)(src + (size_t)c1 * DIM + lo2));
        float2 p2 = h2f2(*(const unsigned int*)(src + (size_t)c2 * DIM + lo2));
        float2 p3 = h2f2(*(const unsigned int*)(src + (size_t)c3 * DIM + lo2));
        float2 p4 = h2f2(*(const unsigned int*)(src + (size_t)c4 * DIM + lo2));
        float2 p5 = h2f2(*(const unsigned int*)(src + (size_t)c5 * DIM + lo2));
        float2 p6 = h2f2(*(const unsigned int*)(src + (size_t)c6 * DIM + lo2));
        float2 p7 = h2f2(*(const unsigned int*)(src + (size_t)c7 * DIM + lo2));
        ax = fmaf(v0, p0.x, fmaf(v1, p1.x, fmaf(v2, p2.x, fmaf(v3, p3.x, ax))));
        ax = fmaf(v4, p4.x, fmaf(v5, p5.x, fmaf(v6, p6.x, fmaf(v7, p7.x, ax))));
        ay = fmaf(v0, p0.y, fmaf(v1, p1.y, fmaf(v2, p2.y, fmaf(v3, p3.y, ay))));
        ay = fmaf(v4, p4.y, fmaf(v5, p5.y, fmaf(v6, p6.y, fmaf(v7, p7.y, ay))));
    }
    float n2 = ax * ax + ay * ay;
    #pragma unroll
    for (int o = 32; o > 0; o >>= 1) n2 += __shfl_xor(n2, o, 64);
    float inv = rsqrtf(fmaxf(n2, 1e-30f));
    *(unsigned int*)(raw_h + (size_t)wid * DIM + lo2) = f2h2(ax, ay);
    float2 bv = *(const float2*)(base + (size_t)wid * DIM + lo2);
    *(float2*)(acc + (size_t)wid * DIM + lo2) =
        make_float2(bv.x + ax * inv, bv.y + ay * inv);
}

// ---------------- out = A[Mx128] @ W^T ; A-tile in LDS ----------------
__global__ __launch_bounds__(256) void gemm_aw_kernel(
        const float* __restrict__ A, const float* __restrict__ W,
        float* __restrict__ store, float* __restrict__ accum,
        const float* __restrict__ fw3, int fsel, int first, int M) {
    __shared__ float Al[32 * 128];                 // 16 KB
    int i0 = blockIdx.x * 32;
    const float4* Ag = (const float4*)(A + (size_t)i0 * DIM);
    float4* Al4 = (float4*)Al;
    for (int qi = threadIdx.x; qi < 1024; qi += 256) Al4[qi] = Ag[qi];
    __syncthreads();
    float coef = accum ? softmax3(fw3, fsel) : 0.f;
    int j2 = threadIdx.x & 63;
    int rg = threadIdx.x >> 6;
    const float4* W0 = (const float4*)(W + (size_t)j2 * DIM);
    const float4* W1 = (const float4*)(W + (size_t)(j2 + 64) * DIM);
    float acc0[8], acc1[8];
    #pragma unroll
    for (int m = 0; m < 8; m++) { acc0[m] = 0.f; acc1[m] = 0.f; }
    for (int kq = 0; kq < 32; kq++) {
        float4 w0 = W0[kq];
        float4 w1 = W1[kq];
        #pragma unroll
        for (int m = 0; m < 8; m++) {
            float4 a = Al4[(rg + 4 * m) * 32 + kq];
            acc0[m] = fmaf(a.x, w0.x, acc0[m]); acc0[m] = fmaf(a.y, w0.y, acc0[m]);
            acc0[m] = fmaf(a.z, w0.z, acc0[m]); acc0[m] = fmaf(a.w, w0.w, acc0[m]);
            acc1[m] = fmaf(a.x, w1.x, acc1[m]); acc1[m] = fmaf(a.y, w1.y, acc1[m]);
            acc1[m] = fmaf(a.z, w1.z, acc1[m]); acc1[m] = fmaf(a.w, w1.w, acc1[m]);
        }
    }
    #pragma unroll
    for (int m = 0; m < 8; m++) {
        int i = i0 + rg + 4 * m;
        if (i >= M) continue;
        size_t o0 = (size_t)i * DIM + j2;
        size_t o1 = o0 + 64;
        if (store) { store[o0] = acc0[m]; store[o1] = acc1[m]; }
        if (accum) {
            float p0 = first ? 0.f : accum[o0];
            float p1 = first ? 0.f : accum[o1];
            accum[o0] = p0 + coef * acc0[m];
            accum[o1] = p1 + coef * acc1[m];
        }
    }
}

// ---------------- 256 selected rows of uf = su @ Wu^T ----------------
__global__ void ufsel_kernel(const float* __restrict__ su, const float* __restrict__ W,
                             const int* __restrict__ uidx, float* __restrict__ outsel) {
    int b = blockIdx.x, j = threadIdx.x;  // block 128
    __shared__ float ar[128];
    int u = iclamp(uidx[b], 0, N_USERS - 1);
    ar[j] = su[(size_t)u * DIM + j];
    __syncthreads();
    const float4* Wr = (const float4*)(W + (size_t)j * DIM);
    float acc = 0.f;
    #pragma unroll 8
    for (int q = 0; q < 32; q++) {
        float4 wq = Wr[q];
        acc = fmaf(ar[4 * q + 0], wq.x, acc);
        acc = fmaf(ar[4 * q + 1], wq.y, acc);
        acc = fmaf(ar[4 * q + 2], wq.z, acc);
        acc = fmaf(ar[4 * q + 3], wq.w, acc);
    }
    outsel[(size_t)b * DIM + j] = acc;
}

// ---------------- alt[b,j] (+)= wn_c * dot(uf_c[b], pf_c[poi]) ----------------
__global__ __launch_bounds__(256) void predict_kernel(
        const float* __restrict__ ufs, const float* __restrict__ pf,
        const int* __restrict__ pidx, const float* __restrict__ w3,
        int wsel, int first, float* __restrict__ alt) {
    int wid = (blockIdx.x * blockDim.x + threadIdx.x) >> 6;
    int lane = threadIdx.x & 63;
    if (wid >= BATCH * NPOS) return;
    int b = wid / NPOS;
    int poi = iclamp(pidx[wid], 0, N_POIS - 1);
    const float2 uv = *(const float2*)(ufs + (size_t)b * DIM + lane * 2);
    const float2 pv = *(const float2*)(pf + (size_t)poi * DIM + lane * 2);
    float s = uv.x * pv.x + uv.y * pv.y;
    #pragma unroll
    for (int o = 32; o > 0; o >>= 1) s += __shfl_xor(s, o, 64);
    if (lane == 0) {
        float coef = softmax3(w3, wsel);
        float prev = first ? 0.f : alt[wid];
        alt[wid] = prev + coef * s;
    }
}

// ---------------- BCE loss ----------------
__global__ void loss_kernel(const float* __restrict__ alt, const float* __restrict__ labels,
                            float* __restrict__ out) {
    __shared__ float red[256];
    float s = 0.f;
    for (int i = threadIdx.x; i < BATCH * NPOS; i += 256) {
        float x = alt[i], y = labels[i];
        s += fmaxf(x, 0.f) - x * y + log1pf(expf(-fabsf(x)));
    }
    red[threadIdx.x] = s;
    __syncthreads();
    for (int off = 128; off > 0; off >>= 1) {
        if (threadIdx.x < off) red[threadIdx.x] += red[threadIdx.x + off];
        __syncthreads();
    }
    if (threadIdx.x == 0) out[0] = red[0] / (float)(BATCH * NPOS);
}

// ---------------- bst[j][b] = id_feat[cur[b]] @ Ws^T + bias (transposed) ----------------
__global__ void bs_kernel(const float* __restrict__ idf, const float* __restrict__ Ws,
                          const float* __restrict__ bias, const int* __restrict__ uidx,
                          float* __restrict__ bst) {
    int b = blockIdx.x, j = threadIdx.x;  // block 128
    __shared__ float ar[128];
    int u = iclamp(uidx[b], 0, N_USERS - 1);
    ar[j] = idf[(size_t)u * DIM + j];
    __syncthreads();
    const float4* Wr = (const float4*)(Ws + (size_t)j * DIM);
    float acc = 0.f;
    #pragma unroll 8
    for (int q = 0; q < 32; q++) {
        float4 wq = Wr[q];
        acc = fmaf(ar[4 * q + 0], wq.x, acc);
        acc = fmaf(ar[4 * q + 1], wq.y, acc);
        acc = fmaf(ar[4 * q + 2], wq.z, acc);
        acc = fmaf(ar[4 * q + 3], wq.w, acc);
    }
    bst[(size_t)j * BATCH + b] = acc + bias[j];
}

__device__ __forceinline__ void topk_insert(float s, int u, float* ts, int* ti) {
    if (s > ts[TOPK - 1]) {
        #pragma unroll
        for (int j = TOPK - 1; j > 0; --j) {
            bool above = s > ts[j - 1];
            bool here = (!above) && (s > ts[j]);
            float nv = above ? ts[j - 1] : (here ? s : ts[j]);
            int ni = above ? ti[j - 1] : (here ? u : ti[j]);
            ts[j] = nv; ti[j] = ni;
        }
        if (s > ts[0]) { ts[0] = s; ti[0] = u; }
    }
}

// ---------------- fused uu scores + per-block top-20: 32 KB LDS, NCHUNK=256 ----------------
__global__ __launch_bounds__(256) void score_topk_kernel(
        const float* __restrict__ idf, const float* __restrict__ bst,
        float* __restrict__ cand_s, int* __restrict__ cand_i) {
    __shared__ __align__(16) unsigned char smraw[32768];
    float* bsl = (float*)smraw;                             // phase 1: [q][b][4] 32 KB
    float* ms  = (float*)smraw;                             // phase 2: [k][tid] 20 KB
    unsigned short* mi = (unsigned short*)(smraw + 20480);  // phase 2: [k][tid] u16 10 KB
    int cid = blockIdx.x, bg = blockIdx.y;
    for (int idx = threadIdx.x; idx < 32 * 64; idx += 256) {
        int b = idx & 63, q = idx >> 6;
        float4 v;
        v.x = bst[(size_t)(4 * q + 0) * BATCH + bg * 64 + b];
        v.y = bst[(size_t)(4 * q + 1) * BATCH + bg * 64 + b];
        v.z = bst[(size_t)(4 * q + 2) * BATCH + bg * 64 + b];
        v.w = bst[(size_t)(4 * q + 3) * BATCH + bg * 64 + b];
        *(float4*)&bsl[(size_t)idx * 4] = v;
    }
    __syncthreads();
    int b_l = threadIdx.x & 63, us = threadIdx.x >> 6;
    const float4* bcol = (const float4*)&bsl[b_l * 4];
    float ts[TOPK]; int ti[TOPK];
    #pragma unroll
    for (int k = 0; k < TOPK; k++) { ts[k] = -3.0e38f; ti[k] = 0; }
    int lo = cid * CPT;
    int hi = lo + CPT; if (hi > N_USERS) hi = N_USERS;
    for (int u0 = lo + us * 4; u0 < hi; u0 += 16) {
        int uc1 = u0 + 1 < N_USERS ? u0 + 1 : N_USERS - 1;
        int uc2 = u0 + 2 < N_USERS ? u0 + 2 : N_USERS - 1;
        int uc3 = u0 + 3 < N_USERS ? u0 + 3 : N_USERS - 1;
        const float4* r0 = (const float4*)(idf + (size_t)u0 * DIM);
        const float4* r1 = (const float4*)(idf + (size_t)uc1 * DIM);
        const float4* r2 = (const float4*)(idf + (size_t)uc2 * DIM);
        const float4* r3 = (const float4*)(idf + (size_t)uc3 * DIM);
        float s0 = 0.f, s1 = 0.f, s2 = 0.f, s3 = 0.f;
        #pragma unroll 8
        for (int q = 0; q < 32; q++) {
            float4 bb = bcol[q * 64];
            float4 a0 = r0[q], a1 = r1[q], a2 = r2[q], a3 = r3[q];
            s0 = fmaf(a0.x, bb.x, fmaf(a0.y, bb.y, fmaf(a0.z, bb.z, fmaf(a0.w, bb.w, s0))));
            s1 = fmaf(a1.x, bb.x, fmaf(a1.y, bb.y, fmaf(a1.z, bb.z, fmaf(a1.w, bb.w, s1))));
            s2 = fmaf(a2.x, bb.x, fmaf(a2.y, bb.y, fmaf(a2.z, bb.z, fmaf(a2.w, bb.w, s2))));
            s3 = fmaf(a3.x, bb.x, fmaf(a3.y, bb.y, fmaf(a3.z, bb.z, fmaf(a3.w, bb.w, s3))));
        }
        topk_insert(s0, u0, ts, ti);
        if (u0 + 1 < hi) topk_insert(s1, u0 + 1, ts, ti);
        if (u0 + 2 < hi) topk_insert(s2, u0 + 2, ts, ti);
        if (u0 + 3 < hi) topk_insert(s3, u0 + 3, ts, ti);
    }
    __syncthreads();
    #pragma unroll
    for (int k = 0; k < TOPK; k++) {
        ms[k * 256 + threadIdx.x] = ts[k];
        mi[k * 256 + threadIdx.x] = (unsigned short)ti[k];
    }
    __syncthreads();
    if (threadIdx.x < 64) {
        int t = threadIdx.x;
        int p0 = 0, p1 = 0, p2 = 0, p3 = 0;
        size_t ob = (((size_t)cid) * 256 + bg * 64 + t) * TOPK;
        for (int k = 0; k < TOPK; k++) {
            float h0 = ms[p0 * 256 + 0 * 64 + t];
            float h1 = ms[p1 * 256 + 1 * 64 + t];
            float h2 = ms[p2 * 256 + 2 * 64 + t];
            float h3 = ms[p3 * 256 + 3 * 64 + t];
            float best = h0; int which = 0;
            if (h1 > best) { best = h1; which = 1; }
            if (h2 > best) { best = h2; which = 2; }
            if (h3 > best) { best = h3; which = 3; }
            int idx;
            if (which == 0)      { idx = mi[p0 * 256 + 0 * 64 + t]; p0++; }
            else if (which == 1) { idx = mi[p1 * 256 + 1 * 64 + t]; p1++; }
            else if (which == 2) { idx = mi[p2 * 256 + 2 * 64 + t]; p2++; }
            else                 { idx = mi[p3 * 256 + 3 * 64 + t]; p3++; }
            cand_s[ob + k] = best;
            cand_i[ob + k] = idx;
        }
    }
}

// ---------------- global merge + softmax + weighted gather (NCHUNK=256 threads) ----------------
__global__ void topk_merge_kernel(const float* __restrict__ cand_s, const int* __restrict__ cand_i,
                                  const float* __restrict__ guf,
                                  float* __restrict__ outp) {
    int b = blockIdx.x, t = threadIdx.x;  // block 256 (= NCHUNK)
    __shared__ float rs[NCHUNK]; __shared__ int ru[NCHUNK]; __shared__ int rt[NCHUNK];
    __shared__ float win_s[TOPK]; __shared__ int win_u[TOPK]; __shared__ float wk[TOPK];
    __shared__ int winner;
    int ptr = 0;
    size_t base = ((size_t)t * 256 + b) * TOPK;
    for (int k = 0; k < TOPK; k++) {
        rs[t] = (ptr < TOPK) ? cand_s[base + ptr] : -3.0e38f;
        ru[t] = (ptr < TOPK) ? cand_i[base + ptr] : 0;
        rt[t] = t;
        __syncthreads();
        for (int off = NCHUNK / 2; off > 0; off >>= 1) {
            if (t < off && rs[t + off] > rs[t]) {
                rs[t] = rs[t + off]; ru[t] = ru[t + off]; rt[t] = rt[t + off];
            }
            __syncthreads();
        }
        if (t == 0) { win_s[k] = rs[0]; win_u[k] = iclamp(ru[0], 0, N_USERS - 1); winner = rt[0]; }
        __syncthreads();
        if (t == winner) ptr++;
        __syncthreads();
    }
    if (t == 0) {
        float m = win_s[0], den = 0.f;
        for (int k = 0; k < TOPK; k++) { wk[k] = expf(win_s[k] - m); den += wk[k]; }
        float inv = 1.f / den;
        for (int k = 0; k < TOPK; k++) wk[k] *= inv;
    }
    __syncthreads();
    if (t < DIM) {
        float acc = 0.f;
        #pragma unroll
        for (int k = 0; k < TOPK; k++)
            acc = fmaf(wk[k], guf[(size_t)win_u[k] * DIM + t], acc);
        outp[1 + (size_t)b * DIM + t] = acc;
    }
}

extern "C" void kernel_launch(void* const* d_in, const int* in_sizes, int n_in,
                              void* d_out, int out_size, void* d_ws, size_t ws_size,
                              hipStream_t stream) {
    (void)in_sizes; (void)n_in; (void)out_size; (void)ws_size;
    const int*   er      = (const int*)d_in[0];
    const int*   ec      = (const int*)d_in[1];
    const float* click   = (const float*)d_in[2];
    const float* favor   = (const float*)d_in[3];
    const float* consume = (const float*)d_in[4];
    const float* uid     = (const float*)d_in[5];
    const float* pid     = (const float*)d_in[6];
    const int*   uidx    = (const int*)d_in[7];
    const int*   pidx    = (const int*)d_in[8];
    const float* labels  = (const float*)d_in[9];
    const float* guf     = (const float*)d_in[10];
    const float* w3      = (const float*)d_in[11];
    const float* fw3     = (const float*)d_in[12];
    const float* Wuc     = (const float*)d_in[13];
    const float* Wpc     = (const float*)d_in[14];
    const float* Wufv    = (const float*)d_in[15];
    const float* Wpfv    = (const float*)d_in[16];
    const float* Wuco    = (const float*)d_in[17];
    const float* Wpco    = (const float*)d_in[18];
    const float* Wss     = (const float*)d_in[19];
    const float* bias    = (const float*)d_in[20];
    float* outp = (float*)d_out;

    char* ws = (char*)d_ws;
    size_t off = 0;
    auto carve = [&](size_t bytes) -> void* {
        off = (off + 255) & ~(size_t)255;
        void* p = ws + off;
        off += bytes;
        return p;
    };
    // total ~84 MB (proven-safe range)
    float* ufs = (float*)carve(4ll * 3 * BATCH * DIM);
    float* alt = (float*)carve(4ll * BATCH * NPOS);
    float* bst = (float*)carve(4ll * DIM * BATCH);
    int* rptr = (int*)carve(4 * (N_USERS + 1));
    int* cptr = (int*)carve(4 * (N_POIS + 1));
    int* cnts = (int*)carve(4 * (2 * (N_USERS + N_POIS)));
    int* rcnt = cnts;
    int* ccnt = cnts + N_USERS;
    int* rcur = ccnt + N_POIS;
    int* ccur = rcur + N_USERS;
    int* rcols = (int*)carve(4 * (size_t)N_EDGES);
    int* crows = (int*)carve(4 * (size_t)N_EDGES);
    float* rv[3]; float* cv[3];
    for (int c = 0; c < 3; c++) rv[c] = (float*)carve(4 * (size_t)N_EDGES);
    for (int c = 0; c < 3; c++) cv[c] = (float*)carve(4 * (size_t)N_EDGES);
    unsigned short* pid_h = (unsigned short*)carve(2ll * N_POIS * DIM);
    unsigned short* utr_h = (unsigned short*)carve(2ll * N_USERS * DIM);  // 10.24 MB; pf alias
    unsigned short* ptr_h = (unsigned short*)carve(2ll * N_POIS * DIM);
    float* su  = (float*)carve(4ll * N_USERS * DIM);   // cand alias
    float* sp  = (float*)carve(4ll * N_POIS * DIM);
    float* idf = (float*)carve(4ll * N_USERS * DIM);
    float* pf = (float*)utr_h;            // utr_h dead before pf written
    float* cand_s = su;                   // su dead before score_topk
    int*   cand_i = (int*)(su + (size_t)NCHUNK * BATCH * TOPK);   // 10.5 MB total, fits su(20.5 MB)

    zero_kernel<<<(2 * (N_USERS + N_POIS) + 255) / 256, 256, 0, stream>>>(
        (unsigned int*)cnts, 2 * (N_USERS + N_POIS));
    cast_f16_kernel<<<(N_POIS * DIM / 2 + 255) / 256, 256, 0, stream>>>(pid, pid_h, N_POIS * DIM / 2);
    hist_kernel<<<(N_EDGES + 255) / 256, 256, 0, stream>>>(er, ec, rcnt, ccnt);
    scan_kernel<<<2, 256, 0, stream>>>(rcnt, rptr, ccnt, cptr);
    fill_kernel<<<(N_EDGES + 255) / 256, 256, 0, stream>>>(
        er, ec, rptr, cptr, rcur, ccur, rcols, crows,
        click, favor, consume, rv[0], rv[1], rv[2], cv[0], cv[1], cv[2]);

    struct Ch { const float* Wu; const float* Wp; int wsel; int fsel; };
    // wn (softmax over w[1,3]):  favor=0, click=1, consume=2
    // fwn (softmax over fw[3,1]): favor=0, consume=1, click=2
    Ch chs[3] = { { Wuc,  Wpc,  1, 2 },     // ch0 = click
                  { Wufv, Wpfv, 0, 0 },     // ch1 = favor
                  { Wuco, Wpco, 2, 1 } };   // ch2 = consume

    for (int c = 0; c < 3; c++) {
        // layer 1: u1 = A p0 ; su = uid + n(u1).  p1 = A^T u1 ; sp = pid + n(p1)
        spmm_kernel<<<N_USERS * 64 / 256, 256, 0, stream>>>(rptr, rcols, rv[c], pid_h, utr_h, uid, su, N_USERS);
        spmm_kernel<<<N_POIS * 64 / 256, 256, 0, stream>>>(cptr, crows, cv[c], utr_h, ptr_h, pid, sp, N_POIS);
        // layer 2
        spmm_kernel<<<N_USERS * 64 / 256, 256, 0, stream>>>(rptr, rcols, rv[c], ptr_h, utr_h, su, su, N_USERS);
        spmm_kernel<<<N_POIS * 64 / 256, 256, 0, stream>>>(cptr, crows, cv[c], utr_h, ptr_h, sp, sp, N_POIS);
        // idf (+)= fwn_c * (su @ Wu^T)
        gemm_aw_kernel<<<N_USERS / 32, 256, 0, stream>>>(su, chs[c].Wu, nullptr, idf, fw3, chs[c].fsel, (c == 0) ? 1 : 0, N_USERS);
        ufsel_kernel<<<BATCH, 128, 0, stream>>>(su, chs[c].Wu, uidx, ufs + (size_t)c * BATCH * DIM);
        // pf = sp @ Wp^T  (pf aliases utr_h, dead after L2 poi hop)
        gemm_aw_kernel<<<N_POIS / 32, 256, 0, stream>>>(sp, chs[c].Wp, pf, nullptr, fw3, 0, 0, N_POIS);
        predict_kernel<<<BATCH * NPOS * 64 / 256, 256, 0, stream>>>(
            ufs + (size_t)c * BATCH * DIM, pf, pidx, w3, chs[c].wsel, (c == 0) ? 1 : 0, alt);
    }

    loss_kernel<<<1, 256, 0, stream>>>(alt, labels, outp);
    bs_kernel<<<BATCH, 128, 0, stream>>>(idf, Wss, bias, uidx, bst);
    dim3 sg(NCHUNK, 4);
    score_topk_kernel<<<sg, 256, 0, stream>>>(idf, bst, cand_s, cand_i);
    topk_merge_kernel<<<BATCH, NCHUNK, 0, stream>>>(cand_s, cand_i, guf, outp);
}

// Round 2
// 971.511 us; speedup vs baseline: 1.1631x; 1.1631x over previous
//
#include <hip/hip_runtime.h>

#define N_USERS 40000
#define N_POIS  20000
#define DIM     128
#define N_EDGES 500000
#define BATCH   256
#define NPOS    100
#define TOPK    20
#define NCHUNK  128
#define CPT     313   // ceil(40000/128)

typedef _Float16 f16x8 __attribute__((ext_vector_type(8)));
typedef float f32x4 __attribute__((ext_vector_type(4)));

__device__ __forceinline__ int iclamp(int x, int lo, int hi) {
    return x < lo ? lo : (x > hi ? hi : x);
}
__device__ __forceinline__ float2 h2f2(unsigned int u) {
    union { unsigned int u32; _Float16 h[2]; } v; v.u32 = u;
    return make_float2((float)v.h[0], (float)v.h[1]);
}
__device__ __forceinline__ unsigned int f2h2(float x, float y) {
    union { unsigned int u32; _Float16 h[2]; } v;
    v.h[0] = (_Float16)x; v.h[1] = (_Float16)y; return v.u32;
}
__device__ __forceinline__ float softmax3(const float* p, int sel) {
    float a0 = p[0], a1 = p[1], a2 = p[2];
    float m = fmaxf(a0, fmaxf(a1, a2));
    float e0 = expf(a0 - m), e1 = expf(a1 - m), e2 = expf(a2 - m);
    float den = e0 + e1 + e2;
    float e = (sel == 0) ? e0 : ((sel == 1) ? e1 : e2);
    return e / den;
}

// ---------------- zero init ----------------
__global__ void zero_kernel(unsigned int* __restrict__ p, int nwords) {
    int i = blockIdx.x * blockDim.x + threadIdx.x;
    if (i < nwords) p[i] = 0u;
}

// ---------------- fp32 -> fp16 cast ----------------
__global__ void cast_f16_kernel(const float* __restrict__ src, unsigned short* __restrict__ dst,
                                int n2) {
    int i = blockIdx.x * blockDim.x + threadIdx.x;
    if (i < n2) {
        float2 v = *(const float2*)(src + 2 * (size_t)i);
        *(unsigned int*)(dst + 2 * (size_t)i) = f2h2(v.x, v.y);
    }
}

// ---------------- CSR build ----------------
__global__ void hist_kernel(const int* __restrict__ er, const int* __restrict__ ec,
                            int* __restrict__ rcnt, int* __restrict__ ccnt) {
    int e = blockIdx.x * blockDim.x + threadIdx.x;
    if (e < N_EDGES) {
        atomicAdd(&rcnt[iclamp(er[e], 0, N_USERS - 1)], 1);
        atomicAdd(&ccnt[iclamp(ec[e], 0, N_POIS - 1)], 1);
    }
}

__global__ void scan_kernel(const int* __restrict__ rcnt, int* __restrict__ rptr,
                            const int* __restrict__ ccnt, int* __restrict__ cptr) {
    const int* cnt = blockIdx.x ? ccnt : rcnt;
    int* ptr = blockIdx.x ? cptr : rptr;
    int n = blockIdx.x ? N_POIS : N_USERS;
    __shared__ int part[256];
    __shared__ int pref[257];
    int C = (n + 255) / 256;
    int lo = threadIdx.x * C;
    int hi = lo + C; if (hi > n) hi = n;
    int s = 0;
    for (int i = lo; i < hi; i++) s += cnt[i];
    part[threadIdx.x] = s;
    __syncthreads();
    if (threadIdx.x == 0) {
        int r = 0;
        for (int i = 0; i < 256; i++) { pref[i] = r; r += part[i]; }
        pref[256] = r;
    }
    __syncthreads();
    int r = pref[threadIdx.x];
    for (int i = lo; i < hi; i++) { ptr[i] = r; r += cnt[i]; }
    if (threadIdx.x == 0) ptr[n] = pref[256];
}

__global__ void fill_kernel(const int* __restrict__ er, const int* __restrict__ ec,
                            const int* __restrict__ rptr, const int* __restrict__ cptr,
                            int* __restrict__ rcur, int* __restrict__ ccur,
                            int* __restrict__ rcols, int* __restrict__ crows,
                            const float* __restrict__ ck, const float* __restrict__ fv,
                            const float* __restrict__ cs,
                            float* __restrict__ rv0, float* __restrict__ rv1, float* __restrict__ rv2,
                            float* __restrict__ cv0, float* __restrict__ cv1, float* __restrict__ cv2) {
    int e = blockIdx.x * blockDim.x + threadIdx.x;
    if (e < N_EDGES) {
        int r = iclamp(er[e], 0, N_USERS - 1), c = iclamp(ec[e], 0, N_POIS - 1);
        float v0 = ck[e], v1 = fv[e], v2 = cs[e];
        int pr = iclamp(rptr[r] + atomicAdd(&rcur[r], 1), 0, N_EDGES - 1);
        rcols[pr] = c; rv0[pr] = v0; rv1[pr] = v1; rv2[pr] = v2;
        int pc = iclamp(cptr[c] + atomicAdd(&ccur[c], 1), 0, N_EDGES - 1);
        crows[pc] = r; cv0[pc] = v0; cv1[pc] = v1; cv2[pc] = v2;
    }
}

// ---------------- SpMM: one wave per row; fp16 src gather; predicated tail batch ----------------
// raw_h (fp16) = A*src ; acc (fp32) = base + raw/||raw||
__global__ __launch_bounds__(256) void spmm_kernel(
        const int* __restrict__ ptr, const int* __restrict__ nbr,
        const float* __restrict__ vals,                 // CSR-ordered
        const unsigned short* __restrict__ src,         // fp16 [*,128]
        unsigned short* __restrict__ raw_h,             // fp16 out
        const float* __restrict__ base,                 // fp32 (may alias acc)
        float* __restrict__ acc, int nrows) {
    int wid = (blockIdx.x * blockDim.x + threadIdx.x) >> 6;
    int lane = threadIdx.x & 63;
    if (wid >= nrows) return;
    int beg = __builtin_amdgcn_readfirstlane(iclamp(ptr[wid], 0, N_EDGES));
    int end = __builtin_amdgcn_readfirstlane(iclamp(ptr[wid + 1], 0, N_EDGES));
    if (end < beg) end = beg;
    float ax = 0.f, ay = 0.f;
    int e = beg;
    int lo2 = lane * 2;
    for (; e + 8 <= end; e += 8) {
        int c0 = nbr[e + 0], c1 = nbr[e + 1], c2 = nbr[e + 2], c3 = nbr[e + 3];
        int c4 = nbr[e + 4], c5 = nbr[e + 5], c6 = nbr[e + 6], c7 = nbr[e + 7];
        float v0 = vals[e + 0], v1 = vals[e + 1], v2 = vals[e + 2], v3 = vals[e + 3];
        float v4 = vals[e + 4], v5 = vals[e + 5], v6 = vals[e + 6], v7 = vals[e + 7];
        float2 p0 = h2f2(*(const unsigned int*)(src + (size_t)c0 * DIM + lo2));
        float2 p1 = h2f2(*(const unsigned int*)(src + (size_t)c1 * DIM + lo2));
        float2 p2 = h2f2(*(const unsigned int*)(src + (size_t)c2 * DIM + lo2));
        float2 p3 = h2f2(*(const unsigned int*)(src + (size_t)c3 * DIM + lo2));
        float2 p4 = h2f2(*(const unsigned int*)(src + (size_t)c4 * DIM + lo2));
        float2 p5 = h2f2(*(const unsigned int*)(src + (size_t)c5 * DIM + lo2));
        float2 p6 = h2f2(*(const unsigned int*)(src + (size_t)c6 * DIM + lo2));
        float2 p7 = h2f2(*(const unsigned int*)(src + (size_t)c7 * DIM + lo2));
        ax = fmaf(v0, p0.x, fmaf(v1, p1.x, fmaf(v2, p2.x, fmaf(v3, p3.x, ax))));
        ax = fmaf(v4, p4.x, fmaf(v5, p5.x, fmaf(v6, p6.x, fmaf(v7, p7.x, ax))));
        ay = fmaf(v0, p0.y, fmaf(v1, p1.y, fmaf(v2, p2.y, fmaf(v3, p3.y, ay))));
        ay = fmaf(v4, p4.y, fmaf(v5, p5.y, fmaf(v6, p6.y, fmaf(v7, p7.y, ay))));
    }
    if (e < end) {
        // branchless predicated batch of up to 8 — all loads in flight before any FMA
        int last = end - 1;
        int e1 = e + 1 <= last ? e + 1 : last;
        int e2 = e + 2 <= last ? e + 2 : last;
        int e3 = e + 3 <= last ? e + 3 : last;
        int e4 = e + 4 <= last ? e + 4 : last;
        int e5 = e + 5 <= last ? e + 5 : last;
        int e6 = e + 6 <= last ? e + 6 : last;
        int e7 = e + 7 <= last ? e + 7 : last;
        int c0 = nbr[e], c1 = nbr[e1], c2 = nbr[e2], c3 = nbr[e3];
        int c4 = nbr[e4], c5 = nbr[e5], c6 = nbr[e6], c7 = nbr[e7];
        float v0 = vals[e];
        float v1 = (e + 1 < end) ? vals[e1] : 0.f;
        float v2 = (e + 2 < end) ? vals[e2] : 0.f;
        float v3 = (e + 3 < end) ? vals[e3] : 0.f;
        float v4 = (e + 4 < end) ? vals[e4] : 0.f;
        float v5 = (e + 5 < end) ? vals[e5] : 0.f;
        float v6 = (e + 6 < end) ? vals[e6] : 0.f;
        float v7 = (e + 7 < end) ? vals[e7] : 0.f;
        float2 p0 = h2f2(*(const unsigned int*)(src + (size_t)c0 * DIM + lo2));
        float2 p1 = h2f2(*(const unsigned int*)(src + (size_t)c1 * DIM + lo2));
        float2 p2 = h2f2(*(const unsigned int*)(src + (size_t)c2 * DIM + lo2));
        float2 p3 = h2f2(*(const unsigned int*)(src + (size_t)c3 * DIM + lo2));
        float2 p4 = h2f2(*(const unsigned int*)(src + (size_t)c4 * DIM + lo2));
        float2 p5 = h2f2(*(const unsigned int*)(src + (size_t)c5 * DIM + lo2));
        float2 p6 = h2f2(*(const unsigned int*)(src + (size_t)c6 * DIM + lo2));
        float2 p7 = h2f2(*(const unsigned int*)(src + (size_t)c7 * DIM + lo2));
        ax = fmaf(v0, p0.x, fmaf(v1, p1.x, fmaf(v2, p2.x, fmaf(v3, p3.x, ax))));
        ax = fmaf(v4, p4.x, fmaf(v5, p5.x, fmaf(v6, p6.x, fmaf(v7, p7.x, ax))));
        ay = fmaf(v0, p0.y, fmaf(v1, p1.y, fmaf(v2, p2.y, fmaf(v3, p3.y, ay))));
        ay = fmaf(v4, p4.y, fmaf(v5, p5.y, fmaf(v6, p6.y, fmaf(v7, p7.y, ay))));
    }
    float n2 = ax * ax + ay * ay;
    #pragma unroll
    for (int o = 32; o > 0; o >>= 1) n2 += __shfl_xor(n2, o, 64);
    float inv = rsqrtf(fmaxf(n2, 1e-30f));
    *(unsigned int*)(raw_h + (size_t)wid * DIM + lo2) = f2h2(ax, ay);
    float2 bv = *(const float2*)(base + (size_t)wid * DIM + lo2);
    *(float2*)(acc + (size_t)wid * DIM + lo2) =
        make_float2(bv.x + ax * inv, bv.y + ay * inv);
}

// ---------------- out = A[Mx128] @ W^T ; A-tile in LDS ----------------
// accum_h: optional fp16 mirror of the final accum (written on last channel)
__global__ __launch_bounds__(256) void gemm_aw_kernel(
        const float* __restrict__ A, const float* __restrict__ W,
        float* __restrict__ store, float* __restrict__ accum,
        _Float16* __restrict__ accum_h,
        const float* __restrict__ fw3, int fsel, int first, int M) {
    __shared__ float Al[32 * 128];                 // 16 KB
    int i0 = blockIdx.x * 32;
    const float4* Ag = (const float4*)(A + (size_t)i0 * DIM);
    float4* Al4 = (float4*)Al;
    for (int qi = threadIdx.x; qi < 1024; qi += 256) Al4[qi] = Ag[qi];
    __syncthreads();
    float coef = accum ? softmax3(fw3, fsel) : 0.f;
    int j2 = threadIdx.x & 63;
    int rg = threadIdx.x >> 6;
    const float4* W0 = (const float4*)(W + (size_t)j2 * DIM);
    const float4* W1 = (const float4*)(W + (size_t)(j2 + 64) * DIM);
    float acc0[8], acc1[8];
    #pragma unroll
    for (int m = 0; m < 8; m++) { acc0[m] = 0.f; acc1[m] = 0.f; }
    for (int kq = 0; kq < 32; kq++) {
        float4 w0 = W0[kq];
        float4 w1 = W1[kq];
        #pragma unroll
        for (int m = 0; m < 8; m++) {
            float4 a = Al4[(rg + 4 * m) * 32 + kq];
            acc0[m] = fmaf(a.x, w0.x, acc0[m]); acc0[m] = fmaf(a.y, w0.y, acc0[m]);
            acc0[m] = fmaf(a.z, w0.z, acc0[m]); acc0[m] = fmaf(a.w, w0.w, acc0[m]);
            acc1[m] = fmaf(a.x, w1.x, acc1[m]); acc1[m] = fmaf(a.y, w1.y, acc1[m]);
            acc1[m] = fmaf(a.z, w1.z, acc1[m]); acc1[m] = fmaf(a.w, w1.w, acc1[m]);
        }
    }
    #pragma unroll
    for (int m = 0; m < 8; m++) {
        int i = i0 + rg + 4 * m;
        if (i >= M) continue;
        size_t o0 = (size_t)i * DIM + j2;
        size_t o1 = o0 + 64;
        if (store) { store[o0] = acc0[m]; store[o1] = acc1[m]; }
        if (accum) {
            float p0 = first ? 0.f : accum[o0];
            float p1 = first ? 0.f : accum[o1];
            float n0 = p0 + coef * acc0[m];
            float n1 = p1 + coef * acc1[m];
            accum[o0] = n0;
            accum[o1] = n1;
            if (accum_h) {
                accum_h[o0] = (_Float16)n0;
                accum_h[o1] = (_Float16)n1;
            }
        }
    }
}

// ---------------- 256 selected rows of uf = su @ Wu^T ----------------
__global__ void ufsel_kernel(const float* __restrict__ su, const float* __restrict__ W,
                             const int* __restrict__ uidx, float* __restrict__ outsel) {
    int b = blockIdx.x, j = threadIdx.x;  // block 128
    __shared__ float ar[128];
    int u = iclamp(uidx[b], 0, N_USERS - 1);
    ar[j] = su[(size_t)u * DIM + j];
    __syncthreads();
    const float4* Wr = (const float4*)(W + (size_t)j * DIM);
    float acc = 0.f;
    #pragma unroll 8
    for (int q = 0; q < 32; q++) {
        float4 wq = Wr[q];
        acc = fmaf(ar[4 * q + 0], wq.x, acc);
        acc = fmaf(ar[4 * q + 1], wq.y, acc);
        acc = fmaf(ar[4 * q + 2], wq.z, acc);
        acc = fmaf(ar[4 * q + 3], wq.w, acc);
    }
    outsel[(size_t)b * DIM + j] = acc;
}

// ---------------- alt[b,j] (+)= wn_c * dot(uf_c[b], pf_c[poi]) ----------------
__global__ __launch_bounds__(256) void predict_kernel(
        const float* __restrict__ ufs, const float* __restrict__ pf,
        const int* __restrict__ pidx, const float* __restrict__ w3,
        int wsel, int first, float* __restrict__ alt) {
    int wid = (blockIdx.x * blockDim.x + threadIdx.x) >> 6;
    int lane = threadIdx.x & 63;
    if (wid >= BATCH * NPOS) return;
    int b = wid / NPOS;
    int poi = iclamp(pidx[wid], 0, N_POIS - 1);
    const float2 uv = *(const float2*)(ufs + (size_t)b * DIM + lane * 2);
    const float2 pv = *(const float2*)(pf + (size_t)poi * DIM + lane * 2);
    float s = uv.x * pv.x + uv.y * pv.y;
    #pragma unroll
    for (int o = 32; o > 0; o >>= 1) s += __shfl_xor(s, o, 64);
    if (lane == 0) {
        float coef = softmax3(w3, wsel);
        float prev = first ? 0.f : alt[wid];
        alt[wid] = prev + coef * s;
    }
}

// ---------------- BCE loss ----------------
__global__ void loss_kernel(const float* __restrict__ alt, const float* __restrict__ labels,
                            float* __restrict__ out) {
    __shared__ float red[256];
    float s = 0.f;
    for (int i = threadIdx.x; i < BATCH * NPOS; i += 256) {
        float x = alt[i], y = labels[i];
        s += fmaxf(x, 0.f) - x * y + log1pf(expf(-fabsf(x)));
    }
    red[threadIdx.x] = s;
    __syncthreads();
    for (int off = 128; off > 0; off >>= 1) {
        if (threadIdx.x < off) red[threadIdx.x] += red[threadIdx.x + off];
        __syncthreads();
    }
    if (threadIdx.x == 0) out[0] = red[0] / (float)(BATCH * NPOS);
}

// ---------------- bst_h[b][j] = id_feat[cur[b]] @ Ws^T + bias (fp16, row-major) ----------------
__global__ void bs_kernel(const float* __restrict__ idf, const float* __restrict__ Ws,
                          const float* __restrict__ bias, const int* __restrict__ uidx,
                          _Float16* __restrict__ bst_h) {
    int b = blockIdx.x, j = threadIdx.x;  // block 128
    __shared__ float ar[128];
    int u = iclamp(uidx[b], 0, N_USERS - 1);
    ar[j] = idf[(size_t)u * DIM + j];
    __syncthreads();
    const float4* Wr = (const float4*)(Ws + (size_t)j * DIM);
    float acc = 0.f;
    #pragma unroll 8
    for (int q = 0; q < 32; q++) {
        float4 wq = Wr[q];
        acc = fmaf(ar[4 * q + 0], wq.x, acc);
        acc = fmaf(ar[4 * q + 1], wq.y, acc);
        acc = fmaf(ar[4 * q + 2], wq.z, acc);
        acc = fmaf(ar[4 * q + 3], wq.w, acc);
    }
    bst_h[(size_t)b * DIM + j] = (_Float16)(acc + bias[j]);
}

__device__ __forceinline__ void topk_insert(float s, int u, float* ts, int* ti) {
    if (s > ts[TOPK - 1]) {
        #pragma unroll
        for (int j = TOPK - 1; j > 0; --j) {
            bool above = s > ts[j - 1];
            bool here = (!above) && (s > ts[j]);
            float nv = above ? ts[j - 1] : (here ? s : ts[j]);
            int ni = above ? ti[j - 1] : (here ? u : ti[j]);
            ts[j] = nv; ti[j] = ni;
        }
        if (s > ts[0]) { ts[0] = s; ti[0] = u; }
    }
}

// ---------------- MFMA uu scores + per-block top-20 ----------------
// uu[u,b] = idf[u,:] . bs[b,:]  via mfma_f32_16x16x32_f16:
//   A = idf tile [16 users x 32 k], B = bst [32 k x 16 batch]
//   frag: lane l -> A row (l&15), k = (l>>4)*8 + j  (16B contiguous in [row][128] fp16)
//   C:    lane l -> col (batch) = l&15, rows (users) = (l>>4)*4 + reg
// Each wave owns 16 batch cols (w*16..), iterates all chunk users in 16-row tiles.
// B-frags are loop-invariant -> kept in 16 VGPRs; NO uniform loads, no LDS in main loop.
__global__ __launch_bounds__(256) void score_topk_kernel(
        const _Float16* __restrict__ idf_h, const _Float16* __restrict__ bst_h,
        float* __restrict__ cand_s, int* __restrict__ cand_i) {
    __shared__ __align__(16) unsigned char smraw[30720];
    float* ms = (float*)smraw;                              // [20][256] 20 KB
    unsigned short* mi = (unsigned short*)(smraw + 20480);  // [20][256] 10 KB
    int cid = blockIdx.x, bg = blockIdx.y;
    int tid = threadIdx.x;
    int w = tid >> 6, l = tid & 63;
    int lg = l >> 4, lc = l & 15;
    // loop-invariant B fragments (this wave's 16 batch columns)
    const _Float16* bbase = bst_h + ((size_t)(bg * 64 + w * 16 + lc)) * DIM + lg * 8;
    f16x8 B0 = *(const f16x8*)(bbase + 0);
    f16x8 B1 = *(const f16x8*)(bbase + 32);
    f16x8 B2 = *(const f16x8*)(bbase + 64);
    f16x8 B3 = *(const f16x8*)(bbase + 96);
    float ts[TOPK]; int ti[TOPK];
    #pragma unroll
    for (int k = 0; k < TOPK; k++) { ts[k] = -3.0e38f; ti[k] = 0; }
    int lo = cid * CPT;
    int hi = lo + CPT; if (hi > N_USERS) hi = N_USERS;
    #pragma unroll 2
    for (int u0 = lo; u0 < hi; u0 += 16) {
        int ar = u0 + lc; if (ar > N_USERS - 1) ar = N_USERS - 1;
        const _Float16* abase = idf_h + (size_t)ar * DIM + lg * 8;
        f16x8 A0 = *(const f16x8*)(abase + 0);
        f16x8 A1 = *(const f16x8*)(abase + 32);
        f16x8 A2 = *(const f16x8*)(abase + 64);
        f16x8 A3 = *(const f16x8*)(abase + 96);
        f32x4 accA = {0.f, 0.f, 0.f, 0.f};
        f32x4 accB = {0.f, 0.f, 0.f, 0.f};
        accA = __builtin_amdgcn_mfma_f32_16x16x32_f16(A0, B0, accA, 0, 0, 0);
        accB = __builtin_amdgcn_mfma_f32_16x16x32_f16(A1, B1, accB, 0, 0, 0);
        accA = __builtin_amdgcn_mfma_f32_16x16x32_f16(A2, B2, accA, 0, 0, 0);
        accB = __builtin_amdgcn_mfma_f32_16x16x32_f16(A3, B3, accB, 0, 0, 0);
        int ub = u0 + lg * 4;
        #pragma unroll
        for (int r = 0; r < 4; r++) {
            float s = accA[r] + accB[r];
            int u = ub + r;
            if (u < hi) topk_insert(s, u, ts, ti);
        }
    }
    // dump per-thread sorted lists; per batch col the 4 lane-groups hold disjoint users
    #pragma unroll
    for (int k = 0; k < TOPK; k++) {
        ms[k * 256 + tid] = ts[k];
        mi[k * 256 + tid] = (unsigned short)ti[k];
    }
    __syncthreads();
    if (tid < 64) {
        int wm = tid >> 4, cm = tid & 15;
        int s0 = wm * 64 + cm;           // lane-group 0 of wave wm, batch col cm
        int s1 = s0 + 16, s2 = s0 + 32, s3 = s0 + 48;
        int p0 = 0, p1 = 0, p2 = 0, p3 = 0;
        size_t ob = ((size_t)cid * 256 + bg * 64 + wm * 16 + cm) * TOPK;
        for (int k = 0; k < TOPK; k++) {
            float h0 = ms[p0 * 256 + s0];
            float h1 = ms[p1 * 256 + s1];
            float h2 = ms[p2 * 256 + s2];
            float h3 = ms[p3 * 256 + s3];
            float best = h0; int which = 0;
            if (h1 > best) { best = h1; which = 1; }
            if (h2 > best) { best = h2; which = 2; }
            if (h3 > best) { best = h3; which = 3; }
            int idx;
            if (which == 0)      { idx = mi[p0 * 256 + s0]; p0++; }
            else if (which == 1) { idx = mi[p1 * 256 + s1]; p1++; }
            else if (which == 2) { idx = mi[p2 * 256 + s2]; p2++; }
            else                 { idx = mi[p3 * 256 + s3]; p3++; }
            cand_s[ob + k] = best;
            cand_i[ob + k] = idx;
        }
    }
}

// ---------------- global merge + softmax + weighted gather ----------------
__global__ void topk_merge_kernel(const float* __restrict__ cand_s, const int* __restrict__ cand_i,
                                  const float* __restrict__ guf,
                                  float* __restrict__ outp) {
    int b = blockIdx.x, t = threadIdx.x;  // block 128 (= NCHUNK)
    __shared__ float rs[NCHUNK]; __shared__ int ru[NCHUNK]; __shared__ int rt[NCHUNK];
    __shared__ float win_s[TOPK]; __shared__ int win_u[TOPK]; __shared__ float wk[TOPK];
    __shared__ int winner;
    int ptr = 0;
    size_t base = ((size_t)t * 256 + b) * TOPK;
    for (int k = 0; k < TOPK; k++) {
        rs[t] = (ptr < TOPK) ? cand_s[base + ptr] : -3.0e38f;
        ru[t] = (ptr < TOPK) ? cand_i[base + ptr] : 0;
        rt[t] = t;
        __syncthreads();
        for (int off = NCHUNK / 2; off > 0; off >>= 1) {
            if (t < off && rs[t + off] > rs[t]) {
                rs[t] = rs[t + off]; ru[t] = ru[t + off]; rt[t] = rt[t + off];
            }
            __syncthreads();
        }
        if (t == 0) { win_s[k] = rs[0]; win_u[k] = iclamp(ru[0], 0, N_USERS - 1); winner = rt[0]; }
        __syncthreads();
        if (t == winner) ptr++;
        __syncthreads();
    }
    if (t == 0) {
        float m = win_s[0], den = 0.f;
        for (int k = 0; k < TOPK; k++) { wk[k] = expf(win_s[k] - m); den += wk[k]; }
        float inv = 1.f / den;
        for (int k = 0; k < TOPK; k++) wk[k] *= inv;
    }
    __syncthreads();
    float acc = 0.f;
    #pragma unroll
    for (int k = 0; k < TOPK; k++)
        acc = fmaf(wk[k], guf[(size_t)win_u[k] * DIM + t], acc);
    outp[1 + (size_t)b * DIM + t] = acc;
}

extern "C" void kernel_launch(void* const* d_in, const int* in_sizes, int n_in,
                              void* d_out, int out_size, void* d_ws, size_t ws_size,
                              hipStream_t stream) {
    (void)in_sizes; (void)n_in; (void)out_size; (void)ws_size;
    const int*   er      = (const int*)d_in[0];
    const int*   ec      = (const int*)d_in[1];
    const float* click   = (const float*)d_in[2];
    const float* favor   = (const float*)d_in[3];
    const float* consume = (const float*)d_in[4];
    const float* uid     = (const float*)d_in[5];
    const float* pid     = (const float*)d_in[6];
    const int*   uidx    = (const int*)d_in[7];
    const int*   pidx    = (const int*)d_in[8];
    const float* labels  = (const float*)d_in[9];
    const float* guf     = (const float*)d_in[10];
    const float* w3      = (const float*)d_in[11];
    const float* fw3     = (const float*)d_in[12];
    const float* Wuc     = (const float*)d_in[13];
    const float* Wpc     = (const float*)d_in[14];
    const float* Wufv    = (const float*)d_in[15];
    const float* Wpfv    = (const float*)d_in[16];
    const float* Wuco    = (const float*)d_in[17];
    const float* Wpco    = (const float*)d_in[18];
    const float* Wss     = (const float*)d_in[19];
    const float* bias    = (const float*)d_in[20];
    float* outp = (float*)d_out;

    char* ws = (char*)d_ws;
    size_t off = 0;
    auto carve = [&](size_t bytes) -> void* {
        off = (off + 255) & ~(size_t)255;
        void* p = ws + off;
        off += bytes;
        return p;
    };
    // total ~84 MB (proven-safe range)
    float* ufs = (float*)carve(4ll * 3 * BATCH * DIM);
    float* alt = (float*)carve(4ll * BATCH * NPOS);
    float* bst = (float*)carve(4ll * DIM * BATCH);       // reused as fp16 bst_h
    int* rptr = (int*)carve(4 * (N_USERS + 1));
    int* cptr = (int*)carve(4 * (N_POIS + 1));
    int* cnts = (int*)carve(4 * (2 * (N_USERS + N_POIS)));
    int* rcnt = cnts;
    int* ccnt = cnts + N_USERS;
    int* rcur = ccnt + N_POIS;
    int* ccur = rcur + N_USERS;
    int* rcols = (int*)carve(4 * (size_t)N_EDGES);
    int* crows = (int*)carve(4 * (size_t)N_EDGES);
    float* rv[3]; float* cv[3];
    for (int c = 0; c < 3; c++) rv[c] = (float*)carve(4 * (size_t)N_EDGES);
    for (int c = 0; c < 3; c++) cv[c] = (float*)carve(4 * (size_t)N_EDGES);
    unsigned short* pid_h = (unsigned short*)carve(2ll * N_POIS * DIM);
    unsigned short* utr_h = (unsigned short*)carve(2ll * N_USERS * DIM);  // 10.24 MB; pf alias
    unsigned short* ptr_h = (unsigned short*)carve(2ll * N_POIS * DIM);
    float* su  = (float*)carve(4ll * N_USERS * DIM);   // cand alias
    float* sp  = (float*)carve(4ll * N_POIS * DIM);
    float* idf = (float*)carve(4ll * N_USERS * DIM);
    float* pf = (float*)utr_h;            // utr_h dead before pf written
    float* cand_s = su;                   // su dead before score_topk
    int*   cand_i = (int*)(su + (size_t)NCHUNK * BATCH * TOPK);
    // idf_h (10.24 MB fp16) aliases the CSR edge arrays (rcols..cv[2], ~16 MB),
    // which are dead after the last spmm of channel 2 — idf_h is written only
    // by the c==2 user gemm_aw, which runs after.
    _Float16* idf_h = (_Float16*)rcols;
    _Float16* bst_h = (_Float16*)bst;

    zero_kernel<<<(2 * (N_USERS + N_POIS) + 255) / 256, 256, 0, stream>>>(
        (unsigned int*)cnts, 2 * (N_USERS + N_POIS));
    cast_f16_kernel<<<(N_POIS * DIM / 2 + 255) / 256, 256, 0, stream>>>(pid, pid_h, N_POIS * DIM / 2);
    hist_kernel<<<(N_EDGES + 255) / 256, 256, 0, stream>>>(er, ec, rcnt, ccnt);
    scan_kernel<<<2, 256, 0, stream>>>(rcnt, rptr, ccnt, cptr);
    fill_kernel<<<(N_EDGES + 255) / 256, 256, 0, stream>>>(
        er, ec, rptr, cptr, rcur, ccur, rcols, crows,
        click, favor, consume, rv[0], rv[1], rv[2], cv[0], cv[1], cv[2]);

    struct Ch { const float* Wu; const float* Wp; int wsel; int fsel; };
    // wn (softmax over w[1,3]):  favor=0, click=1, consume=2
    // fwn (softmax over fw[3,1]): favor=0, consume=1, click=2
    Ch chs[3] = { { Wuc,  Wpc,  1, 2 },     // ch0 = click
                  { Wufv, Wpfv, 0, 0 },     // ch1 = favor
                  { Wuco, Wpco, 2, 1 } };   // ch2 = consume

    for (int c = 0; c < 3; c++) {
        // layer 1: u1 = A p0 ; su = uid + n(u1).  p1 = A^T u1 ; sp = pid + n(p1)
        spmm_kernel<<<N_USERS * 64 / 256, 256, 0, stream>>>(rptr, rcols, rv[c], pid_h, utr_h, uid, su, N_USERS);
        spmm_kernel<<<N_POIS * 64 / 256, 256, 0, stream>>>(cptr, crows, cv[c], utr_h, ptr_h, pid, sp, N_POIS);
        // layer 2
        spmm_kernel<<<N_USERS * 64 / 256, 256, 0, stream>>>(rptr, rcols, rv[c], ptr_h, utr_h, su, su, N_USERS);
        spmm_kernel<<<N_POIS * 64 / 256, 256, 0, stream>>>(cptr, crows, cv[c], utr_h, ptr_h, sp, sp, N_POIS);
        // idf (+)= fwn_c * (su @ Wu^T); on last channel also emit fp16 idf_h
        gemm_aw_kernel<<<N_USERS / 32, 256, 0, stream>>>(
            su, chs[c].Wu, nullptr, idf, (c == 2) ? idf_h : nullptr,
            fw3, chs[c].fsel, (c == 0) ? 1 : 0, N_USERS);
        ufsel_kernel<<<BATCH, 128, 0, stream>>>(su, chs[c].Wu, uidx, ufs + (size_t)c * BATCH * DIM);
        // pf = sp @ Wp^T  (pf aliases utr_h, dead after L2 poi hop)
        gemm_aw_kernel<<<N_POIS / 32, 256, 0, stream>>>(
            sp, chs[c].Wp, pf, nullptr, nullptr, fw3, 0, 0, N_POIS);
        predict_kernel<<<BATCH * NPOS * 64 / 256, 256, 0, stream>>>(
            ufs + (size_t)c * BATCH * DIM, pf, pidx, w3, chs[c].wsel, (c == 0) ? 1 : 0, alt);
    }

    loss_kernel<<<1, 256, 0, stream>>>(alt, labels, outp);
    bs_kernel<<<BATCH, 128, 0, stream>>>(idf, Wss, bias, uidx, bst_h);
    dim3 sg(NCHUNK, 4);
    score_topk_kernel<<<sg, 256, 0, stream>>>(idf_h, bst_h, cand_s, cand_i);
    topk_merge_kernel<<<BATCH, NCHUNK, 0, stream>>>(cand_s, cand_i, guf, outp);
}

// Round 3
// 968.012 us; speedup vs baseline: 1.1673x; 1.0036x over previous
//
#include <hip/hip_runtime.h>

#define N_USERS 40000
#define N_POIS  20000
#define DIM     128
#define N_EDGES 500000
#define BATCH   256
#define NPOS    100
#define TOPK    20
#define NCHUNK  128
#define CPT     313   // ceil(40000/128)

typedef _Float16 f16x8 __attribute__((ext_vector_type(8)));
typedef float f32x4 __attribute__((ext_vector_type(4)));

__device__ __forceinline__ int iclamp(int x, int lo, int hi) {
    return x < lo ? lo : (x > hi ? hi : x);
}
__device__ __forceinline__ float2 h2f2(unsigned int u) {
    union { unsigned int u32; _Float16 h[2]; } v; v.u32 = u;
    return make_float2((float)v.h[0], (float)v.h[1]);
}
__device__ __forceinline__ unsigned int f2h2(float x, float y) {
    union { unsigned int u32; _Float16 h[2]; } v;
    v.h[0] = (_Float16)x; v.h[1] = (_Float16)y; return v.u32;
}
__device__ __forceinline__ float softmax3(const float* p, int sel) {
    float a0 = p[0], a1 = p[1], a2 = p[2];
    float m = fmaxf(a0, fmaxf(a1, a2));
    float e0 = expf(a0 - m), e1 = expf(a1 - m), e2 = expf(a2 - m);
    float den = e0 + e1 + e2;
    float e = (sel == 0) ? e0 : ((sel == 1) ? e1 : e2);
    return e / den;
}
// pick channel value from packed edge {idx, v0, v1, v2}
__device__ __forceinline__ float pickv(int4 q, int ch) {
    return __int_as_float(ch == 0 ? q.y : (ch == 1 ? q.z : q.w));
}

// ---------------- zero init ----------------
__global__ void zero_kernel(unsigned int* __restrict__ p, int nwords) {
    int i = blockIdx.x * blockDim.x + threadIdx.x;
    if (i < nwords) p[i] = 0u;
}

// ---------------- fp32 -> fp16 cast ----------------
__global__ void cast_f16_kernel(const float* __restrict__ src, unsigned short* __restrict__ dst,
                                int n2) {
    int i = blockIdx.x * blockDim.x + threadIdx.x;
    if (i < n2) {
        float2 v = *(const float2*)(src + 2 * (size_t)i);
        *(unsigned int*)(dst + 2 * (size_t)i) = f2h2(v.x, v.y);
    }
}

// ---------------- CSR build ----------------
__global__ void hist_kernel(const int* __restrict__ er, const int* __restrict__ ec,
                            int* __restrict__ rcnt, int* __restrict__ ccnt) {
    int e = blockIdx.x * blockDim.x + threadIdx.x;
    if (e < N_EDGES) {
        atomicAdd(&rcnt[iclamp(er[e], 0, N_USERS - 1)], 1);
        atomicAdd(&ccnt[iclamp(ec[e], 0, N_POIS - 1)], 1);
    }
}

__global__ void scan_kernel(const int* __restrict__ rcnt, int* __restrict__ rptr,
                            const int* __restrict__ ccnt, int* __restrict__ cptr) {
    const int* cnt = blockIdx.x ? ccnt : rcnt;
    int* ptr = blockIdx.x ? cptr : rptr;
    int n = blockIdx.x ? N_POIS : N_USERS;
    __shared__ int part[256];
    __shared__ int pref[257];
    int C = (n + 255) / 256;
    int lo = threadIdx.x * C;
    int hi = lo + C; if (hi > n) hi = n;
    int s = 0;
    for (int i = lo; i < hi; i++) s += cnt[i];
    part[threadIdx.x] = s;
    __syncthreads();
    if (threadIdx.x == 0) {
        int r = 0;
        for (int i = 0; i < 256; i++) { pref[i] = r; r += part[i]; }
        pref[256] = r;
    }
    __syncthreads();
    int r = pref[threadIdx.x];
    for (int i = lo; i < hi; i++) { ptr[i] = r; r += cnt[i]; }
    if (threadIdx.x == 0) ptr[n] = pref[256];
}

// ---------------- AoS CSR fill: 2 x 16B scattered stores per edge (was 8 x 4B) ----------------
__global__ void fill_kernel(const int* __restrict__ er, const int* __restrict__ ec,
                            const int* __restrict__ rptr, const int* __restrict__ cptr,
                            int* __restrict__ rcur, int* __restrict__ ccur,
                            int4* __restrict__ rpack, int4* __restrict__ cpack,
                            const float* __restrict__ ck, const float* __restrict__ fv,
                            const float* __restrict__ cs) {
    int e = blockIdx.x * blockDim.x + threadIdx.x;
    if (e < N_EDGES) {
        int r = iclamp(er[e], 0, N_USERS - 1), c = iclamp(ec[e], 0, N_POIS - 1);
        int v0 = __float_as_int(ck[e]);
        int v1 = __float_as_int(fv[e]);
        int v2 = __float_as_int(cs[e]);
        int pr = iclamp(rptr[r] + atomicAdd(&rcur[r], 1), 0, N_EDGES - 1);
        rpack[pr] = make_int4(c, v0, v1, v2);
        int pc = iclamp(cptr[c] + atomicAdd(&ccur[c], 1), 0, N_EDGES - 1);
        cpack[pc] = make_int4(r, v0, v1, v2);
    }
}

// ---------------- SpMM: one wave per row; packed edges; fp16 src gather ----------------
// raw_h (fp16) = A*src ; acc (fp32) = base + raw/||raw||
__global__ __launch_bounds__(256) void spmm_kernel(
        const int* __restrict__ ptr, const int4* __restrict__ pack, int ch,
        const unsigned short* __restrict__ src,         // fp16 [*,128]
        unsigned short* __restrict__ raw_h,             // fp16 out
        const float* __restrict__ base,                 // fp32 (may alias acc)
        float* __restrict__ acc, int nrows) {
    int wid = (blockIdx.x * blockDim.x + threadIdx.x) >> 6;
    int lane = threadIdx.x & 63;
    if (wid >= nrows) return;
    int beg = __builtin_amdgcn_readfirstlane(iclamp(ptr[wid], 0, N_EDGES));
    int end = __builtin_amdgcn_readfirstlane(iclamp(ptr[wid + 1], 0, N_EDGES));
    if (end < beg) end = beg;
    float ax = 0.f, ay = 0.f;
    int e = beg;
    int lo2 = lane * 2;
    for (; e + 8 <= end; e += 8) {
        int4 q0 = pack[e + 0], q1 = pack[e + 1], q2 = pack[e + 2], q3 = pack[e + 3];
        int4 q4 = pack[e + 4], q5 = pack[e + 5], q6 = pack[e + 6], q7 = pack[e + 7];
        float v0 = pickv(q0, ch), v1 = pickv(q1, ch), v2 = pickv(q2, ch), v3 = pickv(q3, ch);
        float v4 = pickv(q4, ch), v5 = pickv(q5, ch), v6 = pickv(q6, ch), v7 = pickv(q7, ch);
        float2 p0 = h2f2(*(const unsigned int*)(src + (size_t)q0.x * DIM + lo2));
        float2 p1 = h2f2(*(const unsigned int*)(src + (size_t)q1.x * DIM + lo2));
        float2 p2 = h2f2(*(const unsigned int*)(src + (size_t)q2.x * DIM + lo2));
        float2 p3 = h2f2(*(const unsigned int*)(src + (size_t)q3.x * DIM + lo2));
        float2 p4 = h2f2(*(const unsigned int*)(src + (size_t)q4.x * DIM + lo2));
        float2 p5 = h2f2(*(const unsigned int*)(src + (size_t)q5.x * DIM + lo2));
        float2 p6 = h2f2(*(const unsigned int*)(src + (size_t)q6.x * DIM + lo2));
        float2 p7 = h2f2(*(const unsigned int*)(src + (size_t)q7.x * DIM + lo2));
        ax = fmaf(v0, p0.x, fmaf(v1, p1.x, fmaf(v2, p2.x, fmaf(v3, p3.x, ax))));
        ax = fmaf(v4, p4.x, fmaf(v5, p5.x, fmaf(v6, p6.x, fmaf(v7, p7.x, ax))));
        ay = fmaf(v0, p0.y, fmaf(v1, p1.y, fmaf(v2, p2.y, fmaf(v3, p3.y, ay))));
        ay = fmaf(v4, p4.y, fmaf(v5, p5.y, fmaf(v6, p6.y, fmaf(v7, p7.y, ay))));
    }
    if (e < end) {
        // branchless predicated batch of up to 8 — all loads in flight before any FMA
        int last = end - 1;
        int e1 = e + 1 <= last ? e + 1 : last;
        int e2 = e + 2 <= last ? e + 2 : last;
        int e3 = e + 3 <= last ? e + 3 : last;
        int e4 = e + 4 <= last ? e + 4 : last;
        int e5 = e + 5 <= last ? e + 5 : last;
        int e6 = e + 6 <= last ? e + 6 : last;
        int e7 = e + 7 <= last ? e + 7 : last;
        int4 q0 = pack[e], q1 = pack[e1], q2 = pack[e2], q3 = pack[e3];
        int4 q4 = pack[e4], q5 = pack[e5], q6 = pack[e6], q7 = pack[e7];
        float v0 = pickv(q0, ch);
        float v1 = (e + 1 < end) ? pickv(q1, ch) : 0.f;
        float v2 = (e + 2 < end) ? pickv(q2, ch) : 0.f;
        float v3 = (e + 3 < end) ? pickv(q3, ch) : 0.f;
        float v4 = (e + 4 < end) ? pickv(q4, ch) : 0.f;
        float v5 = (e + 5 < end) ? pickv(q5, ch) : 0.f;
        float v6 = (e + 6 < end) ? pickv(q6, ch) : 0.f;
        float v7 = (e + 7 < end) ? pickv(q7, ch) : 0.f;
        float2 p0 = h2f2(*(const unsigned int*)(src + (size_t)q0.x * DIM + lo2));
        float2 p1 = h2f2(*(const unsigned int*)(src + (size_t)q1.x * DIM + lo2));
        float2 p2 = h2f2(*(const unsigned int*)(src + (size_t)q2.x * DIM + lo2));
        float2 p3 = h2f2(*(const unsigned int*)(src + (size_t)q3.x * DIM + lo2));
        float2 p4 = h2f2(*(const unsigned int*)(src + (size_t)q4.x * DIM + lo2));
        float2 p5 = h2f2(*(const unsigned int*)(src + (size_t)q5.x * DIM + lo2));
        float2 p6 = h2f2(*(const unsigned int*)(src + (size_t)q6.x * DIM + lo2));
        float2 p7 = h2f2(*(const unsigned int*)(src + (size_t)q7.x * DIM + lo2));
        ax = fmaf(v0, p0.x, fmaf(v1, p1.x, fmaf(v2, p2.x, fmaf(v3, p3.x, ax))));
        ax = fmaf(v4, p4.x, fmaf(v5, p5.x, fmaf(v6, p6.x, fmaf(v7, p7.x, ax))));
        ay = fmaf(v0, p0.y, fmaf(v1, p1.y, fmaf(v2, p2.y, fmaf(v3, p3.y, ay))));
        ay = fmaf(v4, p4.y, fmaf(v5, p5.y, fmaf(v6, p6.y, fmaf(v7, p7.y, ay))));
    }
    float n2 = ax * ax + ay * ay;
    #pragma unroll
    for (int o = 32; o > 0; o >>= 1) n2 += __shfl_xor(n2, o, 64);
    float inv = rsqrtf(fmaxf(n2, 1e-30f));
    *(unsigned int*)(raw_h + (size_t)wid * DIM + lo2) = f2h2(ax, ay);
    float2 bv = *(const float2*)(base + (size_t)wid * DIM + lo2);
    *(float2*)(acc + (size_t)wid * DIM + lo2) =
        make_float2(bv.x + ax * inv, bv.y + ay * inv);
}

// ---------------- out = A[Mx128] @ W^T ; A-tile in LDS ----------------
// accum_h: optional fp16 mirror of the final accum (written on last channel)
__global__ __launch_bounds__(256) void gemm_aw_kernel(
        const float* __restrict__ A, const float* __restrict__ W,
        float* __restrict__ store, float* __restrict__ accum,
        _Float16* __restrict__ accum_h,
        const float* __restrict__ fw3, int fsel, int first, int M) {
    __shared__ float Al[32 * 128];                 // 16 KB
    int i0 = blockIdx.x * 32;
    const float4* Ag = (const float4*)(A + (size_t)i0 * DIM);
    float4* Al4 = (float4*)Al;
    for (int qi = threadIdx.x; qi < 1024; qi += 256) Al4[qi] = Ag[qi];
    __syncthreads();
    float coef = accum ? softmax3(fw3, fsel) : 0.f;
    int j2 = threadIdx.x & 63;
    int rg = threadIdx.x >> 6;
    const float4* W0 = (const float4*)(W + (size_t)j2 * DIM);
    const float4* W1 = (const float4*)(W + (size_t)(j2 + 64) * DIM);
    float acc0[8], acc1[8];
    #pragma unroll
    for (int m = 0; m < 8; m++) { acc0[m] = 0.f; acc1[m] = 0.f; }
    for (int kq = 0; kq < 32; kq++) {
        float4 w0 = W0[kq];
        float4 w1 = W1[kq];
        #pragma unroll
        for (int m = 0; m < 8; m++) {
            float4 a = Al4[(rg + 4 * m) * 32 + kq];
            acc0[m] = fmaf(a.x, w0.x, acc0[m]); acc0[m] = fmaf(a.y, w0.y, acc0[m]);
            acc0[m] = fmaf(a.z, w0.z, acc0[m]); acc0[m] = fmaf(a.w, w0.w, acc0[m]);
            acc1[m] = fmaf(a.x, w1.x, acc1[m]); acc1[m] = fmaf(a.y, w1.y, acc1[m]);
            acc1[m] = fmaf(a.z, w1.z, acc1[m]); acc1[m] = fmaf(a.w, w1.w, acc1[m]);
        }
    }
    #pragma unroll
    for (int m = 0; m < 8; m++) {
        int i = i0 + rg + 4 * m;
        if (i >= M) continue;
        size_t o0 = (size_t)i * DIM + j2;
        size_t o1 = o0 + 64;
        if (store) { store[o0] = acc0[m]; store[o1] = acc1[m]; }
        if (accum) {
            float p0 = first ? 0.f : accum[o0];
            float p1 = first ? 0.f : accum[o1];
            float n0 = p0 + coef * acc0[m];
            float n1 = p1 + coef * acc1[m];
            accum[o0] = n0;
            accum[o1] = n1;
            if (accum_h) {
                accum_h[o0] = (_Float16)n0;
                accum_h[o1] = (_Float16)n1;
            }
        }
    }
}

// ---------------- 256 selected rows of uf = su @ Wu^T ----------------
__global__ void ufsel_kernel(const float* __restrict__ su, const float* __restrict__ W,
                             const int* __restrict__ uidx, float* __restrict__ outsel) {
    int b = blockIdx.x, j = threadIdx.x;  // block 128
    __shared__ float ar[128];
    int u = iclamp(uidx[b], 0, N_USERS - 1);
    ar[j] = su[(size_t)u * DIM + j];
    __syncthreads();
    const float4* Wr = (const float4*)(W + (size_t)j * DIM);
    float acc = 0.f;
    #pragma unroll 8
    for (int q = 0; q < 32; q++) {
        float4 wq = Wr[q];
        acc = fmaf(ar[4 * q + 0], wq.x, acc);
        acc = fmaf(ar[4 * q + 1], wq.y, acc);
        acc = fmaf(ar[4 * q + 2], wq.z, acc);
        acc = fmaf(ar[4 * q + 3], wq.w, acc);
    }
    outsel[(size_t)b * DIM + j] = acc;
}

// ---------------- alt[b,j] (+)= wn_c * dot(uf_c[b], pf_c[poi]) ----------------
__global__ __launch_bounds__(256) void predict_kernel(
        const float* __restrict__ ufs, const float* __restrict__ pf,
        const int* __restrict__ pidx, const float* __restrict__ w3,
        int wsel, int first, float* __restrict__ alt) {
    int wid = (blockIdx.x * blockDim.x + threadIdx.x) >> 6;
    int lane = threadIdx.x & 63;
    if (wid >= BATCH * NPOS) return;
    int b = wid / NPOS;
    int poi = iclamp(pidx[wid], 0, N_POIS - 1);
    const float2 uv = *(const float2*)(ufs + (size_t)b * DIM + lane * 2);
    const float2 pv = *(const float2*)(pf + (size_t)poi * DIM + lane * 2);
    float s = uv.x * pv.x + uv.y * pv.y;
    #pragma unroll
    for (int o = 32; o > 0; o >>= 1) s += __shfl_xor(s, o, 64);
    if (lane == 0) {
        float coef = softmax3(w3, wsel);
        float prev = first ? 0.f : alt[wid];
        alt[wid] = prev + coef * s;
    }
}

// ---------------- BCE loss ----------------
__global__ void loss_kernel(const float* __restrict__ alt, const float* __restrict__ labels,
                            float* __restrict__ out) {
    __shared__ float red[256];
    float s = 0.f;
    for (int i = threadIdx.x; i < BATCH * NPOS; i += 256) {
        float x = alt[i], y = labels[i];
        s += fmaxf(x, 0.f) - x * y + log1pf(expf(-fabsf(x)));
    }
    red[threadIdx.x] = s;
    __syncthreads();
    for (int off = 128; off > 0; off >>= 1) {
        if (threadIdx.x < off) red[threadIdx.x] += red[threadIdx.x + off];
        __syncthreads();
    }
    if (threadIdx.x == 0) out[0] = red[0] / (float)(BATCH * NPOS);
}

// ---------------- bst_h[b][j] = id_feat[cur[b]] @ Ws^T + bias (fp16, row-major) ----------------
__global__ void bs_kernel(const float* __restrict__ idf, const float* __restrict__ Ws,
                          const float* __restrict__ bias, const int* __restrict__ uidx,
                          _Float16* __restrict__ bst_h) {
    int b = blockIdx.x, j = threadIdx.x;  // block 128
    __shared__ float ar[128];
    int u = iclamp(uidx[b], 0, N_USERS - 1);
    ar[j] = idf[(size_t)u * DIM + j];
    __syncthreads();
    const float4* Wr = (const float4*)(Ws + (size_t)j * DIM);
    float acc = 0.f;
    #pragma unroll 8
    for (int q = 0; q < 32; q++) {
        float4 wq = Wr[q];
        acc = fmaf(ar[4 * q + 0], wq.x, acc);
        acc = fmaf(ar[4 * q + 1], wq.y, acc);
        acc = fmaf(ar[4 * q + 2], wq.z, acc);
        acc = fmaf(ar[4 * q + 3], wq.w, acc);
    }
    bst_h[(size_t)b * DIM + j] = (_Float16)(acc + bias[j]);
}

__device__ __forceinline__ void topk_insert(float s, int u, float* ts, int* ti) {
    if (s > ts[TOPK - 1]) {
        #pragma unroll
        for (int j = TOPK - 1; j > 0; --j) {
            bool above = s > ts[j - 1];
            bool here = (!above) && (s > ts[j]);
            float nv = above ? ts[j - 1] : (here ? s : ts[j]);
            int ni = above ? ti[j - 1] : (here ? u : ti[j]);
            ts[j] = nv; ti[j] = ni;
        }
        if (s > ts[0]) { ts[0] = s; ti[0] = u; }
    }
}

// ---------------- MFMA uu scores + per-block top-20 ----------------
// uu[u,b] = idf[u,:] . bs[b,:]  via mfma_f32_16x16x32_f16:
//   A = idf tile [16 users x 32 k], B = bst [32 k x 16 batch]
//   frag: lane l -> A row (l&15), k = (l>>4)*8 + j  (16B contiguous in [row][128] fp16)
//   C:    lane l -> col (batch) = l&15, rows (users) = (l>>4)*4 + reg
// Each wave owns 16 batch cols (w*16..), iterates all chunk users in 16-row tiles.
// B-frags are loop-invariant -> kept in 16 VGPRs; NO uniform loads, no LDS in main loop.
__global__ __launch_bounds__(256) void score_topk_kernel(
        const _Float16* __restrict__ idf_h, const _Float16* __restrict__ bst_h,
        float* __restrict__ cand_s, int* __restrict__ cand_i) {
    __shared__ __align__(16) unsigned char smraw[30720];
    float* ms = (float*)smraw;                              // [20][256] 20 KB
    unsigned short* mi = (unsigned short*)(smraw + 20480);  // [20][256] 10 KB
    int cid = blockIdx.x, bg = blockIdx.y;
    int tid = threadIdx.x;
    int w = tid >> 6, l = tid & 63;
    int lg = l >> 4, lc = l & 15;
    // loop-invariant B fragments (this wave's 16 batch columns)
    const _Float16* bbase = bst_h + ((size_t)(bg * 64 + w * 16 + lc)) * DIM + lg * 8;
    f16x8 B0 = *(const f16x8*)(bbase + 0);
    f16x8 B1 = *(const f16x8*)(bbase + 32);
    f16x8 B2 = *(const f16x8*)(bbase + 64);
    f16x8 B3 = *(const f16x8*)(bbase + 96);
    float ts[TOPK]; int ti[TOPK];
    #pragma unroll
    for (int k = 0; k < TOPK; k++) { ts[k] = -3.0e38f; ti[k] = 0; }
    int lo = cid * CPT;
    int hi = lo + CPT; if (hi > N_USERS) hi = N_USERS;
    #pragma unroll 2
    for (int u0 = lo; u0 < hi; u0 += 16) {
        int ar = u0 + lc; if (ar > N_USERS - 1) ar = N_USERS - 1;
        const _Float16* abase = idf_h + (size_t)ar * DIM + lg * 8;
        f16x8 A0 = *(const f16x8*)(abase + 0);
        f16x8 A1 = *(const f16x8*)(abase + 32);
        f16x8 A2 = *(const f16x8*)(abase + 64);
        f16x8 A3 = *(const f16x8*)(abase + 96);
        f32x4 accA = {0.f, 0.f, 0.f, 0.f};
        f32x4 accB = {0.f, 0.f, 0.f, 0.f};
        accA = __builtin_amdgcn_mfma_f32_16x16x32_f16(A0, B0, accA, 0, 0, 0);
        accB = __builtin_amdgcn_mfma_f32_16x16x32_f16(A1, B1, accB, 0, 0, 0);
        accA = __builtin_amdgcn_mfma_f32_16x16x32_f16(A2, B2, accA, 0, 0, 0);
        accB = __builtin_amdgcn_mfma_f32_16x16x32_f16(A3, B3, accB, 0, 0, 0);
        int ub = u0 + lg * 4;
        #pragma unroll
        for (int r = 0; r < 4; r++) {
            float s = accA[r] + accB[r];
            int u = ub + r;
            if (u < hi) topk_insert(s, u, ts, ti);
        }
    }
    // dump per-thread sorted lists; per batch col the 4 lane-groups hold disjoint users
    #pragma unroll
    for (int k = 0; k < TOPK; k++) {
        ms[k * 256 + tid] = ts[k];
        mi[k * 256 + tid] = (unsigned short)ti[k];
    }
    __syncthreads();
    if (tid < 64) {
        int wm = tid >> 4, cm = tid & 15;
        int s0 = wm * 64 + cm;           // lane-group 0 of wave wm, batch col cm
        int s1 = s0 + 16, s2 = s0 + 32, s3 = s0 + 48;
        int p0 = 0, p1 = 0, p2 = 0, p3 = 0;
        size_t ob = ((size_t)cid * 256 + bg * 64 + wm * 16 + cm) * TOPK;
        for (int k = 0; k < TOPK; k++) {
            float h0 = ms[p0 * 256 + s0];
            float h1 = ms[p1 * 256 + s1];
            float h2 = ms[p2 * 256 + s2];
            float h3 = ms[p3 * 256 + s3];
            float best = h0; int which = 0;
            if (h1 > best) { best = h1; which = 1; }
            if (h2 > best) { best = h2; which = 2; }
            if (h3 > best) { best = h3; which = 3; }
            int idx;
            if (which == 0)      { idx = mi[p0 * 256 + s0]; p0++; }
            else if (which == 1) { idx = mi[p1 * 256 + s1]; p1++; }
            else if (which == 2) { idx = mi[p2 * 256 + s2]; p2++; }
            else                 { idx = mi[p3 * 256 + s3]; p3++; }
            cand_s[ob + k] = best;
            cand_i[ob + k] = idx;
        }
    }
}

// ---------------- global merge + softmax + weighted gather ----------------
__global__ void topk_merge_kernel(const float* __restrict__ cand_s, const int* __restrict__ cand_i,
                                  const float* __restrict__ guf,
                                  float* __restrict__ outp) {
    int b = blockIdx.x, t = threadIdx.x;  // block 128 (= NCHUNK)
    __shared__ float rs[NCHUNK]; __shared__ int ru[NCHUNK]; __shared__ int rt[NCHUNK];
    __shared__ float win_s[TOPK]; __shared__ int win_u[TOPK]; __shared__ float wk[TOPK];
    __shared__ int winner;
    int ptr = 0;
    size_t base = ((size_t)t * 256 + b) * TOPK;
    for (int k = 0; k < TOPK; k++) {
        rs[t] = (ptr < TOPK) ? cand_s[base + ptr] : -3.0e38f;
        ru[t] = (ptr < TOPK) ? cand_i[base + ptr] : 0;
        rt[t] = t;
        __syncthreads();
        for (int off = NCHUNK / 2; off > 0; off >>= 1) {
            if (t < off && rs[t + off] > rs[t]) {
                rs[t] = rs[t + off]; ru[t] = ru[t + off]; rt[t] = rt[t + off];
            }
            __syncthreads();
        }
        if (t == 0) { win_s[k] = rs[0]; win_u[k] = iclamp(ru[0], 0, N_USERS - 1); winner = rt[0]; }
        __syncthreads();
        if (t == winner) ptr++;
        __syncthreads();
    }
    if (t == 0) {
        float m = win_s[0], den = 0.f;
        for (int k = 0; k < TOPK; k++) { wk[k] = expf(win_s[k] - m); den += wk[k]; }
        float inv = 1.f / den;
        for (int k = 0; k < TOPK; k++) wk[k] *= inv;
    }
    __syncthreads();
    float acc = 0.f;
    #pragma unroll
    for (int k = 0; k < TOPK; k++)
        acc = fmaf(wk[k], guf[(size_t)win_u[k] * DIM + t], acc);
    outp[1 + (size_t)b * DIM + t] = acc;
}

extern "C" void kernel_launch(void* const* d_in, const int* in_sizes, int n_in,
                              void* d_out, int out_size, void* d_ws, size_t ws_size,
                              hipStream_t stream) {
    (void)in_sizes; (void)n_in; (void)out_size; (void)ws_size;
    const int*   er      = (const int*)d_in[0];
    const int*   ec      = (const int*)d_in[1];
    const float* click   = (const float*)d_in[2];
    const float* favor   = (const float*)d_in[3];
    const float* consume = (const float*)d_in[4];
    const float* uid     = (const float*)d_in[5];
    const float* pid     = (const float*)d_in[6];
    const int*   uidx    = (const int*)d_in[7];
    const int*   pidx    = (const int*)d_in[8];
    const float* labels  = (const float*)d_in[9];
    const float* guf     = (const float*)d_in[10];
    const float* w3      = (const float*)d_in[11];
    const float* fw3     = (const float*)d_in[12];
    const float* Wuc     = (const float*)d_in[13];
    const float* Wpc     = (const float*)d_in[14];
    const float* Wufv    = (const float*)d_in[15];
    const float* Wpfv    = (const float*)d_in[16];
    const float* Wuco    = (const float*)d_in[17];
    const float* Wpco    = (const float*)d_in[18];
    const float* Wss     = (const float*)d_in[19];
    const float* bias    = (const float*)d_in[20];
    float* outp = (float*)d_out;

    char* ws = (char*)d_ws;
    size_t off = 0;
    auto carve = [&](size_t bytes) -> void* {
        off = (off + 255) & ~(size_t)255;
        void* p = ws + off;
        off += bytes;
        return p;
    };
    // total ~84 MB (proven-safe range; AoS pack == old SoA footprint)
    float* ufs = (float*)carve(4ll * 3 * BATCH * DIM);
    float* alt = (float*)carve(4ll * BATCH * NPOS);
    float* bst = (float*)carve(4ll * DIM * BATCH);       // reused as fp16 bst_h
    int* rptr = (int*)carve(4 * (N_USERS + 1));
    int* cptr = (int*)carve(4 * (N_POIS + 1));
    int* cnts = (int*)carve(4 * (2 * (N_USERS + N_POIS)));
    int* rcnt = cnts;
    int* ccnt = cnts + N_USERS;
    int* rcur = ccnt + N_POIS;
    int* ccur = rcur + N_USERS;
    int4* rpack = (int4*)carve(16ll * N_EDGES);   // {col, v0, v1, v2}
    int4* cpack = (int4*)carve(16ll * N_EDGES);   // {row, v0, v1, v2}
    unsigned short* pid_h = (unsigned short*)carve(2ll * N_POIS * DIM);
    unsigned short* utr_h = (unsigned short*)carve(2ll * N_USERS * DIM);  // 10.24 MB; pf alias
    unsigned short* ptr_h = (unsigned short*)carve(2ll * N_POIS * DIM);
    float* su  = (float*)carve(4ll * N_USERS * DIM);   // cand alias
    float* sp  = (float*)carve(4ll * N_POIS * DIM);
    float* idf = (float*)carve(4ll * N_USERS * DIM);
    float* pf = (float*)utr_h;            // utr_h dead before pf written
    float* cand_s = su;                   // su dead before score_topk
    int*   cand_i = (int*)(su + (size_t)NCHUNK * BATCH * TOPK);
    // idf_h (10.24 MB fp16) aliases rpack+cpack (16 MB contiguous), dead after
    // the last spmm of channel 2 — idf_h is written only by the c==2 user
    // gemm_aw, which runs after the final cpack read (c==2 poi-L2 spmm).
    _Float16* idf_h = (_Float16*)rpack;
    _Float16* bst_h = (_Float16*)bst;

    zero_kernel<<<(2 * (N_USERS + N_POIS) + 255) / 256, 256, 0, stream>>>(
        (unsigned int*)cnts, 2 * (N_USERS + N_POIS));
    cast_f16_kernel<<<(N_POIS * DIM / 2 + 255) / 256, 256, 0, stream>>>(pid, pid_h, N_POIS * DIM / 2);
    hist_kernel<<<(N_EDGES + 255) / 256, 256, 0, stream>>>(er, ec, rcnt, ccnt);
    scan_kernel<<<2, 256, 0, stream>>>(rcnt, rptr, ccnt, cptr);
    fill_kernel<<<(N_EDGES + 255) / 256, 256, 0, stream>>>(
        er, ec, rptr, cptr, rcur, ccur, rpack, cpack, click, favor, consume);

    struct Ch { const float* Wu; const float* Wp; int wsel; int fsel; };
    // wn (softmax over w[1,3]):  favor=0, click=1, consume=2
    // fwn (softmax over fw[3,1]): favor=0, consume=1, click=2
    Ch chs[3] = { { Wuc,  Wpc,  1, 2 },     // ch0 = click
                  { Wufv, Wpfv, 0, 0 },     // ch1 = favor
                  { Wuco, Wpco, 2, 1 } };   // ch2 = consume

    for (int c = 0; c < 3; c++) {
        // layer 1: u1 = A p0 ; su = uid + n(u1).  p1 = A^T u1 ; sp = pid + n(p1)
        spmm_kernel<<<N_USERS * 64 / 256, 256, 0, stream>>>(rptr, rpack, c, pid_h, utr_h, uid, su, N_USERS);
        spmm_kernel<<<N_POIS * 64 / 256, 256, 0, stream>>>(cptr, cpack, c, utr_h, ptr_h, pid, sp, N_POIS);
        // layer 2
        spmm_kernel<<<N_USERS * 64 / 256, 256, 0, stream>>>(rptr, rpack, c, ptr_h, utr_h, su, su, N_USERS);
        spmm_kernel<<<N_POIS * 64 / 256, 256, 0, stream>>>(cptr, cpack, c, utr_h, ptr_h, sp, sp, N_POIS);
        // idf (+)= fwn_c * (su @ Wu^T); on last channel also emit fp16 idf_h
        gemm_aw_kernel<<<N_USERS / 32, 256, 0, stream>>>(
            su, chs[c].Wu, nullptr, idf, (c == 2) ? idf_h : nullptr,
            fw3, chs[c].fsel, (c == 0) ? 1 : 0, N_USERS);
        ufsel_kernel<<<BATCH, 128, 0, stream>>>(su, chs[c].Wu, uidx, ufs + (size_t)c * BATCH * DIM);
        // pf = sp @ Wp^T  (pf aliases utr_h, dead after L2 poi hop)
        gemm_aw_kernel<<<N_POIS / 32, 256, 0, stream>>>(
            sp, chs[c].Wp, pf, nullptr, nullptr, fw3, 0, 0, N_POIS);
        predict_kernel<<<BATCH * NPOS * 64 / 256, 256, 0, stream>>>(
            ufs + (size_t)c * BATCH * DIM, pf, pidx, w3, chs[c].wsel, (c == 0) ? 1 : 0, alt);
    }

    loss_kernel<<<1, 256, 0, stream>>>(alt, labels, outp);
    bs_kernel<<<BATCH, 128, 0, stream>>>(idf, Wss, bias, uidx, bst_h);
    dim3 sg(NCHUNK, 4);
    score_topk_kernel<<<sg, 256, 0, stream>>>(idf_h, bst_h, cand_s, cand_i);
    topk_merge_kernel<<<BATCH, NCHUNK, 0, stream>>>(cand_s, cand_i, guf, outp);
}

// Round 4
// 915.349 us; speedup vs baseline: 1.2344x; 1.0575x over previous
//
#include <hip/hip_runtime.h>

#define N_USERS 40000
#define N_POIS  20000
#define DIM     128
#define N_EDGES 500000
#define BATCH   256
#define NPOS    100
#define TOPK    20
#define NCHUNK  128
#define CPT     313   // ceil(40000/128)

typedef _Float16 f16x8 __attribute__((ext_vector_type(8)));
typedef float f32x4 __attribute__((ext_vector_type(4)));

__device__ __forceinline__ int iclamp(int x, int lo, int hi) {
    return x < lo ? lo : (x > hi ? hi : x);
}
__device__ __forceinline__ float2 h2f2(unsigned int u) {
    union { unsigned int u32; _Float16 h[2]; } v; v.u32 = u;
    return make_float2((float)v.h[0], (float)v.h[1]);
}
__device__ __forceinline__ unsigned int f2h2(float x, float y) {
    union { unsigned int u32; _Float16 h[2]; } v;
    v.h[0] = (_Float16)x; v.h[1] = (_Float16)y; return v.u32;
}
__device__ __forceinline__ float softmax3(const float* p, int sel) {
    float a0 = p[0], a1 = p[1], a2 = p[2];
    float m = fmaxf(a0, fmaxf(a1, a2));
    float e0 = expf(a0 - m), e1 = expf(a1 - m), e2 = expf(a2 - m);
    float den = e0 + e1 + e2;
    float e = (sel == 0) ? e0 : ((sel == 1) ? e1 : e2);
    return e / den;
}
// pick channel value from packed edge {idx, v0, v1, v2}
__device__ __forceinline__ float pickv(int4 q, int ch) {
    return __int_as_float(ch == 0 ? q.y : (ch == 1 ? q.z : q.w));
}

// ---------------- zero init ----------------
__global__ void zero_kernel(unsigned int* __restrict__ p, int nwords) {
    int i = blockIdx.x * blockDim.x + threadIdx.x;
    if (i < nwords) p[i] = 0u;
}

// ---------------- fp32 -> fp16 cast ----------------
__global__ void cast_f16_kernel(const float* __restrict__ src, unsigned short* __restrict__ dst,
                                int n2) {
    int i = blockIdx.x * blockDim.x + threadIdx.x;
    if (i < n2) {
        float2 v = *(const float2*)(src + 2 * (size_t)i);
        *(unsigned int*)(dst + 2 * (size_t)i) = f2h2(v.x, v.y);
    }
}

// ---------------- CSR build ----------------
__global__ void hist_kernel(const int* __restrict__ er, const int* __restrict__ ec,
                            int* __restrict__ rcnt, int* __restrict__ ccnt) {
    int e = blockIdx.x * blockDim.x + threadIdx.x;
    if (e < N_EDGES) {
        atomicAdd(&rcnt[iclamp(er[e], 0, N_USERS - 1)], 1);
        atomicAdd(&ccnt[iclamp(ec[e], 0, N_POIS - 1)], 1);
    }
}

__global__ void scan_kernel(const int* __restrict__ rcnt, int* __restrict__ rptr,
                            const int* __restrict__ ccnt, int* __restrict__ cptr) {
    const int* cnt = blockIdx.x ? ccnt : rcnt;
    int* ptr = blockIdx.x ? cptr : rptr;
    int n = blockIdx.x ? N_POIS : N_USERS;
    __shared__ int part[256];
    __shared__ int pref[257];
    int C = (n + 255) / 256;
    int lo = threadIdx.x * C;
    int hi = lo + C; if (hi > n) hi = n;
    int s = 0;
    for (int i = lo; i < hi; i++) s += cnt[i];
    part[threadIdx.x] = s;
    __syncthreads();
    if (threadIdx.x == 0) {
        int r = 0;
        for (int i = 0; i < 256; i++) { pref[i] = r; r += part[i]; }
        pref[256] = r;
    }
    __syncthreads();
    int r = pref[threadIdx.x];
    for (int i = lo; i < hi; i++) { ptr[i] = r; r += cnt[i]; }
    if (threadIdx.x == 0) ptr[n] = pref[256];
}

// ---------------- AoS CSR fill: 4 edges/thread for MLP; 2 x 16B stores per edge ----------------
__global__ void fill_kernel(const int* __restrict__ er, const int* __restrict__ ec,
                            const int* __restrict__ rptr, const int* __restrict__ cptr,
                            int* __restrict__ rcur, int* __restrict__ ccur,
                            int4* __restrict__ rpack, int4* __restrict__ cpack,
                            const float* __restrict__ ck, const float* __restrict__ fv,
                            const float* __restrict__ cs) {
    int e0 = 4 * (blockIdx.x * blockDim.x + threadIdx.x);
    if (e0 + 4 <= N_EDGES) {
        int4 r4 = *(const int4*)(er + e0);
        int4 c4 = *(const int4*)(ec + e0);
        float4 k4 = *(const float4*)(ck + e0);
        float4 f4 = *(const float4*)(fv + e0);
        float4 s4 = *(const float4*)(cs + e0);
        int rr[4] = { r4.x, r4.y, r4.z, r4.w };
        int cc[4] = { c4.x, c4.y, c4.z, c4.w };
        float kk[4] = { k4.x, k4.y, k4.z, k4.w };
        float ff[4] = { f4.x, f4.y, f4.z, f4.w };
        float ss[4] = { s4.x, s4.y, s4.z, s4.w };
        #pragma unroll
        for (int j = 0; j < 4; j++) {
            int r = iclamp(rr[j], 0, N_USERS - 1), c = iclamp(cc[j], 0, N_POIS - 1);
            int v0 = __float_as_int(kk[j]);
            int v1 = __float_as_int(ff[j]);
            int v2 = __float_as_int(ss[j]);
            int pr = iclamp(rptr[r] + atomicAdd(&rcur[r], 1), 0, N_EDGES - 1);
            rpack[pr] = make_int4(c, v0, v1, v2);
            int pc = iclamp(cptr[c] + atomicAdd(&ccur[c], 1), 0, N_EDGES - 1);
            cpack[pc] = make_int4(r, v0, v1, v2);
        }
    } else {
        for (int e = e0; e < N_EDGES; e++) {
            int r = iclamp(er[e], 0, N_USERS - 1), c = iclamp(ec[e], 0, N_POIS - 1);
            int v0 = __float_as_int(ck[e]);
            int v1 = __float_as_int(fv[e]);
            int v2 = __float_as_int(cs[e]);
            int pr = iclamp(rptr[r] + atomicAdd(&rcur[r], 1), 0, N_EDGES - 1);
            rpack[pr] = make_int4(c, v0, v1, v2);
            int pc = iclamp(cptr[c] + atomicAdd(&ccur[c], 1), 0, N_EDGES - 1);
            cpack[pc] = make_int4(r, v0, v1, v2);
        }
    }
}

// ---------------- SpMM: one wave per row; packed edges; fp16 src gather ----------------
// raw_h (fp16) = A*src ; acc (fp32) = base + raw/||raw||
__global__ __launch_bounds__(256) void spmm_kernel(
        const int* __restrict__ ptr, const int4* __restrict__ pack, int ch,
        const unsigned short* __restrict__ src,         // fp16 [*,128]
        unsigned short* __restrict__ raw_h,             // fp16 out
        const float* __restrict__ base,                 // fp32 (may alias acc)
        float* __restrict__ acc, int nrows) {
    int wid = (blockIdx.x * blockDim.x + threadIdx.x) >> 6;
    int lane = threadIdx.x & 63;
    if (wid >= nrows) return;
    int beg = __builtin_amdgcn_readfirstlane(iclamp(ptr[wid], 0, N_EDGES));
    int end = __builtin_amdgcn_readfirstlane(iclamp(ptr[wid + 1], 0, N_EDGES));
    if (end < beg) end = beg;
    float ax = 0.f, ay = 0.f;
    int e = beg;
    int lo2 = lane * 2;
    for (; e + 8 <= end; e += 8) {
        int4 q0 = pack[e + 0], q1 = pack[e + 1], q2 = pack[e + 2], q3 = pack[e + 3];
        int4 q4 = pack[e + 4], q5 = pack[e + 5], q6 = pack[e + 6], q7 = pack[e + 7];
        float v0 = pickv(q0, ch), v1 = pickv(q1, ch), v2 = pickv(q2, ch), v3 = pickv(q3, ch);
        float v4 = pickv(q4, ch), v5 = pickv(q5, ch), v6 = pickv(q6, ch), v7 = pickv(q7, ch);
        float2 p0 = h2f2(*(const unsigned int*)(src + (size_t)q0.x * DIM + lo2));
        float2 p1 = h2f2(*(const unsigned int*)(src + (size_t)q1.x * DIM + lo2));
        float2 p2 = h2f2(*(const unsigned int*)(src + (size_t)q2.x * DIM + lo2));
        float2 p3 = h2f2(*(const unsigned int*)(src + (size_t)q3.x * DIM + lo2));
        float2 p4 = h2f2(*(const unsigned int*)(src + (size_t)q4.x * DIM + lo2));
        float2 p5 = h2f2(*(const unsigned int*)(src + (size_t)q5.x * DIM + lo2));
        float2 p6 = h2f2(*(const unsigned int*)(src + (size_t)q6.x * DIM + lo2));
        float2 p7 = h2f2(*(const unsigned int*)(src + (size_t)q7.x * DIM + lo2));
        ax = fmaf(v0, p0.x, fmaf(v1, p1.x, fmaf(v2, p2.x, fmaf(v3, p3.x, ax))));
        ax = fmaf(v4, p4.x, fmaf(v5, p5.x, fmaf(v6, p6.x, fmaf(v7, p7.x, ax))));
        ay = fmaf(v0, p0.y, fmaf(v1, p1.y, fmaf(v2, p2.y, fmaf(v3, p3.y, ay))));
        ay = fmaf(v4, p4.y, fmaf(v5, p5.y, fmaf(v6, p6.y, fmaf(v7, p7.y, ay))));
    }
    if (e < end) {
        int last = end - 1;
        int e1 = e + 1 <= last ? e + 1 : last;
        int e2 = e + 2 <= last ? e + 2 : last;
        int e3 = e + 3 <= last ? e + 3 : last;
        int e4 = e + 4 <= last ? e + 4 : last;
        int e5 = e + 5 <= last ? e + 5 : last;
        int e6 = e + 6 <= last ? e + 6 : last;
        int e7 = e + 7 <= last ? e + 7 : last;
        int4 q0 = pack[e], q1 = pack[e1], q2 = pack[e2], q3 = pack[e3];
        int4 q4 = pack[e4], q5 = pack[e5], q6 = pack[e6], q7 = pack[e7];
        float v0 = pickv(q0, ch);
        float v1 = (e + 1 < end) ? pickv(q1, ch) : 0.f;
        float v2 = (e + 2 < end) ? pickv(q2, ch) : 0.f;
        float v3 = (e + 3 < end) ? pickv(q3, ch) : 0.f;
        float v4 = (e + 4 < end) ? pickv(q4, ch) : 0.f;
        float v5 = (e + 5 < end) ? pickv(q5, ch) : 0.f;
        float v6 = (e + 6 < end) ? pickv(q6, ch) : 0.f;
        float v7 = (e + 7 < end) ? pickv(q7, ch) : 0.f;
        float2 p0 = h2f2(*(const unsigned int*)(src + (size_t)q0.x * DIM + lo2));
        float2 p1 = h2f2(*(const unsigned int*)(src + (size_t)q1.x * DIM + lo2));
        float2 p2 = h2f2(*(const unsigned int*)(src + (size_t)q2.x * DIM + lo2));
        float2 p3 = h2f2(*(const unsigned int*)(src + (size_t)q3.x * DIM + lo2));
        float2 p4 = h2f2(*(const unsigned int*)(src + (size_t)q4.x * DIM + lo2));
        float2 p5 = h2f2(*(const unsigned int*)(src + (size_t)q5.x * DIM + lo2));
        float2 p6 = h2f2(*(const unsigned int*)(src + (size_t)q6.x * DIM + lo2));
        float2 p7 = h2f2(*(const unsigned int*)(src + (size_t)q7.x * DIM + lo2));
        ax = fmaf(v0, p0.x, fmaf(v1, p1.x, fmaf(v2, p2.x, fmaf(v3, p3.x, ax))));
        ax = fmaf(v4, p4.x, fmaf(v5, p5.x, fmaf(v6, p6.x, fmaf(v7, p7.x, ax))));
        ay = fmaf(v0, p0.y, fmaf(v1, p1.y, fmaf(v2, p2.y, fmaf(v3, p3.y, ay))));
        ay = fmaf(v4, p4.y, fmaf(v5, p5.y, fmaf(v6, p6.y, fmaf(v7, p7.y, ay))));
    }
    float n2 = ax * ax + ay * ay;
    #pragma unroll
    for (int o = 32; o > 0; o >>= 1) n2 += __shfl_xor(n2, o, 64);
    float inv = rsqrtf(fmaxf(n2, 1e-30f));
    *(unsigned int*)(raw_h + (size_t)wid * DIM + lo2) = f2h2(ax, ay);
    float2 bv = *(const float2*)(base + (size_t)wid * DIM + lo2);
    *(float2*)(acc + (size_t)wid * DIM + lo2) =
        make_float2(bv.x + ax * inv, bv.y + ay * inv);
}

// ---------------- fused 3-channel L1-user SpMM: shared gather, 3 raw outputs ----------------
__global__ __launch_bounds__(256) void spmm3_kernel(
        const int* __restrict__ ptr, const int4* __restrict__ pack,
        const unsigned short* __restrict__ src,     // pid_h (shared across channels)
        unsigned short* __restrict__ r0, unsigned short* __restrict__ r1,
        unsigned short* __restrict__ r2, int nrows) {
    int wid = (blockIdx.x * blockDim.x + threadIdx.x) >> 6;
    int lane = threadIdx.x & 63;
    if (wid >= nrows) return;
    int beg = __builtin_amdgcn_readfirstlane(iclamp(ptr[wid], 0, N_EDGES));
    int end = __builtin_amdgcn_readfirstlane(iclamp(ptr[wid + 1], 0, N_EDGES));
    if (end < beg) end = beg;
    float a0x = 0.f, a0y = 0.f, a1x = 0.f, a1y = 0.f, a2x = 0.f, a2y = 0.f;
    int e = beg;
    int lo2 = lane * 2;
    for (; e + 4 <= end; e += 4) {
        int4 q0 = pack[e + 0], q1 = pack[e + 1], q2 = pack[e + 2], q3 = pack[e + 3];
        float2 p0 = h2f2(*(const unsigned int*)(src + (size_t)q0.x * DIM + lo2));
        float2 p1 = h2f2(*(const unsigned int*)(src + (size_t)q1.x * DIM + lo2));
        float2 p2 = h2f2(*(const unsigned int*)(src + (size_t)q2.x * DIM + lo2));
        float2 p3 = h2f2(*(const unsigned int*)(src + (size_t)q3.x * DIM + lo2));
        a0x = fmaf(__int_as_float(q0.y), p0.x, fmaf(__int_as_float(q1.y), p1.x,
              fmaf(__int_as_float(q2.y), p2.x, fmaf(__int_as_float(q3.y), p3.x, a0x))));
        a0y = fmaf(__int_as_float(q0.y), p0.y, fmaf(__int_as_float(q1.y), p1.y,
              fmaf(__int_as_float(q2.y), p2.y, fmaf(__int_as_float(q3.y), p3.y, a0y))));
        a1x = fmaf(__int_as_float(q0.z), p0.x, fmaf(__int_as_float(q1.z), p1.x,
              fmaf(__int_as_float(q2.z), p2.x, fmaf(__int_as_float(q3.z), p3.x, a1x))));
        a1y = fmaf(__int_as_float(q0.z), p0.y, fmaf(__int_as_float(q1.z), p1.y,
              fmaf(__int_as_float(q2.z), p2.y, fmaf(__int_as_float(q3.z), p3.y, a1y))));
        a2x = fmaf(__int_as_float(q0.w), p0.x, fmaf(__int_as_float(q1.w), p1.x,
              fmaf(__int_as_float(q2.w), p2.x, fmaf(__int_as_float(q3.w), p3.x, a2x))));
        a2y = fmaf(__int_as_float(q0.w), p0.y, fmaf(__int_as_float(q1.w), p1.y,
              fmaf(__int_as_float(q2.w), p2.y, fmaf(__int_as_float(q3.w), p3.y, a2y))));
    }
    for (; e < end; e++) {
        int4 q = pack[e];
        float2 p = h2f2(*(const unsigned int*)(src + (size_t)q.x * DIM + lo2));
        a0x = fmaf(__int_as_float(q.y), p.x, a0x);
        a0y = fmaf(__int_as_float(q.y), p.y, a0y);
        a1x = fmaf(__int_as_float(q.z), p.x, a1x);
        a1y = fmaf(__int_as_float(q.z), p.y, a1y);
        a2x = fmaf(__int_as_float(q.w), p.x, a2x);
        a2y = fmaf(__int_as_float(q.w), p.y, a2y);
    }
    size_t o = (size_t)wid * DIM + lo2;
    *(unsigned int*)(r0 + o) = f2h2(a0x, a0y);
    *(unsigned int*)(r1 + o) = f2h2(a1x, a1y);
    *(unsigned int*)(r2 + o) = f2h2(a2x, a2y);
}

// ---------------- L2-user SpMM: su = uid + n(u1) + n(u2); u1raw overwritten with u2 ----------------
__global__ __launch_bounds__(256) void spmm_l2u_kernel(
        const int* __restrict__ ptr, const int4* __restrict__ pack, int ch,
        const unsigned short* __restrict__ src,     // ptr_h (p1 raw fp16)
        unsigned short* __restrict__ u1raw,         // in: u1 raw; out: u2 raw
        const float* __restrict__ uid,
        float* __restrict__ su, int nrows) {
    int wid = (blockIdx.x * blockDim.x + threadIdx.x) >> 6;
    int lane = threadIdx.x & 63;
    if (wid >= nrows) return;
    int beg = __builtin_amdgcn_readfirstlane(iclamp(ptr[wid], 0, N_EDGES));
    int end = __builtin_amdgcn_readfirstlane(iclamp(ptr[wid + 1], 0, N_EDGES));
    if (end < beg) end = beg;
    float ax = 0.f, ay = 0.f;
    int e = beg;
    int lo2 = lane * 2;
    for (; e + 8 <= end; e += 8) {
        int4 q0 = pack[e + 0], q1 = pack[e + 1], q2 = pack[e + 2], q3 = pack[e + 3];
        int4 q4 = pack[e + 4], q5 = pack[e + 5], q6 = pack[e + 6], q7 = pack[e + 7];
        float v0 = pickv(q0, ch), v1 = pickv(q1, ch), v2 = pickv(q2, ch), v3 = pickv(q3, ch);
        float v4 = pickv(q4, ch), v5 = pickv(q5, ch), v6 = pickv(q6, ch), v7 = pickv(q7, ch);
        float2 p0 = h2f2(*(const unsigned int*)(src + (size_t)q0.x * DIM + lo2));
        float2 p1 = h2f2(*(const unsigned int*)(src + (size_t)q1.x * DIM + lo2));
        float2 p2 = h2f2(*(const unsigned int*)(src + (size_t)q2.x * DIM + lo2));
        float2 p3 = h2f2(*(const unsigned int*)(src + (size_t)q3.x * DIM + lo2));
        float2 p4 = h2f2(*(const unsigned int*)(src + (size_t)q4.x * DIM + lo2));
        float2 p5 = h2f2(*(const unsigned int*)(src + (size_t)q5.x * DIM + lo2));
        float2 p6 = h2f2(*(const unsigned int*)(src + (size_t)q6.x * DIM + lo2));
        float2 p7 = h2f2(*(const unsigned int*)(src + (size_t)q7.x * DIM + lo2));
        ax = fmaf(v0, p0.x, fmaf(v1, p1.x, fmaf(v2, p2.x, fmaf(v3, p3.x, ax))));
        ax = fmaf(v4, p4.x, fmaf(v5, p5.x, fmaf(v6, p6.x, fmaf(v7, p7.x, ax))));
        ay = fmaf(v0, p0.y, fmaf(v1, p1.y, fmaf(v2, p2.y, fmaf(v3, p3.y, ay))));
        ay = fmaf(v4, p4.y, fmaf(v5, p5.y, fmaf(v6, p6.y, fmaf(v7, p7.y, ay))));
    }
    if (e < end) {
        int last = end - 1;
        int e1 = e + 1 <= last ? e + 1 : last;
        int e2 = e + 2 <= last ? e + 2 : last;
        int e3 = e + 3 <= last ? e + 3 : last;
        int e4 = e + 4 <= last ? e + 4 : last;
        int e5 = e + 5 <= last ? e + 5 : last;
        int e6 = e + 6 <= last ? e + 6 : last;
        int e7 = e + 7 <= last ? e + 7 : last;
        int4 q0 = pack[e], q1 = pack[e1], q2 = pack[e2], q3 = pack[e3];
        int4 q4 = pack[e4], q5 = pack[e5], q6 = pack[e6], q7 = pack[e7];
        float v0 = pickv(q0, ch);
        float v1 = (e + 1 < end) ? pickv(q1, ch) : 0.f;
        float v2 = (e + 2 < end) ? pickv(q2, ch) : 0.f;
        float v3 = (e + 3 < end) ? pickv(q3, ch) : 0.f;
        float v4 = (e + 4 < end) ? pickv(q4, ch) : 0.f;
        float v5 = (e + 5 < end) ? pickv(q5, ch) : 0.f;
        float v6 = (e + 6 < end) ? pickv(q6, ch) : 0.f;
        float v7 = (e + 7 < end) ? pickv(q7, ch) : 0.f;
        float2 p0 = h2f2(*(const unsigned int*)(src + (size_t)q0.x * DIM + lo2));
        float2 p1 = h2f2(*(const unsigned int*)(src + (size_t)q1.x * DIM + lo2));
        float2 p2 = h2f2(*(const unsigned int*)(src + (size_t)q2.x * DIM + lo2));
        float2 p3 = h2f2(*(const unsigned int*)(src + (size_t)q3.x * DIM + lo2));
        float2 p4 = h2f2(*(const unsigned int*)(src + (size_t)q4.x * DIM + lo2));
        float2 p5 = h2f2(*(const unsigned int*)(src + (size_t)q5.x * DIM + lo2));
        float2 p6 = h2f2(*(const unsigned int*)(src + (size_t)q6.x * DIM + lo2));
        float2 p7 = h2f2(*(const unsigned int*)(src + (size_t)q7.x * DIM + lo2));
        ax = fmaf(v0, p0.x, fmaf(v1, p1.x, fmaf(v2, p2.x, fmaf(v3, p3.x, ax))));
        ax = fmaf(v4, p4.x, fmaf(v5, p5.x, fmaf(v6, p6.x, fmaf(v7, p7.x, ax))));
        ay = fmaf(v0, p0.y, fmaf(v1, p1.y, fmaf(v2, p2.y, fmaf(v3, p3.y, ay))));
        ay = fmaf(v4, p4.y, fmaf(v5, p5.y, fmaf(v6, p6.y, fmaf(v7, p7.y, ay))));
    }
    size_t o = (size_t)wid * DIM + lo2;
    float2 u1 = h2f2(*(const unsigned int*)(u1raw + o));
    float n2a = ax * ax + ay * ay;        // u2
    float n2b = u1.x * u1.x + u1.y * u1.y; // u1
    #pragma unroll
    for (int oo = 32; oo > 0; oo >>= 1) {
        n2a += __shfl_xor(n2a, oo, 64);
        n2b += __shfl_xor(n2b, oo, 64);
    }
    float i2 = rsqrtf(fmaxf(n2a, 1e-30f));
    float i1 = rsqrtf(fmaxf(n2b, 1e-30f));
    *(unsigned int*)(u1raw + o) = f2h2(ax, ay);   // u2 raw (src for L2-poi)
    float2 bv = *(const float2*)(uid + o);
    *(float2*)(su + o) = make_float2(bv.x + u1.x * i1 + ax * i2,
                                     bv.y + u1.y * i1 + ay * i2);
}

// ---------------- out = A[Mx128] @ W^T ; A-tile in LDS ----------------
// accum_h: optional fp16 mirror of the final accum (written on last channel)
__global__ __launch_bounds__(256) void gemm_aw_kernel(
        const float* __restrict__ A, const float* __restrict__ W,
        float* __restrict__ store, float* __restrict__ accum,
        _Float16* __restrict__ accum_h,
        const float* __restrict__ fw3, int fsel, int first, int M) {
    __shared__ float Al[32 * 128];                 // 16 KB
    int i0 = blockIdx.x * 32;
    const float4* Ag = (const float4*)(A + (size_t)i0 * DIM);
    float4* Al4 = (float4*)Al;
    for (int qi = threadIdx.x; qi < 1024; qi += 256) Al4[qi] = Ag[qi];
    __syncthreads();
    float coef = accum ? softmax3(fw3, fsel) : 0.f;
    int j2 = threadIdx.x & 63;
    int rg = threadIdx.x >> 6;
    const float4* W0 = (const float4*)(W + (size_t)j2 * DIM);
    const float4* W1 = (const float4*)(W + (size_t)(j2 + 64) * DIM);
    float acc0[8], acc1[8];
    #pragma unroll
    for (int m = 0; m < 8; m++) { acc0[m] = 0.f; acc1[m] = 0.f; }
    for (int kq = 0; kq < 32; kq++) {
        float4 w0 = W0[kq];
        float4 w1 = W1[kq];
        #pragma unroll
        for (int m = 0; m < 8; m++) {
            float4 a = Al4[(rg + 4 * m) * 32 + kq];
            acc0[m] = fmaf(a.x, w0.x, acc0[m]); acc0[m] = fmaf(a.y, w0.y, acc0[m]);
            acc0[m] = fmaf(a.z, w0.z, acc0[m]); acc0[m] = fmaf(a.w, w0.w, acc0[m]);
            acc1[m] = fmaf(a.x, w1.x, acc1[m]); acc1[m] = fmaf(a.y, w1.y, acc1[m]);
            acc1[m] = fmaf(a.z, w1.z, acc1[m]); acc1[m] = fmaf(a.w, w1.w, acc1[m]);
        }
    }
    #pragma unroll
    for (int m = 0; m < 8; m++) {
        int i = i0 + rg + 4 * m;
        if (i >= M) continue;
        size_t o0 = (size_t)i * DIM + j2;
        size_t o1 = o0 + 64;
        if (store) { store[o0] = acc0[m]; store[o1] = acc1[m]; }
        if (accum) {
            float p0 = first ? 0.f : accum[o0];
            float p1 = first ? 0.f : accum[o1];
            float n0 = p0 + coef * acc0[m];
            float n1 = p1 + coef * acc1[m];
            accum[o0] = n0;
            accum[o1] = n1;
            if (accum_h) {
                accum_h[o0] = (_Float16)n0;
                accum_h[o1] = (_Float16)n1;
            }
        }
    }
}

// ---------------- 256 selected rows of uf = su @ Wu^T ----------------
__global__ void ufsel_kernel(const float* __restrict__ su, const float* __restrict__ W,
                             const int* __restrict__ uidx, float* __restrict__ outsel) {
    int b = blockIdx.x, j = threadIdx.x;  // block 128
    __shared__ float ar[128];
    int u = iclamp(uidx[b], 0, N_USERS - 1);
    ar[j] = su[(size_t)u * DIM + j];
    __syncthreads();
    const float4* Wr = (const float4*)(W + (size_t)j * DIM);
    float acc = 0.f;
    #pragma unroll 8
    for (int q = 0; q < 32; q++) {
        float4 wq = Wr[q];
        acc = fmaf(ar[4 * q + 0], wq.x, acc);
        acc = fmaf(ar[4 * q + 1], wq.y, acc);
        acc = fmaf(ar[4 * q + 2], wq.z, acc);
        acc = fmaf(ar[4 * q + 3], wq.w, acc);
    }
    outsel[(size_t)b * DIM + j] = acc;
}

// ---------------- alt[b,j] (+)= wn_c * dot(uf_c[b], pf_c[poi]) ----------------
__global__ __launch_bounds__(256) void predict_kernel(
        const float* __restrict__ ufs, const float* __restrict__ pf,
        const int* __restrict__ pidx, const float* __restrict__ w3,
        int wsel, int first, float* __restrict__ alt) {
    int wid = (blockIdx.x * blockDim.x + threadIdx.x) >> 6;
    int lane = threadIdx.x & 63;
    if (wid >= BATCH * NPOS) return;
    int b = wid / NPOS;
    int poi = iclamp(pidx[wid], 0, N_POIS - 1);
    const float2 uv = *(const float2*)(ufs + (size_t)b * DIM + lane * 2);
    const float2 pv = *(const float2*)(pf + (size_t)poi * DIM + lane * 2);
    float s = uv.x * pv.x + uv.y * pv.y;
    #pragma unroll
    for (int o = 32; o > 0; o >>= 1) s += __shfl_xor(s, o, 64);
    if (lane == 0) {
        float coef = softmax3(w3, wsel);
        float prev = first ? 0.f : alt[wid];
        alt[wid] = prev + coef * s;
    }
}

// ---------------- BCE loss ----------------
__global__ void loss_kernel(const float* __restrict__ alt, const float* __restrict__ labels,
                            float* __restrict__ out) {
    __shared__ float red[256];
    float s = 0.f;
    for (int i = threadIdx.x; i < BATCH * NPOS; i += 256) {
        float x = alt[i], y = labels[i];
        s += fmaxf(x, 0.f) - x * y + log1pf(expf(-fabsf(x)));
    }
    red[threadIdx.x] = s;
    __syncthreads();
    for (int off = 128; off > 0; off >>= 1) {
        if (threadIdx.x < off) red[threadIdx.x] += red[threadIdx.x + off];
        __syncthreads();
    }
    if (threadIdx.x == 0) out[0] = red[0] / (float)(BATCH * NPOS);
}

// ---------------- bst_h[b][j] = id_feat[cur[b]] @ Ws^T + bias (fp16, row-major) ----------------
__global__ void bs_kernel(const float* __restrict__ idf, const float* __restrict__ Ws,
                          const float* __restrict__ bias, const int* __restrict__ uidx,
                          _Float16* __restrict__ bst_h) {
    int b = blockIdx.x, j = threadIdx.x;  // block 128
    __shared__ float ar[128];
    int u = iclamp(uidx[b], 0, N_USERS - 1);
    ar[j] = idf[(size_t)u * DIM + j];
    __syncthreads();
    const float4* Wr = (const float4*)(Ws + (size_t)j * DIM);
    float acc = 0.f;
    #pragma unroll 8
    for (int q = 0; q < 32; q++) {
        float4 wq = Wr[q];
        acc = fmaf(ar[4 * q + 0], wq.x, acc);
        acc = fmaf(ar[4 * q + 1], wq.y, acc);
        acc = fmaf(ar[4 * q + 2], wq.z, acc);
        acc = fmaf(ar[4 * q + 3], wq.w, acc);
    }
    bst_h[(size_t)b * DIM + j] = (_Float16)(acc + bias[j]);
}

__device__ __forceinline__ void topk_insert(float s, int u, float* ts, int* ti) {
    if (s > ts[TOPK - 1]) {
        #pragma unroll
        for (int j = TOPK - 1; j > 0; --j) {
            bool above = s > ts[j - 1];
            bool here = (!above) && (s > ts[j]);
            float nv = above ? ts[j - 1] : (here ? s : ts[j]);
            int ni = above ? ti[j - 1] : (here ? u : ti[j]);
            ts[j] = nv; ti[j] = ni;
        }
        if (s > ts[0]) { ts[0] = s; ti[0] = u; }
    }
}

// ---------------- MFMA uu scores + per-block top-20 ----------------
__global__ __launch_bounds__(256) void score_topk_kernel(
        const _Float16* __restrict__ idf_h, const _Float16* __restrict__ bst_h,
        float* __restrict__ cand_s, int* __restrict__ cand_i) {
    __shared__ __align__(16) unsigned char smraw[30720];
    float* ms = (float*)smraw;                              // [20][256] 20 KB
    unsigned short* mi = (unsigned short*)(smraw + 20480);  // [20][256] 10 KB
    int cid = blockIdx.x, bg = blockIdx.y;
    int tid = threadIdx.x;
    int w = tid >> 6, l = tid & 63;
    int lg = l >> 4, lc = l & 15;
    const _Float16* bbase = bst_h + ((size_t)(bg * 64 + w * 16 + lc)) * DIM + lg * 8;
    f16x8 B0 = *(const f16x8*)(bbase + 0);
    f16x8 B1 = *(const f16x8*)(bbase + 32);
    f16x8 B2 = *(const f16x8*)(bbase + 64);
    f16x8 B3 = *(const f16x8*)(bbase + 96);
    float ts[TOPK]; int ti[TOPK];
    #pragma unroll
    for (int k = 0; k < TOPK; k++) { ts[k] = -3.0e38f; ti[k] = 0; }
    int lo = cid * CPT;
    int hi = lo + CPT; if (hi > N_USERS) hi = N_USERS;
    #pragma unroll 2
    for (int u0 = lo; u0 < hi; u0 += 16) {
        int ar = u0 + lc; if (ar > N_USERS - 1) ar = N_USERS - 1;
        const _Float16* abase = idf_h + (size_t)ar * DIM + lg * 8;
        f16x8 A0 = *(const f16x8*)(abase + 0);
        f16x8 A1 = *(const f16x8*)(abase + 32);
        f16x8 A2 = *(const f16x8*)(abase + 64);
        f16x8 A3 = *(const f16x8*)(abase + 96);
        f32x4 accA = {0.f, 0.f, 0.f, 0.f};
        f32x4 accB = {0.f, 0.f, 0.f, 0.f};
        accA = __builtin_amdgcn_mfma_f32_16x16x32_f16(A0, B0, accA, 0, 0, 0);
        accB = __builtin_amdgcn_mfma_f32_16x16x32_f16(A1, B1, accB, 0, 0, 0);
        accA = __builtin_amdgcn_mfma_f32_16x16x32_f16(A2, B2, accA, 0, 0, 0);
        accB = __builtin_amdgcn_mfma_f32_16x16x32_f16(A3, B3, accB, 0, 0, 0);
        int ub = u0 + lg * 4;
        #pragma unroll
        for (int r = 0; r < 4; r++) {
            float s = accA[r] + accB[r];
            int u = ub + r;
            if (u < hi) topk_insert(s, u, ts, ti);
        }
    }
    #pragma unroll
    for (int k = 0; k < TOPK; k++) {
        ms[k * 256 + tid] = ts[k];
        mi[k * 256 + tid] = (unsigned short)ti[k];
    }
    __syncthreads();
    if (tid < 64) {
        int wm = tid >> 4, cm = tid & 15;
        int s0 = wm * 64 + cm;
        int s1 = s0 + 16, s2 = s0 + 32, s3 = s0 + 48;
        int p0 = 0, p1 = 0, p2 = 0, p3 = 0;
        size_t ob = ((size_t)cid * 256 + bg * 64 + wm * 16 + cm) * TOPK;
        for (int k = 0; k < TOPK; k++) {
            float h0 = ms[p0 * 256 + s0];
            float h1 = ms[p1 * 256 + s1];
            float h2 = ms[p2 * 256 + s2];
            float h3 = ms[p3 * 256 + s3];
            float best = h0; int which = 0;
            if (h1 > best) { best = h1; which = 1; }
            if (h2 > best) { best = h2; which = 2; }
            if (h3 > best) { best = h3; which = 3; }
            int idx;
            if (which == 0)      { idx = mi[p0 * 256 + s0]; p0++; }
            else if (which == 1) { idx = mi[p1 * 256 + s1]; p1++; }
            else if (which == 2) { idx = mi[p2 * 256 + s2]; p2++; }
            else                 { idx = mi[p3 * 256 + s3]; p3++; }
            cand_s[ob + k] = best;
            cand_i[ob + k] = idx;
        }
    }
}

// ---------------- global merge + softmax + weighted gather ----------------
__global__ void topk_merge_kernel(const float* __restrict__ cand_s, const int* __restrict__ cand_i,
                                  const float* __restrict__ guf,
                                  float* __restrict__ outp) {
    int b = blockIdx.x, t = threadIdx.x;  // block 128 (= NCHUNK)
    __shared__ float rs[NCHUNK]; __shared__ int ru[NCHUNK]; __shared__ int rt[NCHUNK];
    __shared__ float win_s[TOPK]; __shared__ int win_u[TOPK]; __shared__ float wk[TOPK];
    __shared__ int winner;
    int ptr = 0;
    size_t base = ((size_t)t * 256 + b) * TOPK;
    for (int k = 0; k < TOPK; k++) {
        rs[t] = (ptr < TOPK) ? cand_s[base + ptr] : -3.0e38f;
        ru[t] = (ptr < TOPK) ? cand_i[base + ptr] : 0;
        rt[t] = t;
        __syncthreads();
        for (int off = NCHUNK / 2; off > 0; off >>= 1) {
            if (t < off && rs[t + off] > rs[t]) {
                rs[t] = rs[t + off]; ru[t] = ru[t + off]; rt[t] = rt[t + off];
            }
            __syncthreads();
        }
        if (t == 0) { win_s[k] = rs[0]; win_u[k] = iclamp(ru[0], 0, N_USERS - 1); winner = rt[0]; }
        __syncthreads();
        if (t == winner) ptr++;
        __syncthreads();
    }
    if (t == 0) {
        float m = win_s[0], den = 0.f;
        for (int k = 0; k < TOPK; k++) { wk[k] = expf(win_s[k] - m); den += wk[k]; }
        float inv = 1.f / den;
        for (int k = 0; k < TOPK; k++) wk[k] *= inv;
    }
    __syncthreads();
    float acc = 0.f;
    #pragma unroll
    for (int k = 0; k < TOPK; k++)
        acc = fmaf(wk[k], guf[(size_t)win_u[k] * DIM + t], acc);
    outp[1 + (size_t)b * DIM + t] = acc;
}

extern "C" void kernel_launch(void* const* d_in, const int* in_sizes, int n_in,
                              void* d_out, int out_size, void* d_ws, size_t ws_size,
                              hipStream_t stream) {
    (void)in_sizes; (void)n_in; (void)out_size;
    const int*   er      = (const int*)d_in[0];
    const int*   ec      = (const int*)d_in[1];
    const float* click   = (const float*)d_in[2];
    const float* favor   = (const float*)d_in[3];
    const float* consume = (const float*)d_in[4];
    const float* uid     = (const float*)d_in[5];
    const float* pid     = (const float*)d_in[6];
    const int*   uidx    = (const int*)d_in[7];
    const int*   pidx    = (const int*)d_in[8];
    const float* labels  = (const float*)d_in[9];
    const float* guf     = (const float*)d_in[10];
    const float* w3      = (const float*)d_in[11];
    const float* fw3     = (const float*)d_in[12];
    const float* Wuc     = (const float*)d_in[13];
    const float* Wpc     = (const float*)d_in[14];
    const float* Wufv    = (const float*)d_in[15];
    const float* Wpfv    = (const float*)d_in[16];
    const float* Wuco    = (const float*)d_in[17];
    const float* Wpco    = (const float*)d_in[18];
    const float* Wss     = (const float*)d_in[19];
    const float* bias    = (const float*)d_in[20];
    float* outp = (float*)d_out;

    char* ws = (char*)d_ws;
    size_t off = 0;
    auto carve = [&](size_t bytes) -> void* {
        off = (off + 255) & ~(size_t)255;
        void* p = ws + off;
        off += bytes;
        return p;
    };
    // base layout (~89 MB, proven safe)
    float* ufs = (float*)carve(4ll * 3 * BATCH * DIM);
    float* alt = (float*)carve(4ll * BATCH * NPOS);
    float* bst = (float*)carve(4ll * DIM * BATCH);       // reused as fp16 bst_h
    int* rptr = (int*)carve(4 * (N_USERS + 1));
    int* cptr = (int*)carve(4 * (N_POIS + 1));
    int* cnts = (int*)carve(4 * (2 * (N_USERS + N_POIS)));
    int* rcnt = cnts;
    int* ccnt = cnts + N_USERS;
    int* rcur = ccnt + N_POIS;
    int* ccur = rcur + N_USERS;
    int4* rpack = (int4*)carve(16ll * N_EDGES);   // {col, v0, v1, v2}
    int4* cpack = (int4*)carve(16ll * N_EDGES);   // {row, v0, v1, v2}
    unsigned short* pid_h = (unsigned short*)carve(2ll * N_POIS * DIM);
    unsigned short* utr0 = (unsigned short*)carve(2ll * N_USERS * DIM);  // 10.24 MB; pf alias
    unsigned short* ptr_h = (unsigned short*)carve(2ll * N_POIS * DIM);
    float* su  = (float*)carve(4ll * N_USERS * DIM);   // cand alias
    float* sp  = (float*)carve(4ll * N_POIS * DIM);
    float* idf = (float*)carve(4ll * N_USERS * DIM);
    float* pf = (float*)utr0;             // utr0 dead before pf written
    float* cand_s = su;                   // su dead before score_topk
    int*   cand_i = (int*)(su + (size_t)NCHUNK * BATCH * TOPK);
    _Float16* idf_h = (_Float16*)rpack;   // rpack dead after last L2-user spmm
    _Float16* bst_h = (_Float16*)bst;
    // extra carves for the channel-fused path (+20.5 MB) — only used if they fit
    unsigned short* utr1 = (unsigned short*)carve(2ll * N_USERS * DIM);
    unsigned short* utr2 = (unsigned short*)carve(2ll * N_USERS * DIM);
    bool fused = (off <= ws_size);

    zero_kernel<<<(2 * (N_USERS + N_POIS) + 255) / 256, 256, 0, stream>>>(
        (unsigned int*)cnts, 2 * (N_USERS + N_POIS));
    cast_f16_kernel<<<(N_POIS * DIM / 2 + 255) / 256, 256, 0, stream>>>(pid, pid_h, N_POIS * DIM / 2);
    hist_kernel<<<(N_EDGES + 255) / 256, 256, 0, stream>>>(er, ec, rcnt, ccnt);
    scan_kernel<<<2, 256, 0, stream>>>(rcnt, rptr, ccnt, cptr);
    fill_kernel<<<(N_EDGES / 4 + 255) / 256, 256, 0, stream>>>(
        er, ec, rptr, cptr, rcur, ccur, rpack, cpack, click, favor, consume);

    struct Ch { const float* Wu; const float* Wp; int wsel; int fsel; };
    // wn (softmax over w[1,3]):  favor=0, click=1, consume=2
    // fwn (softmax over fw[3,1]): favor=0, consume=1, click=2
    Ch chs[3] = { { Wuc,  Wpc,  1, 2 },     // ch0 = click
                  { Wufv, Wpfv, 0, 0 },     // ch1 = favor
                  { Wuco, Wpco, 2, 1 } };   // ch2 = consume

    if (fused) {
        // fused 3-channel L1-user hop: one shared pid_h gather, 3 raw outputs
        spmm3_kernel<<<N_USERS * 64 / 256, 256, 0, stream>>>(
            rptr, rpack, pid_h, utr0, utr1, utr2, N_USERS);
        for (int c = 0; c < 3; c++) {
            unsigned short* uc = (c == 0) ? utr0 : ((c == 1) ? utr1 : utr2);
            // L1 poi hop: p1 = A^T u1 ; sp = pid + n(p1)
            spmm_kernel<<<N_POIS * 64 / 256, 256, 0, stream>>>(cptr, cpack, c, uc, ptr_h, pid, sp, N_POIS);
            // L2 user hop: u2 = A p1 ; su = uid + n(u1) + n(u2) ; uc <- u2 raw
            spmm_l2u_kernel<<<N_USERS * 64 / 256, 256, 0, stream>>>(rptr, rpack, c, ptr_h, uc, uid, su, N_USERS);
            // L2 poi hop
            spmm_kernel<<<N_POIS * 64 / 256, 256, 0, stream>>>(cptr, cpack, c, uc, ptr_h, sp, sp, N_POIS);
            gemm_aw_kernel<<<N_USERS / 32, 256, 0, stream>>>(
                su, chs[c].Wu, nullptr, idf, (c == 2) ? idf_h : nullptr,
                fw3, chs[c].fsel, (c == 0) ? 1 : 0, N_USERS);
            ufsel_kernel<<<BATCH, 128, 0, stream>>>(su, chs[c].Wu, uidx, ufs + (size_t)c * BATCH * DIM);
            gemm_aw_kernel<<<N_POIS / 32, 256, 0, stream>>>(
                sp, chs[c].Wp, pf, nullptr, nullptr, fw3, 0, 0, N_POIS);
            predict_kernel<<<BATCH * NPOS * 64 / 256, 256, 0, stream>>>(
                ufs + (size_t)c * BATCH * DIM, pf, pidx, w3, chs[c].wsel, (c == 0) ? 1 : 0, alt);
        }
    } else {
        // proven fallback: per-channel schedule, single utr0 buffer
        for (int c = 0; c < 3; c++) {
            spmm_kernel<<<N_USERS * 64 / 256, 256, 0, stream>>>(rptr, rpack, c, pid_h, utr0, uid, su, N_USERS);
            spmm_kernel<<<N_POIS * 64 / 256, 256, 0, stream>>>(cptr, cpack, c, utr0, ptr_h, pid, sp, N_POIS);
            spmm_kernel<<<N_USERS * 64 / 256, 256, 0, stream>>>(rptr, rpack, c, ptr_h, utr0, su, su, N_USERS);
            spmm_kernel<<<N_POIS * 64 / 256, 256, 0, stream>>>(cptr, cpack, c, utr0, ptr_h, sp, sp, N_POIS);
            gemm_aw_kernel<<<N_USERS / 32, 256, 0, stream>>>(
                su, chs[c].Wu, nullptr, idf, (c == 2) ? idf_h : nullptr,
                fw3, chs[c].fsel, (c == 0) ? 1 : 0, N_USERS);
            ufsel_kernel<<<BATCH, 128, 0, stream>>>(su, chs[c].Wu, uidx, ufs + (size_t)c * BATCH * DIM);
            gemm_aw_kernel<<<N_POIS / 32, 256, 0, stream>>>(
                sp, chs[c].Wp, pf, nullptr, nullptr, fw3, 0, 0, N_POIS);
            predict_kernel<<<BATCH * NPOS * 64 / 256, 256, 0, stream>>>(
                ufs + (size_t)c * BATCH * DIM, pf, pidx, w3, chs[c].wsel, (c == 0) ? 1 : 0, alt);
        }
    }

    loss_kernel<<<1, 256, 0, stream>>>(alt, labels, outp);
    bs_kernel<<<BATCH, 128, 0, stream>>>(idf, Wss, bias, uidx, bst_h);
    dim3 sg(NCHUNK, 4);
    score_topk_kernel<<<sg, 256, 0, stream>>>(idf_h, bst_h, cand_s, cand_i);
    topk_merge_kernel<<<BATCH, NCHUNK, 0, stream>>>(cand_s, cand_i, guf, outp);
}

// Round 5
// 809.957 us; speedup vs baseline: 1.3950x; 1.1301x over previous
//
#include <hip/hip_runtime.h>

#define N_USERS 40000
#define N_POIS  20000
#define DIM     128
#define N_EDGES 500000
#define BATCH   256
#define NPOS    100
#define TOPK    20
#define NCHUNK  128
#define CPT     313   // ceil(40000/128)
#define SCHUNK  1024  // scan chunk (256 thr x 4)
#define RCH     40    // ceil(40000/1024)
#define CCH     20    // ceil(20000/1024)
#define LOSS_BLOCKS 25  // 25600/1024

typedef _Float16 f16x8 __attribute__((ext_vector_type(8)));
typedef float f32x4 __attribute__((ext_vector_type(4)));

__device__ __forceinline__ int iclamp(int x, int lo, int hi) {
    return x < lo ? lo : (x > hi ? hi : x);
}
__device__ __forceinline__ float2 h2f2(unsigned int u) {
    union { unsigned int u32; _Float16 h[2]; } v; v.u32 = u;
    return make_float2((float)v.h[0], (float)v.h[1]);
}
__device__ __forceinline__ unsigned int f2h2(float x, float y) {
    union { unsigned int u32; _Float16 h[2]; } v;
    v.h[0] = (_Float16)x; v.h[1] = (_Float16)y; return v.u32;
}
__device__ __forceinline__ float softmax3(const float* p, int sel) {
    float a0 = p[0], a1 = p[1], a2 = p[2];
    float m = fmaxf(a0, fmaxf(a1, a2));
    float e0 = expf(a0 - m), e1 = expf(a1 - m), e2 = expf(a2 - m);
    float den = e0 + e1 + e2;
    float e = (sel == 0) ? e0 : ((sel == 1) ? e1 : e2);
    return e / den;
}
// pick channel value from packed edge {idx, v0, v1, v2}
__device__ __forceinline__ float pickv(int4 q, int ch) {
    return __int_as_float(ch == 0 ? q.y : (ch == 1 ? q.z : q.w));
}

// ---------------- zero init ----------------
__global__ void zero_kernel(unsigned int* __restrict__ p, int nwords) {
    int i = blockIdx.x * blockDim.x + threadIdx.x;
    if (i < nwords) p[i] = 0u;
}

// ---------------- fp32 -> fp16 cast ----------------
__global__ void cast_f16_kernel(const float* __restrict__ src, unsigned short* __restrict__ dst,
                                int n2) {
    int i = blockIdx.x * blockDim.x + threadIdx.x;
    if (i < n2) {
        float2 v = *(const float2*)(src + 2 * (size_t)i);
        *(unsigned int*)(dst + 2 * (size_t)i) = f2h2(v.x, v.y);
    }
}

// ---------------- CSR build ----------------
__global__ void hist_kernel(const int* __restrict__ er, const int* __restrict__ ec,
                            int* __restrict__ rcnt, int* __restrict__ ccnt) {
    int e = blockIdx.x * blockDim.x + threadIdx.x;
    if (e < N_EDGES) {
        atomicAdd(&rcnt[iclamp(er[e], 0, N_USERS - 1)], 1);
        atomicAdd(&ccnt[iclamp(ec[e], 0, N_POIS - 1)], 1);
    }
}

// ---------------- parallel prefix sum, stage 1: per-1024-chunk sums ----------------
__global__ void chunksum_kernel(const int* __restrict__ rcnt, const int* __restrict__ ccnt,
                                int* __restrict__ rsum, int* __restrict__ csum) {
    int side = blockIdx.y;
    const int* cnt = side ? ccnt : rcnt;
    int n = side ? N_POIS : N_USERS;
    int nch = side ? CCH : RCH;
    int b = blockIdx.x;
    if (b >= nch) return;
    int t = threadIdx.x;
    int i = b * SCHUNK + t * 4;
    int s = 0;
    if (i + 4 <= n) {
        int4 v = *(const int4*)(cnt + i);
        s = v.x + v.y + v.z + v.w;
    } else {
        for (int j = i; j < n; j++) s += cnt[j];
    }
    __shared__ int red[256];
    red[t] = s;
    __syncthreads();
    for (int o = 128; o > 0; o >>= 1) {
        if (t < o) red[t] += red[t + o];
        __syncthreads();
    }
    if (t == 0) (side ? csum : rsum)[b] = red[0];
}

// ---------------- stage 2: scan chunk sums (wave shfl), write totals ----------------
__global__ void chunkscan_kernel(const int* __restrict__ rsum, const int* __restrict__ csum,
                                 int* __restrict__ rbase, int* __restrict__ cbase,
                                 int* __restrict__ rptr, int* __restrict__ cptr) {
    int w = threadIdx.x >> 6, l = threadIdx.x & 63;  // block 128: wave0=users, wave1=pois
    const int* src = w ? csum : rsum;
    int* dst = w ? cbase : rbase;
    int nch = w ? CCH : RCH;
    int orig = (l < nch) ? src[l] : 0;
    int v = orig;
    #pragma unroll
    for (int o = 1; o < 64; o <<= 1) {
        int u = __shfl_up(v, o, 64);
        if (l >= o) v += u;
    }
    if (l < nch) dst[l] = v - orig;                 // exclusive base
    if (l == nch - 1) {
        if (w) cptr[N_POIS] = v; else rptr[N_USERS] = v;
    }
}

// ---------------- stage 3: block scan within chunk + chunk base ----------------
__global__ void scatterscan_kernel(const int* __restrict__ rcnt, const int* __restrict__ ccnt,
                                   const int* __restrict__ rbase, const int* __restrict__ cbase,
                                   int* __restrict__ rptr, int* __restrict__ cptr) {
    int side = blockIdx.y;
    const int* cnt = side ? ccnt : rcnt;
    const int* basea = side ? cbase : rbase;
    int* ptr = side ? cptr : rptr;
    int n = side ? N_POIS : N_USERS;
    int nch = side ? CCH : RCH;
    int b = blockIdx.x;
    if (b >= nch) return;
    int t = threadIdx.x;
    int i = b * SCHUNK + t * 4;
    int c0 = 0, c1 = 0, c2 = 0, c3 = 0;
    if (i + 4 <= n) {
        int4 v = *(const int4*)(cnt + i);
        c0 = v.x; c1 = v.y; c2 = v.z; c3 = v.w;
    } else {
        if (i + 0 < n) c0 = cnt[i + 0];
        if (i + 1 < n) c1 = cnt[i + 1];
        if (i + 2 < n) c2 = cnt[i + 2];
    }
    int tsum = c0 + c1 + c2 + c3;
    int l = t & 63, w = t >> 6;
    int v = tsum;
    #pragma unroll
    for (int o = 1; o < 64; o <<= 1) {
        int u = __shfl_up(v, o, 64);
        if (l >= o) v += u;
    }
    __shared__ int wsum[4];
    if (l == 63) wsum[w] = v;
    __syncthreads();
    int wbase = 0;
    for (int k = 0; k < w; k++) wbase += wsum[k];
    int ex = v - tsum + wbase + basea[b];
    if (i + 4 <= n) {
        *(int4*)(ptr + i) = make_int4(ex, ex + c0, ex + c0 + c1, ex + c0 + c1 + c2);
    } else {
        if (i + 0 < n) ptr[i + 0] = ex;
        if (i + 1 < n) ptr[i + 1] = ex + c0;
        if (i + 2 < n) ptr[i + 2] = ex + c0 + c1;
    }
}

// ---------------- AoS CSR fill: 4 edges/thread for MLP; 2 x 16B stores per edge ----------------
__global__ void fill_kernel(const int* __restrict__ er, const int* __restrict__ ec,
                            const int* __restrict__ rptr, const int* __restrict__ cptr,
                            int* __restrict__ rcur, int* __restrict__ ccur,
                            int4* __restrict__ rpack, int4* __restrict__ cpack,
                            const float* __restrict__ ck, const float* __restrict__ fv,
                            const float* __restrict__ cs) {
    int e0 = 4 * (blockIdx.x * blockDim.x + threadIdx.x);
    if (e0 + 4 <= N_EDGES) {
        int4 r4 = *(const int4*)(er + e0);
        int4 c4 = *(const int4*)(ec + e0);
        float4 k4 = *(const float4*)(ck + e0);
        float4 f4 = *(const float4*)(fv + e0);
        float4 s4 = *(const float4*)(cs + e0);
        int rr[4] = { r4.x, r4.y, r4.z, r4.w };
        int cc[4] = { c4.x, c4.y, c4.z, c4.w };
        float kk[4] = { k4.x, k4.y, k4.z, k4.w };
        float ff[4] = { f4.x, f4.y, f4.z, f4.w };
        float ss[4] = { s4.x, s4.y, s4.z, s4.w };
        #pragma unroll
        for (int j = 0; j < 4; j++) {
            int r = iclamp(rr[j], 0, N_USERS - 1), c = iclamp(cc[j], 0, N_POIS - 1);
            int v0 = __float_as_int(kk[j]);
            int v1 = __float_as_int(ff[j]);
            int v2 = __float_as_int(ss[j]);
            int pr = iclamp(rptr[r] + atomicAdd(&rcur[r], 1), 0, N_EDGES - 1);
            rpack[pr] = make_int4(c, v0, v1, v2);
            int pc = iclamp(cptr[c] + atomicAdd(&ccur[c], 1), 0, N_EDGES - 1);
            cpack[pc] = make_int4(r, v0, v1, v2);
        }
    } else {
        for (int e = e0; e < N_EDGES; e++) {
            int r = iclamp(er[e], 0, N_USERS - 1), c = iclamp(ec[e], 0, N_POIS - 1);
            int v0 = __float_as_int(ck[e]);
            int v1 = __float_as_int(fv[e]);
            int v2 = __float_as_int(cs[e]);
            int pr = iclamp(rptr[r] + atomicAdd(&rcur[r], 1), 0, N_EDGES - 1);
            rpack[pr] = make_int4(c, v0, v1, v2);
            int pc = iclamp(cptr[c] + atomicAdd(&ccur[c], 1), 0, N_EDGES - 1);
            cpack[pc] = make_int4(r, v0, v1, v2);
        }
    }
}

// ---------------- SpMM: one wave per row; packed edges; fp16 src gather ----------------
// raw_h (fp16) = A*src ; acc (fp32) = base + raw/||raw||
__global__ __launch_bounds__(256) void spmm_kernel(
        const int* __restrict__ ptr, const int4* __restrict__ pack, int ch,
        const unsigned short* __restrict__ src,         // fp16 [*,128]
        unsigned short* __restrict__ raw_h,             // fp16 out
        const float* __restrict__ base,                 // fp32 (may alias acc)
        float* __restrict__ acc, int nrows) {
    int wid = (blockIdx.x * blockDim.x + threadIdx.x) >> 6;
    int lane = threadIdx.x & 63;
    if (wid >= nrows) return;
    int beg = __builtin_amdgcn_readfirstlane(iclamp(ptr[wid], 0, N_EDGES));
    int end = __builtin_amdgcn_readfirstlane(iclamp(ptr[wid + 1], 0, N_EDGES));
    if (end < beg) end = beg;
    float ax = 0.f, ay = 0.f;
    int e = beg;
    int lo2 = lane * 2;
    for (; e + 8 <= end; e += 8) {
        int4 q0 = pack[e + 0], q1 = pack[e + 1], q2 = pack[e + 2], q3 = pack[e + 3];
        int4 q4 = pack[e + 4], q5 = pack[e + 5], q6 = pack[e + 6], q7 = pack[e + 7];
        float v0 = pickv(q0, ch), v1 = pickv(q1, ch), v2 = pickv(q2, ch), v3 = pickv(q3, ch);
        float v4 = pickv(q4, ch), v5 = pickv(q5, ch), v6 = pickv(q6, ch), v7 = pickv(q7, ch);
        float2 p0 = h2f2(*(const unsigned int*)(src + (size_t)q0.x * DIM + lo2));
        float2 p1 = h2f2(*(const unsigned int*)(src + (size_t)q1.x * DIM + lo2));
        float2 p2 = h2f2(*(const unsigned int*)(src + (size_t)q2.x * DIM + lo2));
        float2 p3 = h2f2(*(const unsigned int*)(src + (size_t)q3.x * DIM + lo2));
        float2 p4 = h2f2(*(const unsigned int*)(src + (size_t)q4.x * DIM + lo2));
        float2 p5 = h2f2(*(const unsigned int*)(src + (size_t)q5.x * DIM + lo2));
        float2 p6 = h2f2(*(const unsigned int*)(src + (size_t)q6.x * DIM + lo2));
        float2 p7 = h2f2(*(const unsigned int*)(src + (size_t)q7.x * DIM + lo2));
        ax = fmaf(v0, p0.x, fmaf(v1, p1.x, fmaf(v2, p2.x, fmaf(v3, p3.x, ax))));
        ax = fmaf(v4, p4.x, fmaf(v5, p5.x, fmaf(v6, p6.x, fmaf(v7, p7.x, ax))));
        ay = fmaf(v0, p0.y, fmaf(v1, p1.y, fmaf(v2, p2.y, fmaf(v3, p3.y, ay))));
        ay = fmaf(v4, p4.y, fmaf(v5, p5.y, fmaf(v6, p6.y, fmaf(v7, p7.y, ay))));
    }
    if (e < end) {
        int last = end - 1;
        int e1 = e + 1 <= last ? e + 1 : last;
        int e2 = e + 2 <= last ? e + 2 : last;
        int e3 = e + 3 <= last ? e + 3 : last;
        int e4 = e + 4 <= last ? e + 4 : last;
        int e5 = e + 5 <= last ? e + 5 : last;
        int e6 = e + 6 <= last ? e + 6 : last;
        int e7 = e + 7 <= last ? e + 7 : last;
        int4 q0 = pack[e], q1 = pack[e1], q2 = pack[e2], q3 = pack[e3];
        int4 q4 = pack[e4], q5 = pack[e5], q6 = pack[e6], q7 = pack[e7];
        float v0 = pickv(q0, ch);
        float v1 = (e + 1 < end) ? pickv(q1, ch) : 0.f;
        float v2 = (e + 2 < end) ? pickv(q2, ch) : 0.f;
        float v3 = (e + 3 < end) ? pickv(q3, ch) : 0.f;
        float v4 = (e + 4 < end) ? pickv(q4, ch) : 0.f;
        float v5 = (e + 5 < end) ? pickv(q5, ch) : 0.f;
        float v6 = (e + 6 < end) ? pickv(q6, ch) : 0.f;
        float v7 = (e + 7 < end) ? pickv(q7, ch) : 0.f;
        float2 p0 = h2f2(*(const unsigned int*)(src + (size_t)q0.x * DIM + lo2));
        float2 p1 = h2f2(*(const unsigned int*)(src + (size_t)q1.x * DIM + lo2));
        float2 p2 = h2f2(*(const unsigned int*)(src + (size_t)q2.x * DIM + lo2));
        float2 p3 = h2f2(*(const unsigned int*)(src + (size_t)q3.x * DIM + lo2));
        float2 p4 = h2f2(*(const unsigned int*)(src + (size_t)q4.x * DIM + lo2));
        float2 p5 = h2f2(*(const unsigned int*)(src + (size_t)q5.x * DIM + lo2));
        float2 p6 = h2f2(*(const unsigned int*)(src + (size_t)q6.x * DIM + lo2));
        float2 p7 = h2f2(*(const unsigned int*)(src + (size_t)q7.x * DIM + lo2));
        ax = fmaf(v0, p0.x, fmaf(v1, p1.x, fmaf(v2, p2.x, fmaf(v3, p3.x, ax))));
        ax = fmaf(v4, p4.x, fmaf(v5, p5.x, fmaf(v6, p6.x, fmaf(v7, p7.x, ax))));
        ay = fmaf(v0, p0.y, fmaf(v1, p1.y, fmaf(v2, p2.y, fmaf(v3, p3.y, ay))));
        ay = fmaf(v4, p4.y, fmaf(v5, p5.y, fmaf(v6, p6.y, fmaf(v7, p7.y, ay))));
    }
    float n2 = ax * ax + ay * ay;
    #pragma unroll
    for (int o = 32; o > 0; o >>= 1) n2 += __shfl_xor(n2, o, 64);
    float inv = rsqrtf(fmaxf(n2, 1e-30f));
    *(unsigned int*)(raw_h + (size_t)wid * DIM + lo2) = f2h2(ax, ay);
    float2 bv = *(const float2*)(base + (size_t)wid * DIM + lo2);
    *(float2*)(acc + (size_t)wid * DIM + lo2) =
        make_float2(bv.x + ax * inv, bv.y + ay * inv);
}

// ---------------- fused 3-channel L1-user SpMM: shared gather, 3 raw outputs ----------------
__global__ __launch_bounds__(256) void spmm3_kernel(
        const int* __restrict__ ptr, const int4* __restrict__ pack,
        const unsigned short* __restrict__ src,     // pid_h (shared across channels)
        unsigned short* __restrict__ r0, unsigned short* __restrict__ r1,
        unsigned short* __restrict__ r2, int nrows) {
    int wid = (blockIdx.x * blockDim.x + threadIdx.x) >> 6;
    int lane = threadIdx.x & 63;
    if (wid >= nrows) return;
    int beg = __builtin_amdgcn_readfirstlane(iclamp(ptr[wid], 0, N_EDGES));
    int end = __builtin_amdgcn_readfirstlane(iclamp(ptr[wid + 1], 0, N_EDGES));
    if (end < beg) end = beg;
    float a0x = 0.f, a0y = 0.f, a1x = 0.f, a1y = 0.f, a2x = 0.f, a2y = 0.f;
    int e = beg;
    int lo2 = lane * 2;
    for (; e + 4 <= end; e += 4) {
        int4 q0 = pack[e + 0], q1 = pack[e + 1], q2 = pack[e + 2], q3 = pack[e + 3];
        float2 p0 = h2f2(*(const unsigned int*)(src + (size_t)q0.x * DIM + lo2));
        float2 p1 = h2f2(*(const unsigned int*)(src + (size_t)q1.x * DIM + lo2));
        float2 p2 = h2f2(*(const unsigned int*)(src + (size_t)q2.x * DIM + lo2));
        float2 p3 = h2f2(*(const unsigned int*)(src + (size_t)q3.x * DIM + lo2));
        a0x = fmaf(__int_as_float(q0.y), p0.x, fmaf(__int_as_float(q1.y), p1.x,
              fmaf(__int_as_float(q2.y), p2.x, fmaf(__int_as_float(q3.y), p3.x, a0x))));
        a0y = fmaf(__int_as_float(q0.y), p0.y, fmaf(__int_as_float(q1.y), p1.y,
              fmaf(__int_as_float(q2.y), p2.y, fmaf(__int_as_float(q3.y), p3.y, a0y))));
        a1x = fmaf(__int_as_float(q0.z), p0.x, fmaf(__int_as_float(q1.z), p1.x,
              fmaf(__int_as_float(q2.z), p2.x, fmaf(__int_as_float(q3.z), p3.x, a1x))));
        a1y = fmaf(__int_as_float(q0.z), p0.y, fmaf(__int_as_float(q1.z), p1.y,
              fmaf(__int_as_float(q2.z), p2.y, fmaf(__int_as_float(q3.z), p3.y, a1y))));
        a2x = fmaf(__int_as_float(q0.w), p0.x, fmaf(__int_as_float(q1.w), p1.x,
              fmaf(__int_as_float(q2.w), p2.x, fmaf(__int_as_float(q3.w), p3.x, a2x))));
        a2y = fmaf(__int_as_float(q0.w), p0.y, fmaf(__int_as_float(q1.w), p1.y,
              fmaf(__int_as_float(q2.w), p2.y, fmaf(__int_as_float(q3.w), p3.y, a2y))));
    }
    for (; e < end; e++) {
        int4 q = pack[e];
        float2 p = h2f2(*(const unsigned int*)(src + (size_t)q.x * DIM + lo2));
        a0x = fmaf(__int_as_float(q.y), p.x, a0x);
        a0y = fmaf(__int_as_float(q.y), p.y, a0y);
        a1x = fmaf(__int_as_float(q.z), p.x, a1x);
        a1y = fmaf(__int_as_float(q.z), p.y, a1y);
        a2x = fmaf(__int_as_float(q.w), p.x, a2x);
        a2y = fmaf(__int_as_float(q.w), p.y, a2y);
    }
    size_t o = (size_t)wid * DIM + lo2;
    *(unsigned int*)(r0 + o) = f2h2(a0x, a0y);
    *(unsigned int*)(r1 + o) = f2h2(a1x, a1y);
    *(unsigned int*)(r2 + o) = f2h2(a2x, a2y);
}

// ---------------- L2-user SpMM: su = uid + n(u1) + n(u2); u1raw overwritten with u2 ----------------
__global__ __launch_bounds__(256) void spmm_l2u_kernel(
        const int* __restrict__ ptr, const int4* __restrict__ pack, int ch,
        const unsigned short* __restrict__ src,     // ptr_h (p1 raw fp16)
        unsigned short* __restrict__ u1raw,         // in: u1 raw; out: u2 raw
        const float* __restrict__ uid,
        float* __restrict__ su, int nrows) {
    int wid = (blockIdx.x * blockDim.x + threadIdx.x) >> 6;
    int lane = threadIdx.x & 63;
    if (wid >= nrows) return;
    int beg = __builtin_amdgcn_readfirstlane(iclamp(ptr[wid], 0, N_EDGES));
    int end = __builtin_amdgcn_readfirstlane(iclamp(ptr[wid + 1], 0, N_EDGES));
    if (end < beg) end = beg;
    float ax = 0.f, ay = 0.f;
    int e = beg;
    int lo2 = lane * 2;
    for (; e + 8 <= end; e += 8) {
        int4 q0 = pack[e + 0], q1 = pack[e + 1], q2 = pack[e + 2], q3 = pack[e + 3];
        int4 q4 = pack[e + 4], q5 = pack[e + 5], q6 = pack[e + 6], q7 = pack[e + 7];
        float v0 = pickv(q0, ch), v1 = pickv(q1, ch), v2 = pickv(q2, ch), v3 = pickv(q3, ch);
        float v4 = pickv(q4, ch), v5 = pickv(q5, ch), v6 = pickv(q6, ch), v7 = pickv(q7, ch);
        float2 p0 = h2f2(*(const unsigned int*)(src + (size_t)q0.x * DIM + lo2));
        float2 p1 = h2f2(*(const unsigned int*)(src + (size_t)q1.x * DIM + lo2));
        float2 p2 = h2f2(*(const unsigned int*)(src + (size_t)q2.x * DIM + lo2));
        float2 p3 = h2f2(*(const unsigned int*)(src + (size_t)q3.x * DIM + lo2));
        float2 p4 = h2f2(*(const unsigned int*)(src + (size_t)q4.x * DIM + lo2));
        float2 p5 = h2f2(*(const unsigned int*)(src + (size_t)q5.x * DIM + lo2));
        float2 p6 = h2f2(*(const unsigned int*)(src + (size_t)q6.x * DIM + lo2));
        float2 p7 = h2f2(*(const unsigned int*)(src + (size_t)q7.x * DIM + lo2));
        ax = fmaf(v0, p0.x, fmaf(v1, p1.x, fmaf(v2, p2.x, fmaf(v3, p3.x, ax))));
        ax = fmaf(v4, p4.x, fmaf(v5, p5.x, fmaf(v6, p6.x, fmaf(v7, p7.x, ax))));
        ay = fmaf(v0, p0.y, fmaf(v1, p1.y, fmaf(v2, p2.y, fmaf(v3, p3.y, ay))));
        ay = fmaf(v4, p4.y, fmaf(v5, p5.y, fmaf(v6, p6.y, fmaf(v7, p7.y, ay))));
    }
    if (e < end) {
        int last = end - 1;
        int e1 = e + 1 <= last ? e + 1 : last;
        int e2 = e + 2 <= last ? e + 2 : last;
        int e3 = e + 3 <= last ? e + 3 : last;
        int e4 = e + 4 <= last ? e + 4 : last;
        int e5 = e + 5 <= last ? e + 5 : last;
        int e6 = e + 6 <= last ? e + 6 : last;
        int e7 = e + 7 <= last ? e + 7 : last;
        int4 q0 = pack[e], q1 = pack[e1], q2 = pack[e2], q3 = pack[e3];
        int4 q4 = pack[e4], q5 = pack[e5], q6 = pack[e6], q7 = pack[e7];
        float v0 = pickv(q0, ch);
        float v1 = (e + 1 < end) ? pickv(q1, ch) : 0.f;
        float v2 = (e + 2 < end) ? pickv(q2, ch) : 0.f;
        float v3 = (e + 3 < end) ? pickv(q3, ch) : 0.f;
        float v4 = (e + 4 < end) ? pickv(q4, ch) : 0.f;
        float v5 = (e + 5 < end) ? pickv(q5, ch) : 0.f;
        float v6 = (e + 6 < end) ? pickv(q6, ch) : 0.f;
        float v7 = (e + 7 < end) ? pickv(q7, ch) : 0.f;
        float2 p0 = h2f2(*(const unsigned int*)(src + (size_t)q0.x * DIM + lo2));
        float2 p1 = h2f2(*(const unsigned int*)(src + (size_t)q1.x * DIM + lo2));
        float2 p2 = h2f2(*(const unsigned int*)(src + (size_t)q2.x * DIM + lo2));
        float2 p3 = h2f2(*(const unsigned int*)(src + (size_t)q3.x * DIM + lo2));
        float2 p4 = h2f2(*(const unsigned int*)(src + (size_t)q4.x * DIM + lo2));
        float2 p5 = h2f2(*(const unsigned int*)(src + (size_t)q5.x * DIM + lo2));
        float2 p6 = h2f2(*(const unsigned int*)(src + (size_t)q6.x * DIM + lo2));
        float2 p7 = h2f2(*(const unsigned int*)(src + (size_t)q7.x * DIM + lo2));
        ax = fmaf(v0, p0.x, fmaf(v1, p1.x, fmaf(v2, p2.x, fmaf(v3, p3.x, ax))));
        ax = fmaf(v4, p4.x, fmaf(v5, p5.x, fmaf(v6, p6.x, fmaf(v7, p7.x, ax))));
        ay = fmaf(v0, p0.y, fmaf(v1, p1.y, fmaf(v2, p2.y, fmaf(v3, p3.y, ay))));
        ay = fmaf(v4, p4.y, fmaf(v5, p5.y, fmaf(v6, p6.y, fmaf(v7, p7.y, ay))));
    }
    size_t o = (size_t)wid * DIM + lo2;
    float2 u1 = h2f2(*(const unsigned int*)(u1raw + o));
    float n2a = ax * ax + ay * ay;        // u2
    float n2b = u1.x * u1.x + u1.y * u1.y; // u1
    #pragma unroll
    for (int oo = 32; oo > 0; oo >>= 1) {
        n2a += __shfl_xor(n2a, oo, 64);
        n2b += __shfl_xor(n2b, oo, 64);
    }
    float i2 = rsqrtf(fmaxf(n2a, 1e-30f));
    float i1 = rsqrtf(fmaxf(n2b, 1e-30f));
    *(unsigned int*)(u1raw + o) = f2h2(ax, ay);   // u2 raw (src for L2-poi)
    float2 bv = *(const float2*)(uid + o);
    *(float2*)(su + o) = make_float2(bv.x + u1.x * i1 + ax * i2,
                                     bv.y + u1.y * i1 + ay * i2);
}

// ---------------- out = A[Mx128] @ W^T ; A-tile in LDS ----------------
// accum_h: optional fp16 mirror of the final accum (written on last channel)
__global__ __launch_bounds__(256) void gemm_aw_kernel(
        const float* __restrict__ A, const float* __restrict__ W,
        float* __restrict__ store, float* __restrict__ accum,
        _Float16* __restrict__ accum_h,
        const float* __restrict__ fw3, int fsel, int first, int M) {
    __shared__ float Al[32 * 128];                 // 16 KB
    int i0 = blockIdx.x * 32;
    const float4* Ag = (const float4*)(A + (size_t)i0 * DIM);
    float4* Al4 = (float4*)Al;
    for (int qi = threadIdx.x; qi < 1024; qi += 256) Al4[qi] = Ag[qi];
    __syncthreads();
    float coef = accum ? softmax3(fw3, fsel) : 0.f;
    int j2 = threadIdx.x & 63;
    int rg = threadIdx.x >> 6;
    const float4* W0 = (const float4*)(W + (size_t)j2 * DIM);
    const float4* W1 = (const float4*)(W + (size_t)(j2 + 64) * DIM);
    float acc0[8], acc1[8];
    #pragma unroll
    for (int m = 0; m < 8; m++) { acc0[m] = 0.f; acc1[m] = 0.f; }
    for (int kq = 0; kq < 32; kq++) {
        float4 w0 = W0[kq];
        float4 w1 = W1[kq];
        #pragma unroll
        for (int m = 0; m < 8; m++) {
            float4 a = Al4[(rg + 4 * m) * 32 + kq];
            acc0[m] = fmaf(a.x, w0.x, acc0[m]); acc0[m] = fmaf(a.y, w0.y, acc0[m]);
            acc0[m] = fmaf(a.z, w0.z, acc0[m]); acc0[m] = fmaf(a.w, w0.w, acc0[m]);
            acc1[m] = fmaf(a.x, w1.x, acc1[m]); acc1[m] = fmaf(a.y, w1.y, acc1[m]);
            acc1[m] = fmaf(a.z, w1.z, acc1[m]); acc1[m] = fmaf(a.w, w1.w, acc1[m]);
        }
    }
    #pragma unroll
    for (int m = 0; m < 8; m++) {
        int i = i0 + rg + 4 * m;
        if (i >= M) continue;
        size_t o0 = (size_t)i * DIM + j2;
        size_t o1 = o0 + 64;
        if (store) { store[o0] = acc0[m]; store[o1] = acc1[m]; }
        if (accum) {
            float p0 = first ? 0.f : accum[o0];
            float p1 = first ? 0.f : accum[o1];
            float n0 = p0 + coef * acc0[m];
            float n1 = p1 + coef * acc1[m];
            accum[o0] = n0;
            accum[o1] = n1;
            if (accum_h) {
                accum_h[o0] = (_Float16)n0;
                accum_h[o1] = (_Float16)n1;
            }
        }
    }
}

// ---------------- 256 selected rows of uf = su @ Wu^T ----------------
__global__ void ufsel_kernel(const float* __restrict__ su, const float* __restrict__ W,
                             const int* __restrict__ uidx, float* __restrict__ outsel) {
    int b = blockIdx.x, j = threadIdx.x;  // block 128
    __shared__ float ar[128];
    int u = iclamp(uidx[b], 0, N_USERS - 1);
    ar[j] = su[(size_t)u * DIM + j];
    __syncthreads();
    const float4* Wr = (const float4*)(W + (size_t)j * DIM);
    float acc = 0.f;
    #pragma unroll 8
    for (int q = 0; q < 32; q++) {
        float4 wq = Wr[q];
        acc = fmaf(ar[4 * q + 0], wq.x, acc);
        acc = fmaf(ar[4 * q + 1], wq.y, acc);
        acc = fmaf(ar[4 * q + 2], wq.z, acc);
        acc = fmaf(ar[4 * q + 3], wq.w, acc);
    }
    outsel[(size_t)b * DIM + j] = acc;
}

// ---------------- alt[b,j] (+)= wn_c * dot(uf_c[b], pf_c[poi]) ----------------
__global__ __launch_bounds__(256) void predict_kernel(
        const float* __restrict__ ufs, const float* __restrict__ pf,
        const int* __restrict__ pidx, const float* __restrict__ w3,
        int wsel, int first, float* __restrict__ alt) {
    int wid = (blockIdx.x * blockDim.x + threadIdx.x) >> 6;
    int lane = threadIdx.x & 63;
    if (wid >= BATCH * NPOS) return;
    int b = wid / NPOS;
    int poi = iclamp(pidx[wid], 0, N_POIS - 1);
    const float2 uv = *(const float2*)(ufs + (size_t)b * DIM + lane * 2);
    const float2 pv = *(const float2*)(pf + (size_t)poi * DIM + lane * 2);
    float s = uv.x * pv.x + uv.y * pv.y;
    #pragma unroll
    for (int o = 32; o > 0; o >>= 1) s += __shfl_xor(s, o, 64);
    if (lane == 0) {
        float coef = softmax3(w3, wsel);
        float prev = first ? 0.f : alt[wid];
        alt[wid] = prev + coef * s;
    }
}

// ---------------- BCE loss: stage 1 partials (25 blocks) ----------------
__global__ void loss_part_kernel(const float* __restrict__ alt, const float* __restrict__ labels,
                                 float* __restrict__ part) {
    int b = blockIdx.x, t = threadIdx.x;
    int i = b * 1024 + t * 4;
    float4 x4 = *(const float4*)(alt + i);
    float4 y4 = *(const float4*)(labels + i);
    float s = 0.f;
    s += fmaxf(x4.x, 0.f) - x4.x * y4.x + log1pf(expf(-fabsf(x4.x)));
    s += fmaxf(x4.y, 0.f) - x4.y * y4.y + log1pf(expf(-fabsf(x4.y)));
    s += fmaxf(x4.z, 0.f) - x4.z * y4.z + log1pf(expf(-fabsf(x4.z)));
    s += fmaxf(x4.w, 0.f) - x4.w * y4.w + log1pf(expf(-fabsf(x4.w)));
    __shared__ float red[256];
    red[t] = s;
    __syncthreads();
    for (int o = 128; o > 0; o >>= 1) {
        if (t < o) red[t] += red[t + o];
        __syncthreads();
    }
    if (t == 0) part[b] = red[0];
}

// ---------------- BCE loss: stage 2 final (1 wave, deterministic) ----------------
__global__ void loss_final_kernel(const float* __restrict__ part, float* __restrict__ out) {
    if (threadIdx.x == 0) {
        float s = 0.f;
        #pragma unroll
        for (int b = 0; b < LOSS_BLOCKS; b++) s += part[b];
        out[0] = s / (float)(BATCH * NPOS);
    }
}

// ---------------- bst_h[b][j] = id_feat[cur[b]] @ Ws^T + bias (fp16, row-major) ----------------
__global__ void bs_kernel(const float* __restrict__ idf, const float* __restrict__ Ws,
                          const float* __restrict__ bias, const int* __restrict__ uidx,
                          _Float16* __restrict__ bst_h) {
    int b = blockIdx.x, j = threadIdx.x;  // block 128
    __shared__ float ar[128];
    int u = iclamp(uidx[b], 0, N_USERS - 1);
    ar[j] = idf[(size_t)u * DIM + j];
    __syncthreads();
    const float4* Wr = (const float4*)(Ws + (size_t)j * DIM);
    float acc = 0.f;
    #pragma unroll 8
    for (int q = 0; q < 32; q++) {
        float4 wq = Wr[q];
        acc = fmaf(ar[4 * q + 0], wq.x, acc);
        acc = fmaf(ar[4 * q + 1], wq.y, acc);
        acc = fmaf(ar[4 * q + 2], wq.z, acc);
        acc = fmaf(ar[4 * q + 3], wq.w, acc);
    }
    bst_h[(size_t)b * DIM + j] = (_Float16)(acc + bias[j]);
}

__device__ __forceinline__ void topk_insert(float s, int u, float* ts, int* ti) {
    if (s > ts[TOPK - 1]) {
        #pragma unroll
        for (int j = TOPK - 1; j > 0; --j) {
            bool above = s > ts[j - 1];
            bool here = (!above) && (s > ts[j]);
            float nv = above ? ts[j - 1] : (here ? s : ts[j]);
            int ni = above ? ti[j - 1] : (here ? u : ti[j]);
            ts[j] = nv; ti[j] = ni;
        }
        if (s > ts[0]) { ts[0] = s; ti[0] = u; }
    }
}

// ---------------- MFMA uu scores + per-block top-20 ----------------
__global__ __launch_bounds__(256) void score_topk_kernel(
        const _Float16* __restrict__ idf_h, const _Float16* __restrict__ bst_h,
        float* __restrict__ cand_s, int* __restrict__ cand_i) {
    __shared__ __align__(16) unsigned char smraw[30720];
    float* ms = (float*)smraw;                              // [20][256] 20 KB
    unsigned short* mi = (unsigned short*)(smraw + 20480);  // [20][256] 10 KB
    int cid = blockIdx.x, bg = blockIdx.y;
    int tid = threadIdx.x;
    int w = tid >> 6, l = tid & 63;
    int lg = l >> 4, lc = l & 15;
    const _Float16* bbase = bst_h + ((size_t)(bg * 64 + w * 16 + lc)) * DIM + lg * 8;
    f16x8 B0 = *(const f16x8*)(bbase + 0);
    f16x8 B1 = *(const f16x8*)(bbase + 32);
    f16x8 B2 = *(const f16x8*)(bbase + 64);
    f16x8 B3 = *(const f16x8*)(bbase + 96);
    float ts[TOPK]; int ti[TOPK];
    #pragma unroll
    for (int k = 0; k < TOPK; k++) { ts[k] = -3.0e38f; ti[k] = 0; }
    int lo = cid * CPT;
    int hi = lo + CPT; if (hi > N_USERS) hi = N_USERS;
    #pragma unroll 2
    for (int u0 = lo; u0 < hi; u0 += 16) {
        int ar = u0 + lc; if (ar > N_USERS - 1) ar = N_USERS - 1;
        const _Float16* abase = idf_h + (size_t)ar * DIM + lg * 8;
        f16x8 A0 = *(const f16x8*)(abase + 0);
        f16x8 A1 = *(const f16x8*)(abase + 32);
        f16x8 A2 = *(const f16x8*)(abase + 64);
        f16x8 A3 = *(const f16x8*)(abase + 96);
        f32x4 accA = {0.f, 0.f, 0.f, 0.f};
        f32x4 accB = {0.f, 0.f, 0.f, 0.f};
        accA = __builtin_amdgcn_mfma_f32_16x16x32_f16(A0, B0, accA, 0, 0, 0);
        accB = __builtin_amdgcn_mfma_f32_16x16x32_f16(A1, B1, accB, 0, 0, 0);
        accA = __builtin_amdgcn_mfma_f32_16x16x32_f16(A2, B2, accA, 0, 0, 0);
        accB = __builtin_amdgcn_mfma_f32_16x16x32_f16(A3, B3, accB, 0, 0, 0);
        int ub = u0 + lg * 4;
        #pragma unroll
        for (int r = 0; r < 4; r++) {
            float s = accA[r] + accB[r];
            int u = ub + r;
            if (u < hi) topk_insert(s, u, ts, ti);
        }
    }
    #pragma unroll
    for (int k = 0; k < TOPK; k++) {
        ms[k * 256 + tid] = ts[k];
        mi[k * 256 + tid] = (unsigned short)ti[k];
    }
    __syncthreads();
    if (tid < 64) {
        int wm = tid >> 4, cm = tid & 15;
        int s0 = wm * 64 + cm;
        int s1 = s0 + 16, s2 = s0 + 32, s3 = s0 + 48;
        int p0 = 0, p1 = 0, p2 = 0, p3 = 0;
        size_t ob = ((size_t)cid * 256 + bg * 64 + wm * 16 + cm) * TOPK;
        for (int k = 0; k < TOPK; k++) {
            float h0 = ms[p0 * 256 + s0];
            float h1 = ms[p1 * 256 + s1];
            float h2 = ms[p2 * 256 + s2];
            float h3 = ms[p3 * 256 + s3];
            float best = h0; int which = 0;
            if (h1 > best) { best = h1; which = 1; }
            if (h2 > best) { best = h2; which = 2; }
            if (h3 > best) { best = h3; which = 3; }
            int idx;
            if (which == 0)      { idx = mi[p0 * 256 + s0]; p0++; }
            else if (which == 1) { idx = mi[p1 * 256 + s1]; p1++; }
            else if (which == 2) { idx = mi[p2 * 256 + s2]; p2++; }
            else                 { idx = mi[p3 * 256 + s3]; p3++; }
            cand_s[ob + k] = best;
            cand_i[ob + k] = idx;
        }
    }
}

// ---------------- global merge + softmax + weighted gather ----------------
__global__ void topk_merge_kernel(const float* __restrict__ cand_s, const int* __restrict__ cand_i,
                                  const float* __restrict__ guf,
                                  float* __restrict__ outp) {
    int b = blockIdx.x, t = threadIdx.x;  // block 128 (= NCHUNK)
    __shared__ float rs[NCHUNK]; __shared__ int ru[NCHUNK]; __shared__ int rt[NCHUNK];
    __shared__ float win_s[TOPK]; __shared__ int win_u[TOPK]; __shared__ float wk[TOPK];
    __shared__ int winner;
    int ptr = 0;
    size_t base = ((size_t)t * 256 + b) * TOPK;
    for (int k = 0; k < TOPK; k++) {
        rs[t] = (ptr < TOPK) ? cand_s[base + ptr] : -3.0e38f;
        ru[t] = (ptr < TOPK) ? cand_i[base + ptr] : 0;
        rt[t] = t;
        __syncthreads();
        for (int off = NCHUNK / 2; off > 0; off >>= 1) {
            if (t < off && rs[t + off] > rs[t]) {
                rs[t] = rs[t + off]; ru[t] = ru[t + off]; rt[t] = rt[t + off];
            }
            __syncthreads();
        }
        if (t == 0) { win_s[k] = rs[0]; win_u[k] = iclamp(ru[0], 0, N_USERS - 1); winner = rt[0]; }
        __syncthreads();
        if (t == winner) ptr++;
        __syncthreads();
    }
    if (t == 0) {
        float m = win_s[0], den = 0.f;
        for (int k = 0; k < TOPK; k++) { wk[k] = expf(win_s[k] - m); den += wk[k]; }
        float inv = 1.f / den;
        for (int k = 0; k < TOPK; k++) wk[k] *= inv;
    }
    __syncthreads();
    float acc = 0.f;
    #pragma unroll
    for (int k = 0; k < TOPK; k++)
        acc = fmaf(wk[k], guf[(size_t)win_u[k] * DIM + t], acc);
    outp[1 + (size_t)b * DIM + t] = acc;
}

extern "C" void kernel_launch(void* const* d_in, const int* in_sizes, int n_in,
                              void* d_out, int out_size, void* d_ws, size_t ws_size,
                              hipStream_t stream) {
    (void)in_sizes; (void)n_in; (void)out_size;
    const int*   er      = (const int*)d_in[0];
    const int*   ec      = (const int*)d_in[1];
    const float* click   = (const float*)d_in[2];
    const float* favor   = (const float*)d_in[3];
    const float* consume = (const float*)d_in[4];
    const float* uid     = (const float*)d_in[5];
    const float* pid     = (const float*)d_in[6];
    const int*   uidx    = (const int*)d_in[7];
    const int*   pidx    = (const int*)d_in[8];
    const float* labels  = (const float*)d_in[9];
    const float* guf     = (const float*)d_in[10];
    const float* w3      = (const float*)d_in[11];
    const float* fw3     = (const float*)d_in[12];
    const float* Wuc     = (const float*)d_in[13];
    const float* Wpc     = (const float*)d_in[14];
    const float* Wufv    = (const float*)d_in[15];
    const float* Wpfv    = (const float*)d_in[16];
    const float* Wuco    = (const float*)d_in[17];
    const float* Wpco    = (const float*)d_in[18];
    const float* Wss     = (const float*)d_in[19];
    const float* bias    = (const float*)d_in[20];
    float* outp = (float*)d_out;

    char* ws = (char*)d_ws;
    size_t off = 0;
    auto carve = [&](size_t bytes) -> void* {
        off = (off + 255) & ~(size_t)255;
        void* p = ws + off;
        off += bytes;
        return p;
    };
    // base layout (~89 MB, proven safe)
    float* ufs = (float*)carve(4ll * 3 * BATCH * DIM);
    float* alt = (float*)carve(4ll * BATCH * NPOS);
    float* bst = (float*)carve(4ll * DIM * BATCH);       // reused as fp16 bst_h
    int* rptr = (int*)carve(4 * (N_USERS + 1));
    int* cptr = (int*)carve(4 * (N_POIS + 1));
    int* cnts = (int*)carve(4 * (2 * (N_USERS + N_POIS)));
    int* rcnt = cnts;
    int* ccnt = cnts + N_USERS;
    int* rcur = ccnt + N_POIS;
    int* ccur = rcur + N_USERS;
    int* scanws = (int*)carve(4 * 2 * (RCH + CCH) + 4 * 64);  // rsum/csum/rbase/cbase
    int* rsum = scanws;
    int* csum = rsum + RCH;
    int* rbase = csum + CCH;
    int* cbase = rbase + RCH;
    float* losspart = (float*)carve(4 * (LOSS_BLOCKS + 7));
    int4* rpack = (int4*)carve(16ll * N_EDGES);   // {col, v0, v1, v2}
    int4* cpack = (int4*)carve(16ll * N_EDGES);   // {row, v0, v1, v2}
    unsigned short* pid_h = (unsigned short*)carve(2ll * N_POIS * DIM);
    unsigned short* utr0 = (unsigned short*)carve(2ll * N_USERS * DIM);  // 10.24 MB; pf alias
    unsigned short* ptr_h = (unsigned short*)carve(2ll * N_POIS * DIM);
    float* su  = (float*)carve(4ll * N_USERS * DIM);   // cand alias
    float* sp  = (float*)carve(4ll * N_POIS * DIM);
    float* idf = (float*)carve(4ll * N_USERS * DIM);
    float* pf = (float*)utr0;             // utr0 dead before pf written
    float* cand_s = su;                   // su dead before score_topk
    int*   cand_i = (int*)(su + (size_t)NCHUNK * BATCH * TOPK);
    _Float16* idf_h = (_Float16*)rpack;   // rpack dead after last L2-user spmm
    _Float16* bst_h = (_Float16*)bst;
    // extra carves for the channel-fused path (+20.5 MB) — only used if they fit
    unsigned short* utr1 = (unsigned short*)carve(2ll * N_USERS * DIM);
    unsigned short* utr2 = (unsigned short*)carve(2ll * N_USERS * DIM);
    bool fused = (off <= ws_size);

    zero_kernel<<<(2 * (N_USERS + N_POIS) + 255) / 256, 256, 0, stream>>>(
        (unsigned int*)cnts, 2 * (N_USERS + N_POIS));
    cast_f16_kernel<<<(N_POIS * DIM / 2 + 255) / 256, 256, 0, stream>>>(pid, pid_h, N_POIS * DIM / 2);
    hist_kernel<<<(N_EDGES + 255) / 256, 256, 0, stream>>>(er, ec, rcnt, ccnt);
    // parallel exclusive prefix sum (replaces 68 us serial scan)
    dim3 sg2(RCH, 2);
    chunksum_kernel<<<sg2, 256, 0, stream>>>(rcnt, ccnt, rsum, csum);
    chunkscan_kernel<<<1, 128, 0, stream>>>(rsum, csum, rbase, cbase, rptr, cptr);
    scatterscan_kernel<<<sg2, 256, 0, stream>>>(rcnt, ccnt, rbase, cbase, rptr, cptr);
    fill_kernel<<<(N_EDGES / 4 + 255) / 256, 256, 0, stream>>>(
        er, ec, rptr, cptr, rcur, ccur, rpack, cpack, click, favor, consume);

    struct Ch { const float* Wu; const float* Wp; int wsel; int fsel; };
    // wn (softmax over w[1,3]):  favor=0, click=1, consume=2
    // fwn (softmax over fw[3,1]): favor=0, consume=1, click=2
    Ch chs[3] = { { Wuc,  Wpc,  1, 2 },     // ch0 = click
                  { Wufv, Wpfv, 0, 0 },     // ch1 = favor
                  { Wuco, Wpco, 2, 1 } };   // ch2 = consume

    if (fused) {
        // fused 3-channel L1-user hop: one shared pid_h gather, 3 raw outputs
        spmm3_kernel<<<N_USERS * 64 / 256, 256, 0, stream>>>(
            rptr, rpack, pid_h, utr0, utr1, utr2, N_USERS);
        for (int c = 0; c < 3; c++) {
            unsigned short* uc = (c == 0) ? utr0 : ((c == 1) ? utr1 : utr2);
            spmm_kernel<<<N_POIS * 64 / 256, 256, 0, stream>>>(cptr, cpack, c, uc, ptr_h, pid, sp, N_POIS);
            spmm_l2u_kernel<<<N_USERS * 64 / 256, 256, 0, stream>>>(rptr, rpack, c, ptr_h, uc, uid, su, N_USERS);
            spmm_kernel<<<N_POIS * 64 / 256, 256, 0, stream>>>(cptr, cpack, c, uc, ptr_h, sp, sp, N_POIS);
            gemm_aw_kernel<<<N_USERS / 32, 256, 0, stream>>>(
                su, chs[c].Wu, nullptr, idf, (c == 2) ? idf_h : nullptr,
                fw3, chs[c].fsel, (c == 0) ? 1 : 0, N_USERS);
            ufsel_kernel<<<BATCH, 128, 0, stream>>>(su, chs[c].Wu, uidx, ufs + (size_t)c * BATCH * DIM);
            gemm_aw_kernel<<<N_POIS / 32, 256, 0, stream>>>(
                sp, chs[c].Wp, pf, nullptr, nullptr, fw3, 0, 0, N_POIS);
            predict_kernel<<<BATCH * NPOS * 64 / 256, 256, 0, stream>>>(
                ufs + (size_t)c * BATCH * DIM, pf, pidx, w3, chs[c].wsel, (c == 0) ? 1 : 0, alt);
        }
    } else {
        // proven fallback: per-channel schedule, single utr0 buffer
        for (int c = 0; c < 3; c++) {
            spmm_kernel<<<N_USERS * 64 / 256, 256, 0, stream>>>(rptr, rpack, c, pid_h, utr0, uid, su, N_USERS);
            spmm_kernel<<<N_POIS * 64 / 256, 256, 0, stream>>>(cptr, cpack, c, utr0, ptr_h, pid, sp, N_POIS);
            spmm_kernel<<<N_USERS * 64 / 256, 256, 0, stream>>>(rptr, rpack, c, ptr_h, utr0, su, su, N_USERS);
            spmm_kernel<<<N_POIS * 64 / 256, 256, 0, stream>>>(cptr, cpack, c, utr0, ptr_h, sp, sp, N_POIS);
            gemm_aw_kernel<<<N_USERS / 32, 256, 0, stream>>>(
                su, chs[c].Wu, nullptr, idf, (c == 2) ? idf_h : nullptr,
                fw3, chs[c].fsel, (c == 0) ? 1 : 0, N_USERS);
            ufsel_kernel<<<BATCH, 128, 0, stream>>>(su, chs[c].Wu, uidx, ufs + (size_t)c * BATCH * DIM);
            gemm_aw_kernel<<<N_POIS / 32, 256, 0, stream>>>(
                sp, chs[c].Wp, pf, nullptr, nullptr, fw3, 0, 0, N_POIS);
            predict_kernel<<<BATCH * NPOS * 64 / 256, 256, 0, stream>>>(
                ufs + (size_t)c * BATCH * DIM, pf, pidx, w3, chs[c].wsel, (c == 0) ? 1 : 0, alt);
        }
    }

    loss_part_kernel<<<LOSS_BLOCKS, 256, 0, stream>>>(alt, labels, losspart);
    loss_final_kernel<<<1, 64, 0, stream>>>(losspart, outp);
    bs_kernel<<<BATCH, 128, 0, stream>>>(idf, Wss, bias, uidx, bst_h);
    dim3 sg(NCHUNK, 4);
    score_topk_kernel<<<sg, 256, 0, stream>>>(idf_h, bst_h, cand_s, cand_i);
    topk_merge_kernel<<<BATCH, NCHUNK, 0, stream>>>(cand_s, cand_i, guf, outp);
}

// Round 6
// 681.620 us; speedup vs baseline: 1.6577x; 1.1883x over previous
//
#include <hip/hip_runtime.h>

#define N_USERS 40000
#define N_POIS  20000
#define DIM     128
#define N_EDGES 500000
#define BATCH   256
#define NPOS    100
#define TOPK    20
#define NCHUNK  128
#define CPT     313   // ceil(40000/128)
#define SCHUNK  1024  // scan chunk (256 thr x 4)
#define RCH     40    // ceil(40000/1024)
#define CCH     20    // ceil(20000/1024)
#define LOSS_BLOCKS 25  // 25600/1024

typedef _Float16 f16x8 __attribute__((ext_vector_type(8)));
typedef float f32x4 __attribute__((ext_vector_type(4)));

__device__ __forceinline__ int iclamp(int x, int lo, int hi) {
    return x < lo ? lo : (x > hi ? hi : x);
}
__device__ __forceinline__ float2 h2f2(unsigned int u) {
    union { unsigned int u32; _Float16 h[2]; } v; v.u32 = u;
    return make_float2((float)v.h[0], (float)v.h[1]);
}
__device__ __forceinline__ unsigned int f2h2(float x, float y) {
    union { unsigned int u32; _Float16 h[2]; } v;
    v.h[0] = (_Float16)x; v.h[1] = (_Float16)y; return v.u32;
}
__device__ __forceinline__ float softmax3(const float* p, int sel) {
    float a0 = p[0], a1 = p[1], a2 = p[2];
    float m = fmaxf(a0, fmaxf(a1, a2));
    float e0 = expf(a0 - m), e1 = expf(a1 - m), e2 = expf(a2 - m);
    float den = e0 + e1 + e2;
    float e = (sel == 0) ? e0 : ((sel == 1) ? e1 : e2);
    return e / den;
}
// pick channel value from packed edge {idx, v0, v1, v2}
__device__ __forceinline__ float pickv(int4 q, int ch) {
    return __int_as_float(ch == 0 ? q.y : (ch == 1 ? q.z : q.w));
}
// build fp16x8 fragment from 8 contiguous fp32
__device__ __forceinline__ f16x8 frag8(const float* p) {
    float4 x = *(const float4*)(p);
    float4 y = *(const float4*)(p + 4);
    f16x8 f;
    f[0] = (_Float16)x.x; f[1] = (_Float16)x.y; f[2] = (_Float16)x.z; f[3] = (_Float16)x.w;
    f[4] = (_Float16)y.x; f[5] = (_Float16)y.y; f[6] = (_Float16)y.z; f[7] = (_Float16)y.w;
    return f;
}

// ---------------- zero init ----------------
__global__ void zero_kernel(unsigned int* __restrict__ p, int nwords) {
    int i = blockIdx.x * blockDim.x + threadIdx.x;
    if (i < nwords) p[i] = 0u;
}

// ---------------- fp32 -> fp16 cast ----------------
__global__ void cast_f16_kernel(const float* __restrict__ src, unsigned short* __restrict__ dst,
                                int n2) {
    int i = blockIdx.x * blockDim.x + threadIdx.x;
    if (i < n2) {
        float2 v = *(const float2*)(src + 2 * (size_t)i);
        *(unsigned int*)(dst + 2 * (size_t)i) = f2h2(v.x, v.y);
    }
}

// ---------------- CSR build ----------------
__global__ void hist_kernel(const int* __restrict__ er, const int* __restrict__ ec,
                            int* __restrict__ rcnt, int* __restrict__ ccnt) {
    int e = blockIdx.x * blockDim.x + threadIdx.x;
    if (e < N_EDGES) {
        atomicAdd(&rcnt[iclamp(er[e], 0, N_USERS - 1)], 1);
        atomicAdd(&ccnt[iclamp(ec[e], 0, N_POIS - 1)], 1);
    }
}

// ---------------- parallel prefix sum, stage 1: per-1024-chunk sums ----------------
__global__ void chunksum_kernel(const int* __restrict__ rcnt, const int* __restrict__ ccnt,
                                int* __restrict__ rsum, int* __restrict__ csum) {
    int side = blockIdx.y;
    const int* cnt = side ? ccnt : rcnt;
    int n = side ? N_POIS : N_USERS;
    int nch = side ? CCH : RCH;
    int b = blockIdx.x;
    if (b >= nch) return;
    int t = threadIdx.x;
    int i = b * SCHUNK + t * 4;
    int s = 0;
    if (i + 4 <= n) {
        int4 v = *(const int4*)(cnt + i);
        s = v.x + v.y + v.z + v.w;
    } else {
        for (int j = i; j < n; j++) s += cnt[j];
    }
    __shared__ int red[256];
    red[t] = s;
    __syncthreads();
    for (int o = 128; o > 0; o >>= 1) {
        if (t < o) red[t] += red[t + o];
        __syncthreads();
    }
    if (t == 0) (side ? csum : rsum)[b] = red[0];
}

// ---------------- stage 2: scan chunk sums (wave shfl), write totals ----------------
__global__ void chunkscan_kernel(const int* __restrict__ rsum, const int* __restrict__ csum,
                                 int* __restrict__ rbase, int* __restrict__ cbase,
                                 int* __restrict__ rptr, int* __restrict__ cptr) {
    int w = threadIdx.x >> 6, l = threadIdx.x & 63;  // block 128: wave0=users, wave1=pois
    const int* src = w ? csum : rsum;
    int* dst = w ? cbase : rbase;
    int nch = w ? CCH : RCH;
    int orig = (l < nch) ? src[l] : 0;
    int v = orig;
    #pragma unroll
    for (int o = 1; o < 64; o <<= 1) {
        int u = __shfl_up(v, o, 64);
        if (l >= o) v += u;
    }
    if (l < nch) dst[l] = v - orig;                 // exclusive base
    if (l == nch - 1) {
        if (w) cptr[N_POIS] = v; else rptr[N_USERS] = v;
    }
}

// ---------------- stage 3: block scan within chunk + chunk base ----------------
__global__ void scatterscan_kernel(const int* __restrict__ rcnt, const int* __restrict__ ccnt,
                                   const int* __restrict__ rbase, const int* __restrict__ cbase,
                                   int* __restrict__ rptr, int* __restrict__ cptr) {
    int side = blockIdx.y;
    const int* cnt = side ? ccnt : rcnt;
    const int* basea = side ? cbase : rbase;
    int* ptr = side ? cptr : rptr;
    int n = side ? N_POIS : N_USERS;
    int nch = side ? CCH : RCH;
    int b = blockIdx.x;
    if (b >= nch) return;
    int t = threadIdx.x;
    int i = b * SCHUNK + t * 4;
    int c0 = 0, c1 = 0, c2 = 0, c3 = 0;
    if (i + 4 <= n) {
        int4 v = *(const int4*)(cnt + i);
        c0 = v.x; c1 = v.y; c2 = v.z; c3 = v.w;
    } else {
        if (i + 0 < n) c0 = cnt[i + 0];
        if (i + 1 < n) c1 = cnt[i + 1];
        if (i + 2 < n) c2 = cnt[i + 2];
    }
    int tsum = c0 + c1 + c2 + c3;
    int l = t & 63, w = t >> 6;
    int v = tsum;
    #pragma unroll
    for (int o = 1; o < 64; o <<= 1) {
        int u = __shfl_up(v, o, 64);
        if (l >= o) v += u;
    }
    __shared__ int wsum[4];
    if (l == 63) wsum[w] = v;
    __syncthreads();
    int wbase = 0;
    for (int k = 0; k < w; k++) wbase += wsum[k];
    int ex = v - tsum + wbase + basea[b];
    if (i + 4 <= n) {
        *(int4*)(ptr + i) = make_int4(ex, ex + c0, ex + c0 + c1, ex + c0 + c1 + c2);
    } else {
        if (i + 0 < n) ptr[i + 0] = ex;
        if (i + 1 < n) ptr[i + 1] = ex + c0;
        if (i + 2 < n) ptr[i + 2] = ex + c0 + c1;
    }
}

// ---------------- AoS CSR fill: 4 edges/thread for MLP; 2 x 16B stores per edge ----------------
__global__ void fill_kernel(const int* __restrict__ er, const int* __restrict__ ec,
                            const int* __restrict__ rptr, const int* __restrict__ cptr,
                            int* __restrict__ rcur, int* __restrict__ ccur,
                            int4* __restrict__ rpack, int4* __restrict__ cpack,
                            const float* __restrict__ ck, const float* __restrict__ fv,
                            const float* __restrict__ cs) {
    int e0 = 4 * (blockIdx.x * blockDim.x + threadIdx.x);
    if (e0 + 4 <= N_EDGES) {
        int4 r4 = *(const int4*)(er + e0);
        int4 c4 = *(const int4*)(ec + e0);
        float4 k4 = *(const float4*)(ck + e0);
        float4 f4 = *(const float4*)(fv + e0);
        float4 s4 = *(const float4*)(cs + e0);
        int rr[4] = { r4.x, r4.y, r4.z, r4.w };
        int cc[4] = { c4.x, c4.y, c4.z, c4.w };
        float kk[4] = { k4.x, k4.y, k4.z, k4.w };
        float ff[4] = { f4.x, f4.y, f4.z, f4.w };
        float ss[4] = { s4.x, s4.y, s4.z, s4.w };
        #pragma unroll
        for (int j = 0; j < 4; j++) {
            int r = iclamp(rr[j], 0, N_USERS - 1), c = iclamp(cc[j], 0, N_POIS - 1);
            int v0 = __float_as_int(kk[j]);
            int v1 = __float_as_int(ff[j]);
            int v2 = __float_as_int(ss[j]);
            int pr = iclamp(rptr[r] + atomicAdd(&rcur[r], 1), 0, N_EDGES - 1);
            rpack[pr] = make_int4(c, v0, v1, v2);
            int pc = iclamp(cptr[c] + atomicAdd(&ccur[c], 1), 0, N_EDGES - 1);
            cpack[pc] = make_int4(r, v0, v1, v2);
        }
    } else {
        for (int e = e0; e < N_EDGES; e++) {
            int r = iclamp(er[e], 0, N_USERS - 1), c = iclamp(ec[e], 0, N_POIS - 1);
            int v0 = __float_as_int(ck[e]);
            int v1 = __float_as_int(fv[e]);
            int v2 = __float_as_int(cs[e]);
            int pr = iclamp(rptr[r] + atomicAdd(&rcur[r], 1), 0, N_EDGES - 1);
            rpack[pr] = make_int4(c, v0, v1, v2);
            int pc = iclamp(cptr[c] + atomicAdd(&ccur[c], 1), 0, N_EDGES - 1);
            cpack[pc] = make_int4(r, v0, v1, v2);
        }
    }
}

// ---------------- SpMM: one wave per row; packed edges; fp16 src gather ----------------
// raw_h (fp16) = A*src ; acc (fp32) = base + raw/||raw||
__global__ __launch_bounds__(256) void spmm_kernel(
        const int* __restrict__ ptr, const int4* __restrict__ pack, int ch,
        const unsigned short* __restrict__ src,         // fp16 [*,128]
        unsigned short* __restrict__ raw_h,             // fp16 out
        const float* __restrict__ base,                 // fp32 (may alias acc)
        float* __restrict__ acc, int nrows) {
    int wid = (blockIdx.x * blockDim.x + threadIdx.x) >> 6;
    int lane = threadIdx.x & 63;
    if (wid >= nrows) return;
    int beg = __builtin_amdgcn_readfirstlane(iclamp(ptr[wid], 0, N_EDGES));
    int end = __builtin_amdgcn_readfirstlane(iclamp(ptr[wid + 1], 0, N_EDGES));
    if (end < beg) end = beg;
    float ax = 0.f, ay = 0.f;
    int e = beg;
    int lo2 = lane * 2;
    for (; e + 8 <= end; e += 8) {
        int4 q0 = pack[e + 0], q1 = pack[e + 1], q2 = pack[e + 2], q3 = pack[e + 3];
        int4 q4 = pack[e + 4], q5 = pack[e + 5], q6 = pack[e + 6], q7 = pack[e + 7];
        float v0 = pickv(q0, ch), v1 = pickv(q1, ch), v2 = pickv(q2, ch), v3 = pickv(q3, ch);
        float v4 = pickv(q4, ch), v5 = pickv(q5, ch), v6 = pickv(q6, ch), v7 = pickv(q7, ch);
        float2 p0 = h2f2(*(const unsigned int*)(src + (size_t)q0.x * DIM + lo2));
        float2 p1 = h2f2(*(const unsigned int*)(src + (size_t)q1.x * DIM + lo2));
        float2 p2 = h2f2(*(const unsigned int*)(src + (size_t)q2.x * DIM + lo2));
        float2 p3 = h2f2(*(const unsigned int*)(src + (size_t)q3.x * DIM + lo2));
        float2 p4 = h2f2(*(const unsigned int*)(src + (size_t)q4.x * DIM + lo2));
        float2 p5 = h2f2(*(const unsigned int*)(src + (size_t)q5.x * DIM + lo2));
        float2 p6 = h2f2(*(const unsigned int*)(src + (size_t)q6.x * DIM + lo2));
        float2 p7 = h2f2(*(const unsigned int*)(src + (size_t)q7.x * DIM + lo2));
        ax = fmaf(v0, p0.x, fmaf(v1, p1.x, fmaf(v2, p2.x, fmaf(v3, p3.x, ax))));
        ax = fmaf(v4, p4.x, fmaf(v5, p5.x, fmaf(v6, p6.x, fmaf(v7, p7.x, ax))));
        ay = fmaf(v0, p0.y, fmaf(v1, p1.y, fmaf(v2, p2.y, fmaf(v3, p3.y, ay))));
        ay = fmaf(v4, p4.y, fmaf(v5, p5.y, fmaf(v6, p6.y, fmaf(v7, p7.y, ay))));
    }
    if (e < end) {
        int last = end - 1;
        int e1 = e + 1 <= last ? e + 1 : last;
        int e2 = e + 2 <= last ? e + 2 : last;
        int e3 = e + 3 <= last ? e + 3 : last;
        int e4 = e + 4 <= last ? e + 4 : last;
        int e5 = e + 5 <= last ? e + 5 : last;
        int e6 = e + 6 <= last ? e + 6 : last;
        int e7 = e + 7 <= last ? e + 7 : last;
        int4 q0 = pack[e], q1 = pack[e1], q2 = pack[e2], q3 = pack[e3];
        int4 q4 = pack[e4], q5 = pack[e5], q6 = pack[e6], q7 = pack[e7];
        float v0 = pickv(q0, ch);
        float v1 = (e + 1 < end) ? pickv(q1, ch) : 0.f;
        float v2 = (e + 2 < end) ? pickv(q2, ch) : 0.f;
        float v3 = (e + 3 < end) ? pickv(q3, ch) : 0.f;
        float v4 = (e + 4 < end) ? pickv(q4, ch) : 0.f;
        float v5 = (e + 5 < end) ? pickv(q5, ch) : 0.f;
        float v6 = (e + 6 < end) ? pickv(q6, ch) : 0.f;
        float v7 = (e + 7 < end) ? pickv(q7, ch) : 0.f;
        float2 p0 = h2f2(*(const unsigned int*)(src + (size_t)q0.x * DIM + lo2));
        float2 p1 = h2f2(*(const unsigned int*)(src + (size_t)q1.x * DIM + lo2));
        float2 p2 = h2f2(*(const unsigned int*)(src + (size_t)q2.x * DIM + lo2));
        float2 p3 = h2f2(*(const unsigned int*)(src + (size_t)q3.x * DIM + lo2));
        float2 p4 = h2f2(*(const unsigned int*)(src + (size_t)q4.x * DIM + lo2));
        float2 p5 = h2f2(*(const unsigned int*)(src + (size_t)q5.x * DIM + lo2));
        float2 p6 = h2f2(*(const unsigned int*)(src + (size_t)q6.x * DIM + lo2));
        float2 p7 = h2f2(*(const unsigned int*)(src + (size_t)q7.x * DIM + lo2));
        ax = fmaf(v0, p0.x, fmaf(v1, p1.x, fmaf(v2, p2.x, fmaf(v3, p3.x, ax))));
        ax = fmaf(v4, p4.x, fmaf(v5, p5.x, fmaf(v6, p6.x, fmaf(v7, p7.x, ax))));
        ay = fmaf(v0, p0.y, fmaf(v1, p1.y, fmaf(v2, p2.y, fmaf(v3, p3.y, ay))));
        ay = fmaf(v4, p4.y, fmaf(v5, p5.y, fmaf(v6, p6.y, fmaf(v7, p7.y, ay))));
    }
    float n2 = ax * ax + ay * ay;
    #pragma unroll
    for (int o = 32; o > 0; o >>= 1) n2 += __shfl_xor(n2, o, 64);
    float inv = rsqrtf(fmaxf(n2, 1e-30f));
    *(unsigned int*)(raw_h + (size_t)wid * DIM + lo2) = f2h2(ax, ay);
    float2 bv = *(const float2*)(base + (size_t)wid * DIM + lo2);
    *(float2*)(acc + (size_t)wid * DIM + lo2) =
        make_float2(bv.x + ax * inv, bv.y + ay * inv);
}

// ---------------- fused 3-channel L1-user SpMM: shared gather, 3 raw outputs ----------------
__global__ __launch_bounds__(256) void spmm3_kernel(
        const int* __restrict__ ptr, const int4* __restrict__ pack,
        const unsigned short* __restrict__ src,     // pid_h (shared across channels)
        unsigned short* __restrict__ r0, unsigned short* __restrict__ r1,
        unsigned short* __restrict__ r2, int nrows) {
    int wid = (blockIdx.x * blockDim.x + threadIdx.x) >> 6;
    int lane = threadIdx.x & 63;
    if (wid >= nrows) return;
    int beg = __builtin_amdgcn_readfirstlane(iclamp(ptr[wid], 0, N_EDGES));
    int end = __builtin_amdgcn_readfirstlane(iclamp(ptr[wid + 1], 0, N_EDGES));
    if (end < beg) end = beg;
    float a0x = 0.f, a0y = 0.f, a1x = 0.f, a1y = 0.f, a2x = 0.f, a2y = 0.f;
    int e = beg;
    int lo2 = lane * 2;
    for (; e + 4 <= end; e += 4) {
        int4 q0 = pack[e + 0], q1 = pack[e + 1], q2 = pack[e + 2], q3 = pack[e + 3];
        float2 p0 = h2f2(*(const unsigned int*)(src + (size_t)q0.x * DIM + lo2));
        float2 p1 = h2f2(*(const unsigned int*)(src + (size_t)q1.x * DIM + lo2));
        float2 p2 = h2f2(*(const unsigned int*)(src + (size_t)q2.x * DIM + lo2));
        float2 p3 = h2f2(*(const unsigned int*)(src + (size_t)q3.x * DIM + lo2));
        a0x = fmaf(__int_as_float(q0.y), p0.x, fmaf(__int_as_float(q1.y), p1.x,
              fmaf(__int_as_float(q2.y), p2.x, fmaf(__int_as_float(q3.y), p3.x, a0x))));
        a0y = fmaf(__int_as_float(q0.y), p0.y, fmaf(__int_as_float(q1.y), p1.y,
              fmaf(__int_as_float(q2.y), p2.y, fmaf(__int_as_float(q3.y), p3.y, a0y))));
        a1x = fmaf(__int_as_float(q0.z), p0.x, fmaf(__int_as_float(q1.z), p1.x,
              fmaf(__int_as_float(q2.z), p2.x, fmaf(__int_as_float(q3.z), p3.x, a1x))));
        a1y = fmaf(__int_as_float(q0.z), p0.y, fmaf(__int_as_float(q1.z), p1.y,
              fmaf(__int_as_float(q2.z), p2.y, fmaf(__int_as_float(q3.z), p3.y, a1y))));
        a2x = fmaf(__int_as_float(q0.w), p0.x, fmaf(__int_as_float(q1.w), p1.x,
              fmaf(__int_as_float(q2.w), p2.x, fmaf(__int_as_float(q3.w), p3.x, a2x))));
        a2y = fmaf(__int_as_float(q0.w), p0.y, fmaf(__int_as_float(q1.w), p1.y,
              fmaf(__int_as_float(q2.w), p2.y, fmaf(__int_as_float(q3.w), p3.y, a2y))));
    }
    for (; e < end; e++) {
        int4 q = pack[e];
        float2 p = h2f2(*(const unsigned int*)(src + (size_t)q.x * DIM + lo2));
        a0x = fmaf(__int_as_float(q.y), p.x, a0x);
        a0y = fmaf(__int_as_float(q.y), p.y, a0y);
        a1x = fmaf(__int_as_float(q.z), p.x, a1x);
        a1y = fmaf(__int_as_float(q.z), p.y, a1y);
        a2x = fmaf(__int_as_float(q.w), p.x, a2x);
        a2y = fmaf(__int_as_float(q.w), p.y, a2y);
    }
    size_t o = (size_t)wid * DIM + lo2;
    *(unsigned int*)(r0 + o) = f2h2(a0x, a0y);
    *(unsigned int*)(r1 + o) = f2h2(a1x, a1y);
    *(unsigned int*)(r2 + o) = f2h2(a2x, a2y);
}

// ---------------- L2-user SpMM: su = uid + n(u1) + n(u2); u1raw overwritten with u2 ----------------
__global__ __launch_bounds__(256) void spmm_l2u_kernel(
        const int* __restrict__ ptr, const int4* __restrict__ pack, int ch,
        const unsigned short* __restrict__ src,     // ptr_h (p1 raw fp16)
        unsigned short* __restrict__ u1raw,         // in: u1 raw; out: u2 raw
        const float* __restrict__ uid,
        float* __restrict__ su, int nrows) {
    int wid = (blockIdx.x * blockDim.x + threadIdx.x) >> 6;
    int lane = threadIdx.x & 63;
    if (wid >= nrows) return;
    int beg = __builtin_amdgcn_readfirstlane(iclamp(ptr[wid], 0, N_EDGES));
    int end = __builtin_amdgcn_readfirstlane(iclamp(ptr[wid + 1], 0, N_EDGES));
    if (end < beg) end = beg;
    float ax = 0.f, ay = 0.f;
    int e = beg;
    int lo2 = lane * 2;
    for (; e + 8 <= end; e += 8) {
        int4 q0 = pack[e + 0], q1 = pack[e + 1], q2 = pack[e + 2], q3 = pack[e + 3];
        int4 q4 = pack[e + 4], q5 = pack[e + 5], q6 = pack[e + 6], q7 = pack[e + 7];
        float v0 = pickv(q0, ch), v1 = pickv(q1, ch), v2 = pickv(q2, ch), v3 = pickv(q3, ch);
        float v4 = pickv(q4, ch), v5 = pickv(q5, ch), v6 = pickv(q6, ch), v7 = pickv(q7, ch);
        float2 p0 = h2f2(*(const unsigned int*)(src + (size_t)q0.x * DIM + lo2));
        float2 p1 = h2f2(*(const unsigned int*)(src + (size_t)q1.x * DIM + lo2));
        float2 p2 = h2f2(*(const unsigned int*)(src + (size_t)q2.x * DIM + lo2));
        float2 p3 = h2f2(*(const unsigned int*)(src + (size_t)q3.x * DIM + lo2));
        float2 p4 = h2f2(*(const unsigned int*)(src + (size_t)q4.x * DIM + lo2));
        float2 p5 = h2f2(*(const unsigned int*)(src + (size_t)q5.x * DIM + lo2));
        float2 p6 = h2f2(*(const unsigned int*)(src + (size_t)q6.x * DIM + lo2));
        float2 p7 = h2f2(*(const unsigned int*)(src + (size_t)q7.x * DIM + lo2));
        ax = fmaf(v0, p0.x, fmaf(v1, p1.x, fmaf(v2, p2.x, fmaf(v3, p3.x, ax))));
        ax = fmaf(v4, p4.x, fmaf(v5, p5.x, fmaf(v6, p6.x, fmaf(v7, p7.x, ax))));
        ay = fmaf(v0, p0.y, fmaf(v1, p1.y, fmaf(v2, p2.y, fmaf(v3, p3.y, ay))));
        ay = fmaf(v4, p4.y, fmaf(v5, p5.y, fmaf(v6, p6.y, fmaf(v7, p7.y, ay))));
    }
    if (e < end) {
        int last = end - 1;
        int e1 = e + 1 <= last ? e + 1 : last;
        int e2 = e + 2 <= last ? e + 2 : last;
        int e3 = e + 3 <= last ? e + 3 : last;
        int e4 = e + 4 <= last ? e + 4 : last;
        int e5 = e + 5 <= last ? e + 5 : last;
        int e6 = e + 6 <= last ? e + 6 : last;
        int e7 = e + 7 <= last ? e + 7 : last;
        int4 q0 = pack[e], q1 = pack[e1], q2 = pack[e2], q3 = pack[e3];
        int4 q4 = pack[e4], q5 = pack[e5], q6 = pack[e6], q7 = pack[e7];
        float v0 = pickv(q0, ch);
        float v1 = (e + 1 < end) ? pickv(q1, ch) : 0.f;
        float v2 = (e + 2 < end) ? pickv(q2, ch) : 0.f;
        float v3 = (e + 3 < end) ? pickv(q3, ch) : 0.f;
        float v4 = (e + 4 < end) ? pickv(q4, ch) : 0.f;
        float v5 = (e + 5 < end) ? pickv(q5, ch) : 0.f;
        float v6 = (e + 6 < end) ? pickv(q6, ch) : 0.f;
        float v7 = (e + 7 < end) ? pickv(q7, ch) : 0.f;
        float2 p0 = h2f2(*(const unsigned int*)(src + (size_t)q0.x * DIM + lo2));
        float2 p1 = h2f2(*(const unsigned int*)(src + (size_t)q1.x * DIM + lo2));
        float2 p2 = h2f2(*(const unsigned int*)(src + (size_t)q2.x * DIM + lo2));
        float2 p3 = h2f2(*(const unsigned int*)(src + (size_t)q3.x * DIM + lo2));
        float2 p4 = h2f2(*(const unsigned int*)(src + (size_t)q4.x * DIM + lo2));
        float2 p5 = h2f2(*(const unsigned int*)(src + (size_t)q5.x * DIM + lo2));
        float2 p6 = h2f2(*(const unsigned int*)(src + (size_t)q6.x * DIM + lo2));
        float2 p7 = h2f2(*(const unsigned int*)(src + (size_t)q7.x * DIM + lo2));
        ax = fmaf(v0, p0.x, fmaf(v1, p1.x, fmaf(v2, p2.x, fmaf(v3, p3.x, ax))));
        ax = fmaf(v4, p4.x, fmaf(v5, p5.x, fmaf(v6, p6.x, fmaf(v7, p7.x, ax))));
        ay = fmaf(v0, p0.y, fmaf(v1, p1.y, fmaf(v2, p2.y, fmaf(v3, p3.y, ay))));
        ay = fmaf(v4, p4.y, fmaf(v5, p5.y, fmaf(v6, p6.y, fmaf(v7, p7.y, ay))));
    }
    size_t o = (size_t)wid * DIM + lo2;
    float2 u1 = h2f2(*(const unsigned int*)(u1raw + o));
    float n2a = ax * ax + ay * ay;        // u2
    float n2b = u1.x * u1.x + u1.y * u1.y; // u1
    #pragma unroll
    for (int oo = 32; oo > 0; oo >>= 1) {
        n2a += __shfl_xor(n2a, oo, 64);
        n2b += __shfl_xor(n2b, oo, 64);
    }
    float i2 = rsqrtf(fmaxf(n2a, 1e-30f));
    float i1 = rsqrtf(fmaxf(n2b, 1e-30f));
    *(unsigned int*)(u1raw + o) = f2h2(ax, ay);   // u2 raw (src for L2-poi)
    float2 bv = *(const float2*)(uid + o);
    *(float2*)(su + o) = make_float2(bv.x + u1.x * i1 + ax * i2,
                                     bv.y + u1.y * i1 + ay * i2);
}

// ---------------- MFMA: out[Mx128] = A[Mx128] @ W^T ; fp32 in, fp16 frags, fp32 accum ----------------
// Block 256 = 4 waves; wave w owns cols [w*32, w*32+32); block covers 64 rows.
// C layout (16x16x32): col = lane&15 (B=W row j), row = (lane>>4)*4 + reg (A row i).
__global__ __launch_bounds__(256) void gemm_mfma_kernel(
        const float* __restrict__ A, const float* __restrict__ W,
        float* __restrict__ store, float* __restrict__ accum,
        _Float16* __restrict__ accum_h,
        const float* __restrict__ fw3, int fsel, int first, int M) {
    int w = threadIdx.x >> 6, l = threadIdx.x & 63;
    int lg = l >> 4, lc = l & 15;
    int j0 = w * 32;
    float coef = accum ? softmax3(fw3, fsel) : 0.f;
    // loop-invariant B fragments: 2 col-tiles x 4 K-slices from W rows (fp32 -> fp16)
    f16x8 Bf[2][4];
    #pragma unroll
    for (int t = 0; t < 2; t++) {
        const float* wr = W + (size_t)(j0 + t * 16 + lc) * DIM + lg * 8;
        #pragma unroll
        for (int s = 0; s < 4; s++) Bf[t][s] = frag8(wr + s * 32);
    }
    int base = blockIdx.x * 64;
    #pragma unroll
    for (int rt = 0; rt < 4; rt++) {
        int u0 = base + rt * 16;
        int ar = u0 + lc; if (ar > M - 1) ar = M - 1;
        const float* arow = A + (size_t)ar * DIM + lg * 8;
        f16x8 Af[4];
        #pragma unroll
        for (int s = 0; s < 4; s++) Af[s] = frag8(arow + s * 32);
        f32x4 acc0 = {0.f, 0.f, 0.f, 0.f};
        f32x4 acc1 = {0.f, 0.f, 0.f, 0.f};
        #pragma unroll
        for (int s = 0; s < 4; s++) {
            acc0 = __builtin_amdgcn_mfma_f32_16x16x32_f16(Af[s], Bf[0][s], acc0, 0, 0, 0);
            acc1 = __builtin_amdgcn_mfma_f32_16x16x32_f16(Af[s], Bf[1][s], acc1, 0, 0, 0);
        }
        int rbase = u0 + lg * 4;
        #pragma unroll
        for (int r = 0; r < 4; r++) {
            int row = rbase + r;
            if (row >= M) continue;
            size_t o0 = (size_t)row * DIM + j0 + lc;
            size_t o1 = o0 + 16;
            if (store) { store[o0] = acc0[r]; store[o1] = acc1[r]; }
            if (accum) {
                float p0 = first ? 0.f : accum[o0];
                float p1 = first ? 0.f : accum[o1];
                float n0 = p0 + coef * acc0[r];
                float n1 = p1 + coef * acc1[r];
                accum[o0] = n0;
                accum[o1] = n1;
                if (accum_h) {
                    accum_h[o0] = (_Float16)n0;
                    accum_h[o1] = (_Float16)n1;
                }
            }
        }
    }
}

// ---------------- 256 selected rows of uf = su @ Wu^T ----------------
__global__ void ufsel_kernel(const float* __restrict__ su, const float* __restrict__ W,
                             const int* __restrict__ uidx, float* __restrict__ outsel) {
    int b = blockIdx.x, j = threadIdx.x;  // block 128
    __shared__ float ar[128];
    int u = iclamp(uidx[b], 0, N_USERS - 1);
    ar[j] = su[(size_t)u * DIM + j];
    __syncthreads();
    const float4* Wr = (const float4*)(W + (size_t)j * DIM);
    float acc = 0.f;
    #pragma unroll 8
    for (int q = 0; q < 32; q++) {
        float4 wq = Wr[q];
        acc = fmaf(ar[4 * q + 0], wq.x, acc);
        acc = fmaf(ar[4 * q + 1], wq.y, acc);
        acc = fmaf(ar[4 * q + 2], wq.z, acc);
        acc = fmaf(ar[4 * q + 3], wq.w, acc);
    }
    outsel[(size_t)b * DIM + j] = acc;
}

// ---------------- alt[b,j] (+)= wn_c * dot(uf_c[b], pf_c[poi]) ----------------
__global__ __launch_bounds__(256) void predict_kernel(
        const float* __restrict__ ufs, const float* __restrict__ pf,
        const int* __restrict__ pidx, const float* __restrict__ w3,
        int wsel, int first, float* __restrict__ alt) {
    int wid = (blockIdx.x * blockDim.x + threadIdx.x) >> 6;
    int lane = threadIdx.x & 63;
    if (wid >= BATCH * NPOS) return;
    int b = wid / NPOS;
    int poi = iclamp(pidx[wid], 0, N_POIS - 1);
    const float2 uv = *(const float2*)(ufs + (size_t)b * DIM + lane * 2);
    const float2 pv = *(const float2*)(pf + (size_t)poi * DIM + lane * 2);
    float s = uv.x * pv.x + uv.y * pv.y;
    #pragma unroll
    for (int o = 32; o > 0; o >>= 1) s += __shfl_xor(s, o, 64);
    if (lane == 0) {
        float coef = softmax3(w3, wsel);
        float prev = first ? 0.f : alt[wid];
        alt[wid] = prev + coef * s;
    }
}

// ---------------- BCE loss: stage 1 partials (25 blocks) ----------------
__global__ void loss_part_kernel(const float* __restrict__ alt, const float* __restrict__ labels,
                                 float* __restrict__ part) {
    int b = blockIdx.x, t = threadIdx.x;
    int i = b * 1024 + t * 4;
    float4 x4 = *(const float4*)(alt + i);
    float4 y4 = *(const float4*)(labels + i);
    float s = 0.f;
    s += fmaxf(x4.x, 0.f) - x4.x * y4.x + log1pf(expf(-fabsf(x4.x)));
    s += fmaxf(x4.y, 0.f) - x4.y * y4.y + log1pf(expf(-fabsf(x4.y)));
    s += fmaxf(x4.z, 0.f) - x4.z * y4.z + log1pf(expf(-fabsf(x4.z)));
    s += fmaxf(x4.w, 0.f) - x4.w * y4.w + log1pf(expf(-fabsf(x4.w)));
    __shared__ float red[256];
    red[t] = s;
    __syncthreads();
    for (int o = 128; o > 0; o >>= 1) {
        if (t < o) red[t] += red[t + o];
        __syncthreads();
    }
    if (t == 0) part[b] = red[0];
}

// ---------------- BCE loss: stage 2 final (deterministic) ----------------
__global__ void loss_final_kernel(const float* __restrict__ part, float* __restrict__ out) {
    if (threadIdx.x == 0) {
        float s = 0.f;
        #pragma unroll
        for (int b = 0; b < LOSS_BLOCKS; b++) s += part[b];
        out[0] = s / (float)(BATCH * NPOS);
    }
}

// ---------------- bst_h[b][j] = id_feat[cur[b]] @ Ws^T + bias (fp16, row-major) ----------------
__global__ void bs_kernel(const float* __restrict__ idf, const float* __restrict__ Ws,
                          const float* __restrict__ bias, const int* __restrict__ uidx,
                          _Float16* __restrict__ bst_h) {
    int b = blockIdx.x, j = threadIdx.x;  // block 128
    __shared__ float ar[128];
    int u = iclamp(uidx[b], 0, N_USERS - 1);
    ar[j] = idf[(size_t)u * DIM + j];
    __syncthreads();
    const float4* Wr = (const float4*)(Ws + (size_t)j * DIM);
    float acc = 0.f;
    #pragma unroll 8
    for (int q = 0; q < 32; q++) {
        float4 wq = Wr[q];
        acc = fmaf(ar[4 * q + 0], wq.x, acc);
        acc = fmaf(ar[4 * q + 1], wq.y, acc);
        acc = fmaf(ar[4 * q + 2], wq.z, acc);
        acc = fmaf(ar[4 * q + 3], wq.w, acc);
    }
    bst_h[(size_t)b * DIM + j] = (_Float16)(acc + bias[j]);
}

__device__ __forceinline__ void topk_insert(float s, int u, float* ts, int* ti) {
    if (s > ts[TOPK - 1]) {
        #pragma unroll
        for (int j = TOPK - 1; j > 0; --j) {
            bool above = s > ts[j - 1];
            bool here = (!above) && (s > ts[j]);
            float nv = above ? ts[j - 1] : (here ? s : ts[j]);
            int ni = above ? ti[j - 1] : (here ? u : ti[j]);
            ts[j] = nv; ti[j] = ni;
        }
        if (s > ts[0]) { ts[0] = s; ti[0] = u; }
    }
}

// ---------------- MFMA uu scores + per-block top-20 ----------------
__global__ __launch_bounds__(256) void score_topk_kernel(
        const _Float16* __restrict__ idf_h, const _Float16* __restrict__ bst_h,
        float* __restrict__ cand_s, int* __restrict__ cand_i) {
    __shared__ __align__(16) unsigned char smraw[30720];
    float* ms = (float*)smraw;                              // [20][256] 20 KB
    unsigned short* mi = (unsigned short*)(smraw + 20480);  // [20][256] 10 KB
    int cid = blockIdx.x, bg = blockIdx.y;
    int tid = threadIdx.x;
    int w = tid >> 6, l = tid & 63;
    int lg = l >> 4, lc = l & 15;
    const _Float16* bbase = bst_h + ((size_t)(bg * 64 + w * 16 + lc)) * DIM + lg * 8;
    f16x8 B0 = *(const f16x8*)(bbase + 0);
    f16x8 B1 = *(const f16x8*)(bbase + 32);
    f16x8 B2 = *(const f16x8*)(bbase + 64);
    f16x8 B3 = *(const f16x8*)(bbase + 96);
    float ts[TOPK]; int ti[TOPK];
    #pragma unroll
    for (int k = 0; k < TOPK; k++) { ts[k] = -3.0e38f; ti[k] = 0; }
    int lo = cid * CPT;
    int hi = lo + CPT; if (hi > N_USERS) hi = N_USERS;
    #pragma unroll 2
    for (int u0 = lo; u0 < hi; u0 += 16) {
        int ar = u0 + lc; if (ar > N_USERS - 1) ar = N_USERS - 1;
        const _Float16* abase = idf_h + (size_t)ar * DIM + lg * 8;
        f16x8 A0 = *(const f16x8*)(abase + 0);
        f16x8 A1 = *(const f16x8*)(abase + 32);
        f16x8 A2 = *(const f16x8*)(abase + 64);
        f16x8 A3 = *(const f16x8*)(abase + 96);
        f32x4 accA = {0.f, 0.f, 0.f, 0.f};
        f32x4 accB = {0.f, 0.f, 0.f, 0.f};
        accA = __builtin_amdgcn_mfma_f32_16x16x32_f16(A0, B0, accA, 0, 0, 0);
        accB = __builtin_amdgcn_mfma_f32_16x16x32_f16(A1, B1, accB, 0, 0, 0);
        accA = __builtin_amdgcn_mfma_f32_16x16x32_f16(A2, B2, accA, 0, 0, 0);
        accB = __builtin_amdgcn_mfma_f32_16x16x32_f16(A3, B3, accB, 0, 0, 0);
        int ub = u0 + lg * 4;
        #pragma unroll
        for (int r = 0; r < 4; r++) {
            float s = accA[r] + accB[r];
            int u = ub + r;
            if (u < hi) topk_insert(s, u, ts, ti);
        }
    }
    #pragma unroll
    for (int k = 0; k < TOPK; k++) {
        ms[k * 256 + tid] = ts[k];
        mi[k * 256 + tid] = (unsigned short)ti[k];
    }
    __syncthreads();
    if (tid < 64) {
        int wm = tid >> 4, cm = tid & 15;
        int s0 = wm * 64 + cm;
        int s1 = s0 + 16, s2 = s0 + 32, s3 = s0 + 48;
        int p0 = 0, p1 = 0, p2 = 0, p3 = 0;
        size_t ob = ((size_t)cid * 256 + bg * 64 + wm * 16 + cm) * TOPK;
        for (int k = 0; k < TOPK; k++) {
            float h0 = ms[p0 * 256 + s0];
            float h1 = ms[p1 * 256 + s1];
            float h2 = ms[p2 * 256 + s2];
            float h3 = ms[p3 * 256 + s3];
            float best = h0; int which = 0;
            if (h1 > best) { best = h1; which = 1; }
            if (h2 > best) { best = h2; which = 2; }
            if (h3 > best) { best = h3; which = 3; }
            int idx;
            if (which == 0)      { idx = mi[p0 * 256 + s0]; p0++; }
            else if (which == 1) { idx = mi[p1 * 256 + s1]; p1++; }
            else if (which == 2) { idx = mi[p2 * 256 + s2]; p2++; }
            else                 { idx = mi[p3 * 256 + s3]; p3++; }
            cand_s[ob + k] = best;
            cand_i[ob + k] = idx;
        }
    }
}

// ---------------- global merge + softmax + weighted gather ----------------
__global__ void topk_merge_kernel(const float* __restrict__ cand_s, const int* __restrict__ cand_i,
                                  const float* __restrict__ guf,
                                  float* __restrict__ outp) {
    int b = blockIdx.x, t = threadIdx.x;  // block 128 (= NCHUNK)
    __shared__ float rs[NCHUNK]; __shared__ int ru[NCHUNK]; __shared__ int rt[NCHUNK];
    __shared__ float win_s[TOPK]; __shared__ int win_u[TOPK]; __shared__ float wk[TOPK];
    __shared__ int winner;
    int ptr = 0;
    size_t base = ((size_t)t * 256 + b) * TOPK;
    for (int k = 0; k < TOPK; k++) {
        rs[t] = (ptr < TOPK) ? cand_s[base + ptr] : -3.0e38f;
        ru[t] = (ptr < TOPK) ? cand_i[base + ptr] : 0;
        rt[t] = t;
        __syncthreads();
        for (int off = NCHUNK / 2; off > 0; off >>= 1) {
            if (t < off && rs[t + off] > rs[t]) {
                rs[t] = rs[t + off]; ru[t] = ru[t + off]; rt[t] = rt[t + off];
            }
            __syncthreads();
        }
        if (t == 0) { win_s[k] = rs[0]; win_u[k] = iclamp(ru[0], 0, N_USERS - 1); winner = rt[0]; }
        __syncthreads();
        if (t == winner) ptr++;
        __syncthreads();
    }
    if (t == 0) {
        float m = win_s[0], den = 0.f;
        for (int k = 0; k < TOPK; k++) { wk[k] = expf(win_s[k] - m); den += wk[k]; }
        float inv = 1.f / den;
        for (int k = 0; k < TOPK; k++) wk[k] *= inv;
    }
    __syncthreads();
    float acc = 0.f;
    #pragma unroll
    for (int k = 0; k < TOPK; k++)
        acc = fmaf(wk[k], guf[(size_t)win_u[k] * DIM + t], acc);
    outp[1 + (size_t)b * DIM + t] = acc;
}

extern "C" void kernel_launch(void* const* d_in, const int* in_sizes, int n_in,
                              void* d_out, int out_size, void* d_ws, size_t ws_size,
                              hipStream_t stream) {
    (void)in_sizes; (void)n_in; (void)out_size;
    const int*   er      = (const int*)d_in[0];
    const int*   ec      = (const int*)d_in[1];
    const float* click   = (const float*)d_in[2];
    const float* favor   = (const float*)d_in[3];
    const float* consume = (const float*)d_in[4];
    const float* uid     = (const float*)d_in[5];
    const float* pid     = (const float*)d_in[6];
    const int*   uidx    = (const int*)d_in[7];
    const int*   pidx    = (const int*)d_in[8];
    const float* labels  = (const float*)d_in[9];
    const float* guf     = (const float*)d_in[10];
    const float* w3      = (const float*)d_in[11];
    const float* fw3     = (const float*)d_in[12];
    const float* Wuc     = (const float*)d_in[13];
    const float* Wpc     = (const float*)d_in[14];
    const float* Wufv    = (const float*)d_in[15];
    const float* Wpfv    = (const float*)d_in[16];
    const float* Wuco    = (const float*)d_in[17];
    const float* Wpco    = (const float*)d_in[18];
    const float* Wss     = (const float*)d_in[19];
    const float* bias    = (const float*)d_in[20];
    float* outp = (float*)d_out;

    char* ws = (char*)d_ws;
    size_t off = 0;
    auto carve = [&](size_t bytes) -> void* {
        off = (off + 255) & ~(size_t)255;
        void* p = ws + off;
        off += bytes;
        return p;
    };
    // base layout (~89 MB, proven safe)
    float* ufs = (float*)carve(4ll * 3 * BATCH * DIM);
    float* alt = (float*)carve(4ll * BATCH * NPOS);
    float* bst = (float*)carve(4ll * DIM * BATCH);       // reused as fp16 bst_h
    int* rptr = (int*)carve(4 * (N_USERS + 1));
    int* cptr = (int*)carve(4 * (N_POIS + 1));
    int* cnts = (int*)carve(4 * (2 * (N_USERS + N_POIS)));
    int* rcnt = cnts;
    int* ccnt = cnts + N_USERS;
    int* rcur = ccnt + N_POIS;
    int* ccur = rcur + N_USERS;
    int* scanws = (int*)carve(4 * 2 * (RCH + CCH) + 4 * 64);  // rsum/csum/rbase/cbase
    int* rsum = scanws;
    int* csum = rsum + RCH;
    int* rbase = csum + CCH;
    int* cbase = rbase + RCH;
    float* losspart = (float*)carve(4 * (LOSS_BLOCKS + 7));
    int4* rpack = (int4*)carve(16ll * N_EDGES);   // {col, v0, v1, v2}
    int4* cpack = (int4*)carve(16ll * N_EDGES);   // {row, v0, v1, v2}
    unsigned short* pid_h = (unsigned short*)carve(2ll * N_POIS * DIM);
    unsigned short* utr0 = (unsigned short*)carve(2ll * N_USERS * DIM);  // 10.24 MB; pf alias
    unsigned short* ptr_h = (unsigned short*)carve(2ll * N_POIS * DIM);
    float* su  = (float*)carve(4ll * N_USERS * DIM);   // cand alias
    float* sp  = (float*)carve(4ll * N_POIS * DIM);
    float* idf = (float*)carve(4ll * N_USERS * DIM);
    float* pf = (float*)utr0;             // utr0 dead before pf written
    float* cand_s = su;                   // su dead before score_topk
    int*   cand_i = (int*)(su + (size_t)NCHUNK * BATCH * TOPK);
    _Float16* idf_h = (_Float16*)rpack;   // rpack dead after last L2-user spmm
    _Float16* bst_h = (_Float16*)bst;
    // extra carves for the channel-fused path (+20.5 MB) — only used if they fit
    unsigned short* utr1 = (unsigned short*)carve(2ll * N_USERS * DIM);
    unsigned short* utr2 = (unsigned short*)carve(2ll * N_USERS * DIM);
    bool fused = (off <= ws_size);

    zero_kernel<<<(2 * (N_USERS + N_POIS) + 255) / 256, 256, 0, stream>>>(
        (unsigned int*)cnts, 2 * (N_USERS + N_POIS));
    cast_f16_kernel<<<(N_POIS * DIM / 2 + 255) / 256, 256, 0, stream>>>(pid, pid_h, N_POIS * DIM / 2);
    hist_kernel<<<(N_EDGES + 255) / 256, 256, 0, stream>>>(er, ec, rcnt, ccnt);
    // parallel exclusive prefix sum
    dim3 sg2(RCH, 2);
    chunksum_kernel<<<sg2, 256, 0, stream>>>(rcnt, ccnt, rsum, csum);
    chunkscan_kernel<<<1, 128, 0, stream>>>(rsum, csum, rbase, cbase, rptr, cptr);
    scatterscan_kernel<<<sg2, 256, 0, stream>>>(rcnt, ccnt, rbase, cbase, rptr, cptr);
    fill_kernel<<<(N_EDGES / 4 + 255) / 256, 256, 0, stream>>>(
        er, ec, rptr, cptr, rcur, ccur, rpack, cpack, click, favor, consume);

    struct Ch { const float* Wu; const float* Wp; int wsel; int fsel; };
    // wn (softmax over w[1,3]):  favor=0, click=1, consume=2
    // fwn (softmax over fw[3,1]): favor=0, consume=1, click=2
    Ch chs[3] = { { Wuc,  Wpc,  1, 2 },     // ch0 = click
                  { Wufv, Wpfv, 0, 0 },     // ch1 = favor
                  { Wuco, Wpco, 2, 1 } };   // ch2 = consume

    const int UGB = N_USERS / 64;                 // 625
    const int PGB = (N_POIS + 63) / 64;           // 313

    if (fused) {
        // fused 3-channel L1-user hop: one shared pid_h gather, 3 raw outputs
        spmm3_kernel<<<N_USERS * 64 / 256, 256, 0, stream>>>(
            rptr, rpack, pid_h, utr0, utr1, utr2, N_USERS);
        for (int c = 0; c < 3; c++) {
            unsigned short* uc = (c == 0) ? utr0 : ((c == 1) ? utr1 : utr2);
            spmm_kernel<<<N_POIS * 64 / 256, 256, 0, stream>>>(cptr, cpack, c, uc, ptr_h, pid, sp, N_POIS);
            spmm_l2u_kernel<<<N_USERS * 64 / 256, 256, 0, stream>>>(rptr, rpack, c, ptr_h, uc, uid, su, N_USERS);
            spmm_kernel<<<N_POIS * 64 / 256, 256, 0, stream>>>(cptr, cpack, c, uc, ptr_h, sp, sp, N_POIS);
            gemm_mfma_kernel<<<UGB, 256, 0, stream>>>(
                su, chs[c].Wu, nullptr, idf, (c == 2) ? idf_h : nullptr,
                fw3, chs[c].fsel, (c == 0) ? 1 : 0, N_USERS);
            ufsel_kernel<<<BATCH, 128, 0, stream>>>(su, chs[c].Wu, uidx, ufs + (size_t)c * BATCH * DIM);
            gemm_mfma_kernel<<<PGB, 256, 0, stream>>>(
                sp, chs[c].Wp, pf, nullptr, nullptr, fw3, 0, 0, N_POIS);
            predict_kernel<<<BATCH * NPOS * 64 / 256, 256, 0, stream>>>(
                ufs + (size_t)c * BATCH * DIM, pf, pidx, w3, chs[c].wsel, (c == 0) ? 1 : 0, alt);
        }
    } else {
        // proven fallback: per-channel schedule, single utr0 buffer
        for (int c = 0; c < 3; c++) {
            spmm_kernel<<<N_USERS * 64 / 256, 256, 0, stream>>>(rptr, rpack, c, pid_h, utr0, uid, su, N_USERS);
            spmm_kernel<<<N_POIS * 64 / 256, 256, 0, stream>>>(cptr, cpack, c, utr0, ptr_h, pid, sp, N_POIS);
            spmm_kernel<<<N_USERS * 64 / 256, 256, 0, stream>>>(rptr, rpack, c, ptr_h, utr0, su, su, N_USERS);
            spmm_kernel<<<N_POIS * 64 / 256, 256, 0, stream>>>(cptr, cpack, c, utr0, ptr_h, sp, sp, N_POIS);
            gemm_mfma_kernel<<<UGB, 256, 0, stream>>>(
                su, chs[c].Wu, nullptr, idf, (c == 2) ? idf_h : nullptr,
                fw3, chs[c].fsel, (c == 0) ? 1 : 0, N_USERS);
            ufsel_kernel<<<BATCH, 128, 0, stream>>>(su, chs[c].Wu, uidx, ufs + (size_t)c * BATCH * DIM);
            gemm_mfma_kernel<<<PGB, 256, 0, stream>>>(
                sp, chs[c].Wp, pf, nullptr, nullptr, fw3, 0, 0, N_POIS);
            predict_kernel<<<BATCH * NPOS * 64 / 256, 256, 0, stream>>>(
                ufs + (size_t)c * BATCH * DIM, pf, pidx, w3, chs[c].wsel, (c == 0) ? 1 : 0, alt);
        }
    }

    loss_part_kernel<<<LOSS_BLOCKS, 256, 0, stream>>>(alt, labels, losspart);
    loss_final_kernel<<<1, 64, 0, stream>>>(losspart, outp);
    bs_kernel<<<BATCH, 128, 0, stream>>>(idf, Wss, bias, uidx, bst_h);
    dim3 sg(NCHUNK, 4);
    score_topk_kernel<<<sg, 256, 0, stream>>>(idf_h, bst_h, cand_s, cand_i);
    topk_merge_kernel<<<BATCH, NCHUNK, 0, stream>>>(cand_s, cand_i, guf, outp);
}